// Round 1
// baseline (2719.824 us; speedup 1.0000x reference)
//
#include <hip/hip_runtime.h>
#include <math.h>

#define Nn 4096
#define Ee 1024
#define Dd 256

// ---------------- block reduce (256 threads) ----------------
__device__ __forceinline__ float block_reduce_sum(float v) {
  __shared__ float sh[4];
  #pragma unroll
  for (int o = 32; o > 0; o >>= 1) v += __shfl_down(v, o);
  int lane = threadIdx.x & 63, w = threadIdx.x >> 6;
  if (lane == 0) sh[w] = v;
  __syncthreads();
  float s = sh[0] + sh[1] + sh[2] + sh[3];
  __syncthreads();
  return s;
}

// ---------------- generic strided GEMM, 64x64 tile, 4x4 microtile ----------------
// C[m,n] = epilogue( alpha * sum_k A[m*Asm + k*Ask] * B[k*Bsk + n*Bsn] )
// requires M%64==0, N%64==0, K%16==0, strides multiple of 4 where float4 paths hit.
__global__ __launch_bounds__(256) void gemm64_k(
    const float* __restrict__ Ap, const float* __restrict__ Bp, float* __restrict__ Cp,
    int M, int N, int K, int Asm, int Ask, int Bsk, int Bsn,
    float alpha, const float* __restrict__ coldiv, int beta, int do_elu)
{
  __shared__ alignas(16) float As[16][68];
  __shared__ alignas(16) float Bs[16][68];
  const int tid = threadIdx.x;
  const int tx = tid & 15, ty = tid >> 4;
  const int m0 = blockIdx.x * 64, n0 = blockIdx.y * 64;
  float acc[4][4] = {};
  for (int k0 = 0; k0 < K; k0 += 16) {
    if (Ask == 1) {
      int mm = tid >> 2, kk = (tid & 3) << 2;
      float4 v = *reinterpret_cast<const float4*>(&Ap[(long)(m0 + mm) * Asm + k0 + kk]);
      As[kk + 0][mm] = v.x; As[kk + 1][mm] = v.y; As[kk + 2][mm] = v.z; As[kk + 3][mm] = v.w;
    } else {  // Asm == 1
      int kk = tid >> 4, mm = (tid & 15) << 2;
      *reinterpret_cast<float4*>(&As[kk][mm]) =
          *reinterpret_cast<const float4*>(&Ap[(long)(k0 + kk) * Ask + m0 + mm]);
    }
    if (Bsn == 1) {
      int kk = tid >> 4, nn = (tid & 15) << 2;
      *reinterpret_cast<float4*>(&Bs[kk][nn]) =
          *reinterpret_cast<const float4*>(&Bp[(long)(k0 + kk) * Bsk + n0 + nn]);
    } else {  // Bsk == 1
      int nn = tid >> 2, kk = (tid & 3) << 2;
      float4 v = *reinterpret_cast<const float4*>(&Bp[(long)(n0 + nn) * Bsn + k0 + kk]);
      Bs[kk + 0][nn] = v.x; Bs[kk + 1][nn] = v.y; Bs[kk + 2][nn] = v.z; Bs[kk + 3][nn] = v.w;
    }
    __syncthreads();
    #pragma unroll
    for (int kk = 0; kk < 16; ++kk) {
      float4 av = *reinterpret_cast<const float4*>(&As[kk][ty << 2]);
      float4 bv = *reinterpret_cast<const float4*>(&Bs[kk][tx << 2]);
      float a[4] = {av.x, av.y, av.z, av.w};
      float b[4] = {bv.x, bv.y, bv.z, bv.w};
      #pragma unroll
      for (int r = 0; r < 4; ++r)
        #pragma unroll
        for (int c = 0; c < 4; ++c) acc[r][c] = fmaf(a[r], b[c], acc[r][c]);
    }
    __syncthreads();
  }
  #pragma unroll
  for (int r = 0; r < 4; ++r) {
    int row = m0 + (ty << 2) + r;
    int col = n0 + (tx << 2);
    long base = (long)row * N + col;
    float vv[4];
    #pragma unroll
    for (int c = 0; c < 4; ++c) vv[c] = acc[r][c] * alpha;
    if (coldiv) {
      #pragma unroll
      for (int c = 0; c < 4; ++c) vv[c] /= fmaxf(coldiv[col + c], 1.f);
    }
    if (beta) {
      float4 p = *reinterpret_cast<const float4*>(&Cp[base]);
      vv[0] += p.x; vv[1] += p.y; vv[2] += p.z; vv[3] += p.w;
    }
    if (do_elu) {
      #pragma unroll
      for (int c = 0; c < 4; ++c) vv[c] = vv[c] > 0.f ? vv[c] : expm1f(vv[c]);
    }
    float4 o = {vv[0], vv[1], vv[2], vv[3]};
    *reinterpret_cast<float4*>(&Cp[base]) = o;
  }
}

// ---------------- generic strided GEMM, 128x128 tile, 8x8 microtile (2x2 quadrants) ----------------
__global__ __launch_bounds__(256) void gemm128_k(
    const float* __restrict__ Ap, const float* __restrict__ Bp, float* __restrict__ Cp,
    int M, int N, int K, int Asm, int Ask, int Bsk, int Bsn,
    float alpha, const float* __restrict__ coldiv, int beta, int do_elu)
{
  __shared__ alignas(16) float As[16][132];
  __shared__ alignas(16) float Bs[16][132];
  const int tid = threadIdx.x;
  const int tx = tid & 15, ty = tid >> 4;
  const int m0 = blockIdx.x * 128, n0 = blockIdx.y * 128;
  float acc[2][2][4][4] = {};
  for (int k0 = 0; k0 < K; k0 += 16) {
    if (Ask == 1) {
      int mm = tid >> 2, kk = (tid & 3) << 2;
      #pragma unroll
      for (int h = 0; h < 2; ++h) {
        float4 v = *reinterpret_cast<const float4*>(&Ap[(long)(m0 + mm + 64 * h) * Asm + k0 + kk]);
        As[kk + 0][mm + 64 * h] = v.x; As[kk + 1][mm + 64 * h] = v.y;
        As[kk + 2][mm + 64 * h] = v.z; As[kk + 3][mm + 64 * h] = v.w;
      }
    } else {
      int kk = tid >> 4, mm = (tid & 15) << 2;
      #pragma unroll
      for (int h = 0; h < 2; ++h)
        *reinterpret_cast<float4*>(&As[kk][mm + 64 * h]) =
            *reinterpret_cast<const float4*>(&Ap[(long)(k0 + kk) * Ask + m0 + mm + 64 * h]);
    }
    if (Bsn == 1) {
      int kk = tid >> 4, nn = (tid & 15) << 2;
      #pragma unroll
      for (int h = 0; h < 2; ++h)
        *reinterpret_cast<float4*>(&Bs[kk][nn + 64 * h]) =
            *reinterpret_cast<const float4*>(&Bp[(long)(k0 + kk) * Bsk + n0 + nn + 64 * h]);
    } else {
      int nn = tid >> 2, kk = (tid & 3) << 2;
      #pragma unroll
      for (int h = 0; h < 2; ++h) {
        float4 v = *reinterpret_cast<const float4*>(&Bp[(long)(n0 + nn + 64 * h) * Bsn + k0 + kk]);
        Bs[kk + 0][nn + 64 * h] = v.x; Bs[kk + 1][nn + 64 * h] = v.y;
        Bs[kk + 2][nn + 64 * h] = v.z; Bs[kk + 3][nn + 64 * h] = v.w;
      }
    }
    __syncthreads();
    #pragma unroll
    for (int kk = 0; kk < 16; ++kk) {
      float a[2][4], b[2][4];
      #pragma unroll
      for (int h = 0; h < 2; ++h) {
        float4 av = *reinterpret_cast<const float4*>(&As[kk][(ty << 2) + 64 * h]);
        a[h][0] = av.x; a[h][1] = av.y; a[h][2] = av.z; a[h][3] = av.w;
        float4 bv = *reinterpret_cast<const float4*>(&Bs[kk][(tx << 2) + 64 * h]);
        b[h][0] = bv.x; b[h][1] = bv.y; b[h][2] = bv.z; b[h][3] = bv.w;
      }
      #pragma unroll
      for (int i = 0; i < 2; ++i)
        #pragma unroll
        for (int j = 0; j < 2; ++j)
          #pragma unroll
          for (int r = 0; r < 4; ++r)
            #pragma unroll
            for (int c = 0; c < 4; ++c)
              acc[i][j][r][c] = fmaf(a[i][r], b[j][c], acc[i][j][r][c]);
    }
    __syncthreads();
  }
  #pragma unroll
  for (int i = 0; i < 2; ++i) {
    #pragma unroll
    for (int r = 0; r < 4; ++r) {
      int row = m0 + 64 * i + (ty << 2) + r;
      #pragma unroll
      for (int j = 0; j < 2; ++j) {
        int col = n0 + 64 * j + (tx << 2);
        long base = (long)row * N + col;
        float vv[4];
        #pragma unroll
        for (int c = 0; c < 4; ++c) vv[c] = acc[i][j][r][c] * alpha;
        if (coldiv) {
          #pragma unroll
          for (int c = 0; c < 4; ++c) vv[c] /= fmaxf(coldiv[col + c], 1.f);
        }
        if (beta) {
          float4 p = *reinterpret_cast<const float4*>(&Cp[base]);
          vv[0] += p.x; vv[1] += p.y; vv[2] += p.z; vv[3] += p.w;
        }
        if (do_elu) {
          #pragma unroll
          for (int c = 0; c < 4; ++c) vv[c] = vv[c] > 0.f ? vv[c] : expm1f(vv[c]);
        }
        float4 o = {vv[0], vv[1], vv[2], vv[3]};
        *reinterpret_cast<float4*>(&Cp[base]) = o;
      }
    }
  }
}

// ---------------- sc/s1/s2 row dots ----------------
__global__ __launch_bounds__(256) void rowdots_k(
    const float* __restrict__ h_he, const float* __restrict__ h_g,
    const float* __restrict__ u, const float* __restrict__ a_g,
    float* __restrict__ esc, float* __restrict__ s1, float* __restrict__ s2)
{
  int i = blockIdx.x, t = threadIdx.x;
  float hh = h_he[(long)i * Dd + t];
  float hg = h_g[(long)i * Dd + t];
  float d0 = block_reduce_sum(hh * u[t]);
  float d1 = block_reduce_sum(hg * a_g[t]);
  float d2 = block_reduce_sum(hg * a_g[Dd + t]);
  if (t == 0) {
    esc[i] = expf(d0 * 0.0625f);  // exp(sc_i)
    s1[i] = d1;
    s2[i] = d2;
  }
}

// ---------------- column softmax stats for A (denominator + hyperedge size) ----------------
__global__ __launch_bounds__(256) void colstats_k(
    const float* __restrict__ H, const float* __restrict__ esc,
    float* __restrict__ colden, float* __restrict__ cnt)
{
  int e = blockIdx.x * 256 + threadIdx.x;
  int r0 = blockIdx.y * 128;
  float d = 0.f, c = 0.f;
  for (int r = r0; r < r0 + 128; ++r) {
    float h = H[(long)r * Ee + e];
    if (h > 0.f) { d += esc[r]; c += 1.f; }
  }
  atomicAdd(&colden[e], d);
  atomicAdd(&cnt[e], c);
}

// ---------------- A = maskH * exp(sc)/colden ----------------
__global__ __launch_bounds__(256) void fillA_k(
    const float* __restrict__ H, const float* __restrict__ esc,
    const float* __restrict__ colden, float* __restrict__ A)
{
  long base = ((long)blockIdx.x * 256 + threadIdx.x) * 4;
  int r = (int)(base >> 10);
  int e = (int)(base & 1023);
  float4 h = *reinterpret_cast<const float4*>(&H[base]);
  float4 cd = *reinterpret_cast<const float4*>(&colden[e]);
  float er = esc[r];
  float4 o;
  o.x = h.x > 0.f ? er / cd.x : 0.f;
  o.y = h.y > 0.f ? er / cd.y : 0.f;
  o.z = h.z > 0.f ? er / cd.z : 0.f;
  o.w = h.w > 0.f ? er / cd.w : 0.f;
  *reinterpret_cast<float4*>(&A[base]) = o;
}

// ---------------- B row softmax (masked, NEG semantics), in place ----------------
__global__ __launch_bounds__(256) void brow_k(float* __restrict__ Bbuf,
                                              const float* __restrict__ H)
{
  int i = blockIdx.x, t = threadIdx.x;
  long base = (long)i * Ee + t * 4;
  float4 raw = *reinterpret_cast<const float4*>(&Bbuf[base]);
  float4 h = *reinterpret_cast<const float4*>(&H[base]);
  float rr[4] = {raw.x, raw.y, raw.z, raw.w}, hh[4] = {h.x, h.y, h.z, h.w};
  float p[4]; float s = 0.f;
  #pragma unroll
  for (int k = 0; k < 4; ++k) { p[k] = hh[k] > 0.f ? expf(rr[k]) : 0.f; s += p[k]; }
  float den = block_reduce_sum(s);
  float inv = den > 0.f ? 1.f / den : 0.f;
  float4 o = {p[0] * inv, p[1] * inv, p[2] * inv, p[3] * inv};
  *reinterpret_cast<float4*>(&Bbuf[base]) = o;
}

// ---------------- G fill: normalized row softmax of graph-attention logits ----------------
__global__ __launch_bounds__(256) void gfill_k(
    const float* __restrict__ adj, const float* __restrict__ s1,
    const float* __restrict__ s2, float* __restrict__ G)
{
  int i = blockIdx.x, t = threadIdx.x;
  float s1i = s1[i];
  float p[16]; float sum = 0.f;
  #pragma unroll
  for (int c = 0; c < 4; ++c) {
    int j = c * 1024 + t * 4;
    float4 a = *reinterpret_cast<const float4*>(&adj[(long)i * Nn + j]);
    float4 sv = *reinterpret_cast<const float4*>(&s2[j]);
    float aa[4] = {a.x, a.y, a.z, a.w}, ss[4] = {sv.x, sv.y, sv.z, sv.w};
    #pragma unroll
    for (int k = 0; k < 4; ++k) {
      float f = (aa[k] > 0.f ? 1.f : 0.f) + ((j + k) == i ? 1.f : 0.f);
      float l = s1i + ss[k];
      l = l > 0.f ? l : 0.2f * l;                    // leaky_relu 0.2
      float val = l * f - 1e9f * fmaxf(1.f - f, 0.f);
      float pp = expf(val);                          // expf(-1e9) == 0
      p[c * 4 + k] = pp; sum += pp;
    }
  }
  float den = block_reduce_sum(sum);
  float inv = 1.f / den;
  #pragma unroll
  for (int c = 0; c < 4; ++c) {
    int j = c * 1024 + t * 4;
    float4 o = {p[c * 4] * inv, p[c * 4 + 1] * inv, p[c * 4 + 2] * inv, p[c * 4 + 3] * inv};
    *reinterpret_cast<float4*>(&G[(long)i * Nn + j]) = o;
  }
}

// ---------------- A_hat denominators: aden[e] = sum_j exp(A[j,e]+M[j,e]) (ALL j) ----------------
__global__ __launch_bounds__(256) void amstats_k(
    const float* __restrict__ A, const float* __restrict__ Mm, float* __restrict__ aden)
{
  int e = blockIdx.x * 256 + threadIdx.x;
  int r0 = blockIdx.y * 128;
  float d = 0.f;
  for (int r = r0; r < r0 + 128; ++r) {
    long idx = (long)r * Ee + e;
    d += expf(A[idx] + Mm[idx]);
  }
  atomicAdd(&aden[e], d);
}

// ---------------- A_hat fill (transpose to [E,N]) ----------------
__global__ __launch_bounds__(256) void ahat_k(
    const float* __restrict__ Abuf, const float* __restrict__ Mm,
    const float* __restrict__ H, const float* __restrict__ aden, float* __restrict__ Ahat)
{
  __shared__ float tile[64][65];
  int j0 = blockIdx.x * 64, e0 = blockIdx.y * 64;
  int te = threadIdx.x & 63;
  int tq = threadIdx.x >> 6;  // 0..3
  int e = e0 + te;
  float inv = 1.f / aden[e];
  for (int jj = tq; jj < 64; jj += 4) {
    long idx = (long)(j0 + jj) * Ee + e;
    float val = (H[idx] > 0.f) ? expf(Abuf[idx] + Mm[idx]) * inv : 0.f;
    tile[te][jj] = val;
  }
  __syncthreads();
  for (int ee = tq; ee < 64; ee += 4) {
    Ahat[(long)(e0 + ee) * Nn + j0 + te] = tile[ee][te];
  }
}

// ---------------- B_hat = softmax(B + M, axis=1)*mask, in place over B ----------------
__global__ __launch_bounds__(256) void bhat_k(float* __restrict__ Bbuf,
                                              const float* __restrict__ Mm,
                                              const float* __restrict__ H)
{
  int i = blockIdx.x, t = threadIdx.x;
  long base = (long)i * Ee + t * 4;
  float4 b = *reinterpret_cast<const float4*>(&Bbuf[base]);
  float4 m = *reinterpret_cast<const float4*>(&Mm[base]);
  float4 h = *reinterpret_cast<const float4*>(&H[base]);
  float bb[4] = {b.x, b.y, b.z, b.w}, mm2[4] = {m.x, m.y, m.z, m.w}, hh[4] = {h.x, h.y, h.z, h.w};
  float p[4]; float s = 0.f;
  #pragma unroll
  for (int k = 0; k < 4; ++k) { p[k] = expf(bb[k] + mm2[k]); s += p[k]; }
  float den = block_reduce_sum(s);
  float inv = 1.f / den;
  #pragma unroll
  for (int k = 0; k < 4; ++k) p[k] = hh[k] > 0.f ? p[k] * inv : 0.f;
  float4 o = {p[0], p[1], p[2], p[3]};
  *reinterpret_cast<float4*>(&Bbuf[base]) = o;
}

// ---------------- G_hat row softmax in place (no mask) ----------------
__global__ __launch_bounds__(256) void ghat_k(float* __restrict__ G)
{
  int i = blockIdx.x, t = threadIdx.x;
  float p[16]; float s = 0.f;
  #pragma unroll
  for (int c = 0; c < 4; ++c) {
    long base = (long)i * Nn + c * 1024 + t * 4;
    float4 v = *reinterpret_cast<const float4*>(&G[base]);
    float vv[4] = {v.x, v.y, v.z, v.w};
    #pragma unroll
    for (int k = 0; k < 4; ++k) { float pe = expf(vv[k]); p[c * 4 + k] = pe; s += pe; }
  }
  float den = block_reduce_sum(s);
  float inv = 1.f / den;
  #pragma unroll
  for (int c = 0; c < 4; ++c) {
    long base = (long)i * Nn + c * 1024 + t * 4;
    float4 o = {p[c * 4] * inv, p[c * 4 + 1] * inv, p[c * 4 + 2] * inv, p[c * 4 + 3] * inv};
    *reinterpret_cast<float4*>(&G[base]) = o;
  }
}

// ---------------- launcher ----------------
extern "C" void kernel_launch(void* const* d_in, const int* in_sizes, int n_in,
                              void* d_out, int out_size, void* d_ws, size_t ws_size,
                              hipStream_t stream) {
  const float* x    = (const float*)d_in[0];
  const float* H    = (const float*)d_in[1];
  const float* adj  = (const float*)d_in[2];
  const float* W_he = (const float*)d_in[3];
  const float* u    = (const float*)d_in[4];
  const float* W_e  = (const float*)d_in[5];
  const float* W_n  = (const float*)d_in[6];
  const float* W_g  = (const float*)d_in[7];
  const float* a_g  = (const float*)d_in[8];
  float* out = (float*)d_out;
  float* ws  = (float*)d_ws;

  size_t off = 0;
  auto alloc = [&](size_t n) { float* p = ws + off; off += n; return p; };
  float* h_he   = alloc((size_t)Nn * Dd);
  float* hn     = alloc((size_t)Nn * Dd);
  float* h_g    = alloc((size_t)Nn * Dd);
  float* esc    = alloc(Nn);
  float* s1     = alloc(Nn);
  float* s2     = alloc(Nn);
  float* colden = alloc(Ee);   // these three contiguous -> one memset
  float* cnt    = alloc(Ee);
  float* aden   = alloc(Ee);
  float* e_repr = alloc((size_t)Ee * Dd);
  float* heb    = alloc((size_t)Ee * Dd);
  float* e_mix  = alloc((size_t)Ee * Dd);
  float* tmp_ew = alloc((size_t)Ee * Dd);
  float* Abuf   = alloc((size_t)Nn * Ee);
  float* Bbuf   = alloc((size_t)Nn * Ee);
  float* Mm     = alloc((size_t)Nn * Ee);
  float* Ahat   = alloc((size_t)Ee * Nn);
  float* G      = alloc((size_t)Nn * Nn);
  (void)ws_size; (void)in_sizes; (void)n_in; (void)out_size;

  hipMemsetAsync(colden, 0, 3 * Ee * sizeof(float), stream);

  auto g64 = [&](const float* A, const float* B, float* C, int M, int N, int K,
                 int Asm, int Ask, int Bsk, int Bsn, float alpha,
                 const float* cd, int beta, int elu) {
    gemm64_k<<<dim3(M / 64, N / 64), 256, 0, stream>>>(A, B, C, M, N, K, Asm, Ask, Bsk, Bsn,
                                                       alpha, cd, beta, elu);
  };
  auto g128 = [&](const float* A, const float* B, float* C, int M, int N, int K,
                  int Asm, int Ask, int Bsk, int Bsn, float alpha,
                  const float* cd, int beta, int elu) {
    gemm128_k<<<dim3(M / 128, N / 128), 256, 0, stream>>>(A, B, C, M, N, K, Asm, Ask, Bsk, Bsn,
                                                          alpha, cd, beta, elu);
  };

  // projections
  g64(x, W_he, h_he, Nn, Dd, Dd, Dd, 1, Dd, 1, 1.f, nullptr, 0, 0);
  g64(x, W_n, hn, Nn, Dd, Dd, Dd, 1, Dd, 1, 1.f, nullptr, 0, 0);
  g64(x, W_g, h_g, Nn, Dd, Dd, Dd, 1, Dd, 1, 1.f, nullptr, 0, 0);
  // sc (as exp(sc)), s1, s2
  rowdots_k<<<Nn, 256, 0, stream>>>(h_he, h_g, u, a_g, esc, s1, s2);
  // A column softmax
  colstats_k<<<dim3(Ee / 256, 32), 256, 0, stream>>>(H, esc, colden, cnt);
  fillA_k<<<(Nn * Ee) / 1024, 256, 0, stream>>>(H, esc, colden, Abuf);
  // e_repr = A^T @ h_he ; he = e_repr @ W_e
  g64(Abuf, h_he, e_repr, Ee, Dd, Nn, 1, Ee, Dd, 1, 1.f, nullptr, 0, 0);
  g64(e_repr, W_e, heb, Ee, Dd, Dd, Dd, 1, Dd, 1, 1.f, nullptr, 0, 0);
  // B = rowsoftmax(mask(hn @ he^T / 16))
  g128(hn, heb, Bbuf, Nn, Ee, Dd, Dd, 1, 1, Dd, 0.0625f, nullptr, 0, 0);
  brow_k<<<Nn, 256, 0, stream>>>(Bbuf, H);
  // G (normalized), M = (G @ H) / he_sz
  gfill_k<<<Nn, 256, 0, stream>>>(adj, s1, s2, G);
  g128(G, H, Mm, Nn, Ee, Nn, Nn, 1, Ee, 1, 1.f, cnt, 0, 0);
  // G += B B^T ; G += A A^T   (G_hat logits)
  g128(Bbuf, Bbuf, G, Nn, Nn, Ee, Ee, 1, 1, Ee, 1.f, nullptr, 1, 0);
  g128(Abuf, Abuf, G, Nn, Nn, Ee, Ee, 1, 1, Ee, 1.f, nullptr, 1, 0);
  // A_hat
  amstats_k<<<dim3(Ee / 256, 32), 256, 0, stream>>>(Abuf, Mm, aden);
  ahat_k<<<dim3(Nn / 64, Ee / 64), 256, 0, stream>>>(Abuf, Mm, H, aden, Ahat);
  // e_mix = A_hat @ h_he ; tmp_ew = e_mix @ W_e
  g64(Ahat, h_he, e_mix, Ee, Dd, Nn, Nn, 1, Dd, 1, 1.f, nullptr, 0, 0);
  g64(e_mix, W_e, tmp_ew, Ee, Dd, Dd, Dd, 1, Dd, 1, 1.f, nullptr, 0, 0);
  // B_hat (in place over B), z_h = elu(B_hat @ tmp_ew)
  bhat_k<<<Nn, 256, 0, stream>>>(Bbuf, Mm, H);
  g64(Bbuf, tmp_ew, out, Nn, Dd, Ee, Ee, 1, Dd, 1, 1.f, nullptr, 0, 1);
  // G_hat (in place), z_g = elu(G_hat @ h_g)
  ghat_k<<<Nn, 256, 0, stream>>>(G);
  g64(G, h_g, out + (size_t)Nn * Dd, Nn, Dd, Nn, Nn, 1, Dd, 1, 1.f, nullptr, 0, 1);
}

// Round 2
// 1687.020 us; speedup vs baseline: 1.6122x; 1.6122x over previous
//
#include <hip/hip_runtime.h>
#include <math.h>
#include <stdint.h>

#define Nn 4096
#define Ee 1024
#define Dd 256

typedef __attribute__((ext_vector_type(8))) __bf16 bf16x8;
typedef __attribute__((ext_vector_type(4))) float f32x4;
typedef __attribute__((ext_vector_type(8))) unsigned short u16x8;

__device__ __forceinline__ unsigned short f2bf(float f) {
  unsigned int u = __float_as_uint(f);
  unsigned int r = (u + 0x7fffu + ((u >> 16) & 1u)) >> 16;
  return (unsigned short)r;
}

__device__ __forceinline__ void gload_lds16(const void* g, void* l) {
  __builtin_amdgcn_global_load_lds(
      (__attribute__((address_space(1))) void*)const_cast<void*>(g),
      (__attribute__((address_space(3))) void*)l, 16, 0, 0);
}

// ---------------- block reduce (256 threads) ----------------
__device__ __forceinline__ float block_reduce_sum(float v) {
  __shared__ float sh[4];
  #pragma unroll
  for (int o = 32; o > 0; o >>= 1) v += __shfl_down(v, o);
  int lane = threadIdx.x & 63, w = threadIdx.x >> 6;
  if (lane == 0) sh[w] = v;
  __syncthreads();
  float s = sh[0] + sh[1] + sh[2] + sh[3];
  __syncthreads();
  return s;
}

// ---------------- bf16 MFMA GEMM: C = A * B^T  (both row-major [*,K] bf16) ----------------
// 128x128 tile, BK=32, 4 waves (2x2), wave-tile 64x64, 16x16x32 MFMA.
__global__ __launch_bounds__(256) void gemm_bt_bf16(
    const unsigned short* __restrict__ Ab,   // [M][K] bf16
    const unsigned short* __restrict__ Bb,   // [N][K] bf16
    float* __restrict__ Cp, const float* __restrict__ Cin,
    int M, int N, int K,
    const float* __restrict__ coldiv, int beta)
{
  __shared__ unsigned short As[2][128 * 32];
  __shared__ unsigned short Bs[2][128 * 32];
  const int tid = threadIdx.x;
  const int m0 = blockIdx.x * 128, n0 = blockIdx.y * 128;
  const int wave = tid >> 6, lane = tid & 63;
  const int wr = (wave >> 1) * 64, wc = (wave & 1) * 64;
  const int l16 = lane & 15, lq = lane >> 4;  // lq 0..3
  f32x4 acc[4][4] = {};
  const int NT = K >> 5;

  auto stage = [&](int buf, int kt) {
    const int k0 = kt * 32;
    #pragma unroll
    for (int i = 0; i < 2; ++i) {
      int t2 = tid + i * 256;
      int r = t2 >> 2, c = (t2 & 3) * 8;
      gload_lds16(Ab + (size_t)(m0 + r) * K + k0 + c, &As[buf][t2 * 8]);
    }
    #pragma unroll
    for (int i = 0; i < 2; ++i) {
      int t2 = tid + i * 256;
      int r = t2 >> 2, c = (t2 & 3) * 8;
      gload_lds16(Bb + (size_t)(n0 + r) * K + k0 + c, &Bs[buf][t2 * 8]);
    }
  };

  stage(0, 0);
  __syncthreads();
  int buf = 0;
  for (int kt = 0; kt < NT; ++kt) {
    if (kt + 1 < NT) stage(buf ^ 1, kt + 1);
    bf16x8 af[4], bfr[4];
    #pragma unroll
    for (int m = 0; m < 4; ++m)
      af[m] = *reinterpret_cast<const bf16x8*>(&As[buf][(wr + m * 16 + l16) * 32 + lq * 8]);
    #pragma unroll
    for (int n = 0; n < 4; ++n)
      bfr[n] = *reinterpret_cast<const bf16x8*>(&Bs[buf][(wc + n * 16 + l16) * 32 + lq * 8]);
    #pragma unroll
    for (int m = 0; m < 4; ++m)
      #pragma unroll
      for (int n = 0; n < 4; ++n)
        acc[m][n] = __builtin_amdgcn_mfma_f32_16x16x32_bf16(af[m], bfr[n], acc[m][n], 0, 0, 0);
    __syncthreads();
    buf ^= 1;
  }
  #pragma unroll
  for (int m = 0; m < 4; ++m) {
    #pragma unroll
    for (int n = 0; n < 4; ++n) {
      int col = n0 + wc + n * 16 + l16;
      float cd = coldiv ? fmaxf(coldiv[col], 1.f) : 1.f;
      #pragma unroll
      for (int q = 0; q < 4; ++q) {
        int row = m0 + wr + m * 16 + lq * 4 + q;
        size_t idx = (size_t)row * N + col;
        float v = acc[m][n][q];
        if (coldiv) v /= cd;
        if (beta) v += Cin[idx];
        Cp[idx] = v;
      }
    }
  }
}

// ---------------- f32 -> bf16 convert (8 elems/thread) ----------------
__global__ __launch_bounds__(256) void cvt_bf16_k(const float* __restrict__ in,
                                                  unsigned short* __restrict__ out, long n) {
  long i = ((long)blockIdx.x * 256 + threadIdx.x) * 8;
  if (i + 8 > n) return;
  float4 a = *reinterpret_cast<const float4*>(&in[i]);
  float4 b = *reinterpret_cast<const float4*>(&in[i + 4]);
  u16x8 o;
  o[0] = f2bf(a.x); o[1] = f2bf(a.y); o[2] = f2bf(a.z); o[3] = f2bf(a.w);
  o[4] = f2bf(b.x); o[5] = f2bf(b.y); o[6] = f2bf(b.z); o[7] = f2bf(b.w);
  *reinterpret_cast<u16x8*>(&out[i]) = o;
}

// ---------------- transpose-convert H [N][E] f32 -> Hbt [E][N] bf16 ----------------
__global__ __launch_bounds__(256) void thbf_k(const float* __restrict__ H,
                                              unsigned short* __restrict__ Hbt) {
  __shared__ unsigned short tile[64][65];
  int n0 = blockIdx.x * 64, e0 = blockIdx.y * 64;
  int t = threadIdx.x & 63, q = threadIdx.x >> 6;
  for (int nn = q; nn < 64; nn += 4)
    tile[t][nn] = f2bf(H[(long)(n0 + nn) * Ee + e0 + t]);
  __syncthreads();
  for (int ee = q; ee < 64; ee += 4)
    Hbt[(long)(e0 + ee) * Nn + n0 + t] = tile[ee][t];
}

// ---------------- generic strided GEMM, 64x64 tile, 4x4 microtile ----------------
__global__ __launch_bounds__(256) void gemm64_k(
    const float* __restrict__ Ap, const float* __restrict__ Bp, float* __restrict__ Cp,
    int M, int N, int K, int Asm, int Ask, int Bsk, int Bsn,
    float alpha, const float* __restrict__ coldiv, int beta, int do_elu)
{
  __shared__ alignas(16) float As[16][68];
  __shared__ alignas(16) float Bs[16][68];
  const int tid = threadIdx.x;
  const int tx = tid & 15, ty = tid >> 4;
  const int m0 = blockIdx.x * 64, n0 = blockIdx.y * 64;
  float acc[4][4] = {};
  for (int k0 = 0; k0 < K; k0 += 16) {
    if (Ask == 1) {
      int mm = tid >> 2, kk = (tid & 3) << 2;
      float4 v = *reinterpret_cast<const float4*>(&Ap[(long)(m0 + mm) * Asm + k0 + kk]);
      As[kk + 0][mm] = v.x; As[kk + 1][mm] = v.y; As[kk + 2][mm] = v.z; As[kk + 3][mm] = v.w;
    } else {
      int kk = tid >> 4, mm = (tid & 15) << 2;
      *reinterpret_cast<float4*>(&As[kk][mm]) =
          *reinterpret_cast<const float4*>(&Ap[(long)(k0 + kk) * Ask + m0 + mm]);
    }
    if (Bsn == 1) {
      int kk = tid >> 4, nn = (tid & 15) << 2;
      *reinterpret_cast<float4*>(&Bs[kk][nn]) =
          *reinterpret_cast<const float4*>(&Bp[(long)(k0 + kk) * Bsk + n0 + nn]);
    } else {
      int nn = tid >> 2, kk = (tid & 3) << 2;
      float4 v = *reinterpret_cast<const float4*>(&Bp[(long)(n0 + nn) * Bsn + k0 + kk]);
      Bs[kk + 0][nn] = v.x; Bs[kk + 1][nn] = v.y; Bs[kk + 2][nn] = v.z; Bs[kk + 3][nn] = v.w;
    }
    __syncthreads();
    #pragma unroll
    for (int kk = 0; kk < 16; ++kk) {
      float4 av = *reinterpret_cast<const float4*>(&As[kk][ty << 2]);
      float4 bv = *reinterpret_cast<const float4*>(&Bs[kk][tx << 2]);
      float a[4] = {av.x, av.y, av.z, av.w};
      float b[4] = {bv.x, bv.y, bv.z, bv.w};
      #pragma unroll
      for (int r = 0; r < 4; ++r)
        #pragma unroll
        for (int c = 0; c < 4; ++c) acc[r][c] = fmaf(a[r], b[c], acc[r][c]);
    }
    __syncthreads();
  }
  #pragma unroll
  for (int r = 0; r < 4; ++r) {
    int row = m0 + (ty << 2) + r;
    int col = n0 + (tx << 2);
    long base = (long)row * N + col;
    float vv[4];
    #pragma unroll
    for (int c = 0; c < 4; ++c) vv[c] = acc[r][c] * alpha;
    if (coldiv) {
      #pragma unroll
      for (int c = 0; c < 4; ++c) vv[c] /= fmaxf(coldiv[col + c], 1.f);
    }
    if (beta) {
      float4 p = *reinterpret_cast<const float4*>(&Cp[base]);
      vv[0] += p.x; vv[1] += p.y; vv[2] += p.z; vv[3] += p.w;
    }
    if (do_elu) {
      #pragma unroll
      for (int c = 0; c < 4; ++c) vv[c] = vv[c] > 0.f ? vv[c] : expm1f(vv[c]);
    }
    float4 o = {vv[0], vv[1], vv[2], vv[3]};
    *reinterpret_cast<float4*>(&Cp[base]) = o;
  }
}

// ---------------- generic strided GEMM, 128x128 tile (f32 fallback) ----------------
__global__ __launch_bounds__(256) void gemm128_k(
    const float* __restrict__ Ap, const float* __restrict__ Bp, float* __restrict__ Cp,
    int M, int N, int K, int Asm, int Ask, int Bsk, int Bsn,
    float alpha, const float* __restrict__ coldiv, int beta, int do_elu)
{
  __shared__ alignas(16) float As[16][132];
  __shared__ alignas(16) float Bs[16][132];
  const int tid = threadIdx.x;
  const int tx = tid & 15, ty = tid >> 4;
  const int m0 = blockIdx.x * 128, n0 = blockIdx.y * 128;
  float acc[2][2][4][4] = {};
  for (int k0 = 0; k0 < K; k0 += 16) {
    if (Ask == 1) {
      int mm = tid >> 2, kk = (tid & 3) << 2;
      #pragma unroll
      for (int h = 0; h < 2; ++h) {
        float4 v = *reinterpret_cast<const float4*>(&Ap[(long)(m0 + mm + 64 * h) * Asm + k0 + kk]);
        As[kk + 0][mm + 64 * h] = v.x; As[kk + 1][mm + 64 * h] = v.y;
        As[kk + 2][mm + 64 * h] = v.z; As[kk + 3][mm + 64 * h] = v.w;
      }
    } else {
      int kk = tid >> 4, mm = (tid & 15) << 2;
      #pragma unroll
      for (int h = 0; h < 2; ++h)
        *reinterpret_cast<float4*>(&As[kk][mm + 64 * h]) =
            *reinterpret_cast<const float4*>(&Ap[(long)(k0 + kk) * Ask + m0 + mm + 64 * h]);
    }
    if (Bsn == 1) {
      int kk = tid >> 4, nn = (tid & 15) << 2;
      #pragma unroll
      for (int h = 0; h < 2; ++h)
        *reinterpret_cast<float4*>(&Bs[kk][nn + 64 * h]) =
            *reinterpret_cast<const float4*>(&Bp[(long)(k0 + kk) * Bsk + n0 + nn + 64 * h]);
    } else {
      int nn = tid >> 2, kk = (tid & 3) << 2;
      #pragma unroll
      for (int h = 0; h < 2; ++h) {
        float4 v = *reinterpret_cast<const float4*>(&Bp[(long)(n0 + nn + 64 * h) * Bsn + k0 + kk]);
        Bs[kk + 0][nn + 64 * h] = v.x; Bs[kk + 1][nn + 64 * h] = v.y;
        Bs[kk + 2][nn + 64 * h] = v.z; Bs[kk + 3][nn + 64 * h] = v.w;
      }
    }
    __syncthreads();
    #pragma unroll
    for (int kk = 0; kk < 16; ++kk) {
      float a[2][4], b[2][4];
      #pragma unroll
      for (int h = 0; h < 2; ++h) {
        float4 av = *reinterpret_cast<const float4*>(&As[kk][(ty << 2) + 64 * h]);
        a[h][0] = av.x; a[h][1] = av.y; a[h][2] = av.z; a[h][3] = av.w;
        float4 bv = *reinterpret_cast<const float4*>(&Bs[kk][(tx << 2) + 64 * h]);
        b[h][0] = bv.x; b[h][1] = bv.y; b[h][2] = bv.z; b[h][3] = bv.w;
      }
      #pragma unroll
      for (int i = 0; i < 2; ++i)
        #pragma unroll
        for (int j = 0; j < 2; ++j)
          #pragma unroll
          for (int r = 0; r < 4; ++r)
            #pragma unroll
            for (int c = 0; c < 4; ++c)
              acc[i][j][r][c] = fmaf(a[i][r], b[j][c], acc[i][j][r][c]);
    }
    __syncthreads();
  }
  #pragma unroll
  for (int i = 0; i < 2; ++i) {
    #pragma unroll
    for (int r = 0; r < 4; ++r) {
      int row = m0 + 64 * i + (ty << 2) + r;
      #pragma unroll
      for (int j = 0; j < 2; ++j) {
        int col = n0 + 64 * j + (tx << 2);
        long base = (long)row * N + col;
        float vv[4];
        #pragma unroll
        for (int c = 0; c < 4; ++c) vv[c] = acc[i][j][r][c] * alpha;
        if (coldiv) {
          #pragma unroll
          for (int c = 0; c < 4; ++c) vv[c] /= fmaxf(coldiv[col + c], 1.f);
        }
        if (beta) {
          float4 p = *reinterpret_cast<const float4*>(&Cp[base]);
          vv[0] += p.x; vv[1] += p.y; vv[2] += p.z; vv[3] += p.w;
        }
        if (do_elu) {
          #pragma unroll
          for (int c = 0; c < 4; ++c) vv[c] = vv[c] > 0.f ? vv[c] : expm1f(vv[c]);
        }
        float4 o = {vv[0], vv[1], vv[2], vv[3]};
        *reinterpret_cast<float4*>(&Cp[base]) = o;
      }
    }
  }
}

// ---------------- sc/s1/s2 row dots ----------------
__global__ __launch_bounds__(256) void rowdots_k(
    const float* __restrict__ h_he, const float* __restrict__ h_g,
    const float* __restrict__ u, const float* __restrict__ a_g,
    float* __restrict__ esc, float* __restrict__ s1, float* __restrict__ s2)
{
  int i = blockIdx.x, t = threadIdx.x;
  float hh = h_he[(long)i * Dd + t];
  float hg = h_g[(long)i * Dd + t];
  float d0 = block_reduce_sum(hh * u[t]);
  float d1 = block_reduce_sum(hg * a_g[t]);
  float d2 = block_reduce_sum(hg * a_g[Dd + t]);
  if (t == 0) {
    esc[i] = expf(d0 * 0.0625f);
    s1[i] = d1;
    s2[i] = d2;
  }
}

// ---------------- column softmax stats for A ----------------
__global__ __launch_bounds__(256) void colstats_k(
    const float* __restrict__ H, const float* __restrict__ esc,
    float* __restrict__ colden, float* __restrict__ cnt)
{
  int e = blockIdx.x * 256 + threadIdx.x;
  int r0 = blockIdx.y * 128;
  float d = 0.f, c = 0.f;
  for (int r = r0; r < r0 + 128; ++r) {
    float h = H[(long)r * Ee + e];
    if (h > 0.f) { d += esc[r]; c += 1.f; }
  }
  atomicAdd(&colden[e], d);
  atomicAdd(&cnt[e], c);
}

// ---------------- A = maskH * exp(sc)/colden ----------------
__global__ __launch_bounds__(256) void fillA_k(
    const float* __restrict__ H, const float* __restrict__ esc,
    const float* __restrict__ colden, float* __restrict__ A)
{
  long base = ((long)blockIdx.x * 256 + threadIdx.x) * 4;
  int r = (int)(base >> 10);
  int e = (int)(base & 1023);
  float4 h = *reinterpret_cast<const float4*>(&H[base]);
  float4 cd = *reinterpret_cast<const float4*>(&colden[e]);
  float er = esc[r];
  float4 o;
  o.x = h.x > 0.f ? er / cd.x : 0.f;
  o.y = h.y > 0.f ? er / cd.y : 0.f;
  o.z = h.z > 0.f ? er / cd.z : 0.f;
  o.w = h.w > 0.f ? er / cd.w : 0.f;
  *reinterpret_cast<float4*>(&A[base]) = o;
}

// ---------------- B row softmax ----------------
__global__ __launch_bounds__(256) void brow_k(float* __restrict__ Bbuf,
                                              const float* __restrict__ H)
{
  int i = blockIdx.x, t = threadIdx.x;
  long base = (long)i * Ee + t * 4;
  float4 raw = *reinterpret_cast<const float4*>(&Bbuf[base]);
  float4 h = *reinterpret_cast<const float4*>(&H[base]);
  float rr[4] = {raw.x, raw.y, raw.z, raw.w}, hh[4] = {h.x, h.y, h.z, h.w};
  float p[4]; float s = 0.f;
  #pragma unroll
  for (int k = 0; k < 4; ++k) { p[k] = hh[k] > 0.f ? expf(rr[k]) : 0.f; s += p[k]; }
  float den = block_reduce_sum(s);
  float inv = den > 0.f ? 1.f / den : 0.f;
  float4 o = {p[0] * inv, p[1] * inv, p[2] * inv, p[3] * inv};
  *reinterpret_cast<float4*>(&Bbuf[base]) = o;
}

// ---------------- G fill ----------------
__global__ __launch_bounds__(256) void gfill_k(
    const float* __restrict__ adj, const float* __restrict__ s1,
    const float* __restrict__ s2, float* __restrict__ G)
{
  int i = blockIdx.x, t = threadIdx.x;
  float s1i = s1[i];
  float p[16]; float sum = 0.f;
  #pragma unroll
  for (int c = 0; c < 4; ++c) {
    int j = c * 1024 + t * 4;
    float4 a = *reinterpret_cast<const float4*>(&adj[(long)i * Nn + j]);
    float4 sv = *reinterpret_cast<const float4*>(&s2[j]);
    float aa[4] = {a.x, a.y, a.z, a.w}, ss[4] = {sv.x, sv.y, sv.z, sv.w};
    #pragma unroll
    for (int k = 0; k < 4; ++k) {
      float f = (aa[k] > 0.f ? 1.f : 0.f) + ((j + k) == i ? 1.f : 0.f);
      float l = s1i + ss[k];
      l = l > 0.f ? l : 0.2f * l;
      float val = l * f - 1e9f * fmaxf(1.f - f, 0.f);
      float pp = expf(val);
      p[c * 4 + k] = pp; sum += pp;
    }
  }
  float den = block_reduce_sum(sum);
  float inv = 1.f / den;
  #pragma unroll
  for (int c = 0; c < 4; ++c) {
    int j = c * 1024 + t * 4;
    float4 o = {p[c * 4] * inv, p[c * 4 + 1] * inv, p[c * 4 + 2] * inv, p[c * 4 + 3] * inv};
    *reinterpret_cast<float4*>(&G[(long)i * Nn + j]) = o;
  }
}

// ---------------- A_hat denominators ----------------
__global__ __launch_bounds__(256) void amstats_k(
    const float* __restrict__ A, const float* __restrict__ Mm, float* __restrict__ aden)
{
  int e = blockIdx.x * 256 + threadIdx.x;
  int r0 = blockIdx.y * 128;
  float d = 0.f;
  for (int r = r0; r < r0 + 128; ++r) {
    long idx = (long)r * Ee + e;
    d += expf(A[idx] + Mm[idx]);
  }
  atomicAdd(&aden[e], d);
}

// ---------------- A_hat fill (transpose to [E,N]) ----------------
__global__ __launch_bounds__(256) void ahat_k(
    const float* __restrict__ Abuf, const float* __restrict__ Mm,
    const float* __restrict__ H, const float* __restrict__ aden, float* __restrict__ Ahat)
{
  __shared__ float tile[64][65];
  int j0 = blockIdx.x * 64, e0 = blockIdx.y * 64;
  int te = threadIdx.x & 63;
  int tq = threadIdx.x >> 6;
  int e = e0 + te;
  float inv = 1.f / aden[e];
  for (int jj = tq; jj < 64; jj += 4) {
    long idx = (long)(j0 + jj) * Ee + e;
    float val = (H[idx] > 0.f) ? expf(Abuf[idx] + Mm[idx]) * inv : 0.f;
    tile[te][jj] = val;
  }
  __syncthreads();
  for (int ee = tq; ee < 64; ee += 4) {
    Ahat[(long)(e0 + ee) * Nn + j0 + te] = tile[ee][te];
  }
}

// ---------------- B_hat ----------------
__global__ __launch_bounds__(256) void bhat_k(float* __restrict__ Bbuf,
                                              const float* __restrict__ Mm,
                                              const float* __restrict__ H)
{
  int i = blockIdx.x, t = threadIdx.x;
  long base = (long)i * Ee + t * 4;
  float4 b = *reinterpret_cast<const float4*>(&Bbuf[base]);
  float4 m = *reinterpret_cast<const float4*>(&Mm[base]);
  float4 h = *reinterpret_cast<const float4*>(&H[base]);
  float bb[4] = {b.x, b.y, b.z, b.w}, mm2[4] = {m.x, m.y, m.z, m.w}, hh[4] = {h.x, h.y, h.z, h.w};
  float p[4]; float s = 0.f;
  #pragma unroll
  for (int k = 0; k < 4; ++k) { p[k] = expf(bb[k] + mm2[k]); s += p[k]; }
  float den = block_reduce_sum(s);
  float inv = 1.f / den;
  #pragma unroll
  for (int k = 0; k < 4; ++k) p[k] = hh[k] > 0.f ? p[k] * inv : 0.f;
  float4 o = {p[0], p[1], p[2], p[3]};
  *reinterpret_cast<float4*>(&Bbuf[base]) = o;
}

// ---------------- G_hat row softmax ----------------
__global__ __launch_bounds__(256) void ghat_k(float* __restrict__ G)
{
  int i = blockIdx.x, t = threadIdx.x;
  float p[16]; float s = 0.f;
  #pragma unroll
  for (int c = 0; c < 4; ++c) {
    long base = (long)i * Nn + c * 1024 + t * 4;
    float4 v = *reinterpret_cast<const float4*>(&G[base]);
    float vv[4] = {v.x, v.y, v.z, v.w};
    #pragma unroll
    for (int k = 0; k < 4; ++k) { float pe = expf(vv[k]); p[c * 4 + k] = pe; s += pe; }
  }
  float den = block_reduce_sum(s);
  float inv = 1.f / den;
  #pragma unroll
  for (int c = 0; c < 4; ++c) {
    long base = (long)i * Nn + c * 1024 + t * 4;
    float4 o = {p[c * 4] * inv, p[c * 4 + 1] * inv, p[c * 4 + 2] * inv, p[c * 4 + 3] * inv};
    *reinterpret_cast<float4*>(&G[base]) = o;
  }
}

// ---------------- launcher ----------------
extern "C" void kernel_launch(void* const* d_in, const int* in_sizes, int n_in,
                              void* d_out, int out_size, void* d_ws, size_t ws_size,
                              hipStream_t stream) {
  const float* x    = (const float*)d_in[0];
  const float* H    = (const float*)d_in[1];
  const float* adj  = (const float*)d_in[2];
  const float* W_he = (const float*)d_in[3];
  const float* u    = (const float*)d_in[4];
  const float* W_e  = (const float*)d_in[5];
  const float* W_n  = (const float*)d_in[6];
  const float* W_g  = (const float*)d_in[7];
  const float* a_g  = (const float*)d_in[8];
  float* out = (float*)d_out;
  float* ws  = (float*)d_ws;

  size_t off = 0;
  auto alloc = [&](size_t n) { float* p = ws + off; off += n; return p; };
  float* h_he   = alloc((size_t)Nn * Dd);
  float* hn     = alloc((size_t)Nn * Dd);
  float* h_g    = alloc((size_t)Nn * Dd);
  float* esc    = alloc(Nn);
  float* s1     = alloc(Nn);
  float* s2     = alloc(Nn);
  float* colden = alloc(Ee);
  float* cnt    = alloc(Ee);
  float* aden   = alloc(Ee);
  float* e_repr = alloc((size_t)Ee * Dd);
  float* heb    = alloc((size_t)Ee * Dd);
  float* e_mix  = alloc((size_t)Ee * Dd);
  float* tmp_ew = alloc((size_t)Ee * Dd);
  float* Abuf   = alloc((size_t)Nn * Ee);
  float* Bbuf   = alloc((size_t)Nn * Ee);
  float* Mm     = alloc((size_t)Nn * Ee);
  float* Ahat   = alloc((size_t)Ee * Nn);
  float* G      = alloc((size_t)Nn * Nn);
  // bf16 scratch (allocated last so the f32 fallback works if ws is small)
  unsigned short* Gb  = (unsigned short*)alloc((size_t)Nn * Nn / 2);
  unsigned short* Hbt = (unsigned short*)alloc((size_t)Ee * Nn / 2);
  unsigned short* Ab2 = (unsigned short*)alloc((size_t)Nn * Ee / 2);
  unsigned short* Bb2 = (unsigned short*)alloc((size_t)Nn * Ee / 2);
  size_t need_bytes = off * sizeof(float);
  const bool use_mfma = ws_size >= need_bytes;
  (void)in_sizes; (void)n_in; (void)out_size;

  hipMemsetAsync(colden, 0, 3 * Ee * sizeof(float), stream);

  auto g64 = [&](const float* A, const float* B, float* C, int M, int N, int K,
                 int Asm, int Ask, int Bsk, int Bsn, float alpha,
                 const float* cd, int beta, int elu) {
    gemm64_k<<<dim3(M / 64, N / 64), 256, 0, stream>>>(A, B, C, M, N, K, Asm, Ask, Bsk, Bsn,
                                                       alpha, cd, beta, elu);
  };
  auto g128 = [&](const float* A, const float* B, float* C, int M, int N, int K,
                  int Asm, int Ask, int Bsk, int Bsn, float alpha,
                  const float* cd, int beta, int elu) {
    gemm128_k<<<dim3(M / 128, N / 128), 256, 0, stream>>>(A, B, C, M, N, K, Asm, Ask, Bsk, Bsn,
                                                          alpha, cd, beta, elu);
  };
  auto gbt = [&](const unsigned short* A, const unsigned short* B, float* C, const float* Cin,
                 int M, int N, int K, const float* cd, int beta) {
    gemm_bt_bf16<<<dim3(M / 128, N / 128), 256, 0, stream>>>(A, B, C, Cin, M, N, K, cd, beta);
  };
  auto cvt = [&](const float* in, unsigned short* o, long n) {
    cvt_bf16_k<<<(int)(n / 2048), 256, 0, stream>>>(in, o, n);
  };

  // projections
  g64(x, W_he, h_he, Nn, Dd, Dd, Dd, 1, Dd, 1, 1.f, nullptr, 0, 0);
  g64(x, W_n, hn, Nn, Dd, Dd, Dd, 1, Dd, 1, 1.f, nullptr, 0, 0);
  g64(x, W_g, h_g, Nn, Dd, Dd, Dd, 1, Dd, 1, 1.f, nullptr, 0, 0);
  rowdots_k<<<Nn, 256, 0, stream>>>(h_he, h_g, u, a_g, esc, s1, s2);
  // A column softmax
  colstats_k<<<dim3(Ee / 256, 32), 256, 0, stream>>>(H, esc, colden, cnt);
  fillA_k<<<(Nn * Ee) / 1024, 256, 0, stream>>>(H, esc, colden, Abuf);
  // e_repr = A^T @ h_he ; he = e_repr @ W_e
  g64(Abuf, h_he, e_repr, Ee, Dd, Nn, 1, Ee, Dd, 1, 1.f, nullptr, 0, 0);
  g64(e_repr, W_e, heb, Ee, Dd, Dd, Dd, 1, Dd, 1, 1.f, nullptr, 0, 0);
  // B = rowsoftmax(mask(hn @ he^T / 16))
  g128(hn, heb, Bbuf, Nn, Ee, Dd, Dd, 1, 1, Dd, 0.0625f, nullptr, 0, 0);
  brow_k<<<Nn, 256, 0, stream>>>(Bbuf, H);
  // G (normalized softmax)
  gfill_k<<<Nn, 256, 0, stream>>>(adj, s1, s2, G);

  if (use_mfma) {
    thbf_k<<<dim3(Nn / 64, Ee / 64), 256, 0, stream>>>(H, Hbt);
    cvt(G, Gb, (long)Nn * Nn);
    cvt(Abuf, Ab2, (long)Nn * Ee);
    cvt(Bbuf, Bb2, (long)Nn * Ee);
    // M = (G @ H) / he_sz
    gbt(Gb, Hbt, Mm, nullptr, Nn, Ee, Nn, cnt, 0);
    // G += B B^T ; G += A A^T
    gbt(Bb2, Bb2, G, G, Nn, Nn, Ee, nullptr, 1);
    gbt(Ab2, Ab2, G, G, Nn, Nn, Ee, nullptr, 1);
  } else {
    g128(G, H, Mm, Nn, Ee, Nn, Nn, 1, Ee, 1, 1.f, cnt, 0, 0);
    g128(Bbuf, Bbuf, G, Nn, Nn, Ee, Ee, 1, 1, Ee, 1.f, nullptr, 1, 0);
    g128(Abuf, Abuf, G, Nn, Nn, Ee, Ee, 1, 1, Ee, 1.f, nullptr, 1, 0);
  }

  // A_hat
  amstats_k<<<dim3(Ee / 256, 32), 256, 0, stream>>>(Abuf, Mm, aden);
  ahat_k<<<dim3(Nn / 64, Ee / 64), 256, 0, stream>>>(Abuf, Mm, H, aden, Ahat);
  // e_mix = A_hat @ h_he ; tmp_ew = e_mix @ W_e
  g64(Ahat, h_he, e_mix, Ee, Dd, Nn, Nn, 1, Dd, 1, 1.f, nullptr, 0, 0);
  g64(e_mix, W_e, tmp_ew, Ee, Dd, Dd, Dd, 1, Dd, 1, 1.f, nullptr, 0, 0);
  // B_hat, z_h
  bhat_k<<<Nn, 256, 0, stream>>>(Bbuf, Mm, H);
  g64(Bbuf, tmp_ew, out, Nn, Dd, Ee, Ee, 1, Dd, 1, 1.f, nullptr, 0, 1);
  // G_hat, z_g
  ghat_k<<<Nn, 256, 0, stream>>>(G);
  g64(G, h_g, out + (size_t)Nn * Dd, Nn, Dd, Nn, Nn, 1, Dd, 1, 1.f, nullptr, 0, 1);
}

// Round 3
// 839.778 us; speedup vs baseline: 3.2387x; 2.0089x over previous
//
#include <hip/hip_runtime.h>
#include <math.h>
#include <stdint.h>

#define Nn 4096
#define Ee 1024
#define Dd 256

typedef __attribute__((ext_vector_type(8))) __bf16 bf16x8;
typedef __attribute__((ext_vector_type(4))) float f32x4;
typedef __attribute__((ext_vector_type(8))) unsigned short u16x8;

__device__ __forceinline__ unsigned short f2bf(float f) {
  unsigned int u = __float_as_uint(f);
  unsigned int r = (u + 0x7fffu + ((u >> 16) & 1u)) >> 16;
  return (unsigned short)r;
}

__device__ __forceinline__ void gload_lds16(const void* g, void* l) {
  __builtin_amdgcn_global_load_lds(
      (__attribute__((address_space(1))) void*)const_cast<void*>(g),
      (__attribute__((address_space(3))) void*)l, 16, 0, 0);
}

// ---------------- block reduce (256 threads) ----------------
__device__ __forceinline__ float block_reduce_sum(float v) {
  __shared__ float sh[4];
  #pragma unroll
  for (int o = 32; o > 0; o >>= 1) v += __shfl_down(v, o);
  int lane = threadIdx.x & 63, w = threadIdx.x >> 6;
  if (lane == 0) sh[w] = v;
  __syncthreads();
  float s = sh[0] + sh[1] + sh[2] + sh[3];
  __syncthreads();
  return s;
}

// ---------------- bf16 MFMA GEMM: C = A * B^T, 128x128 tile, BK=32 ----------------
__global__ __launch_bounds__(256) void gemm_bt_bf16(
    const unsigned short* __restrict__ Ab,   // [M][K] bf16
    const unsigned short* __restrict__ Bb,   // [N][K] bf16
    float* __restrict__ Cp, const float* __restrict__ Cin,
    int M, int N, int K,
    const float* __restrict__ coldiv, int beta)
{
  __shared__ unsigned short As[2][128 * 32];
  __shared__ unsigned short Bs[2][128 * 32];
  const int tid = threadIdx.x;
  const int m0 = blockIdx.x * 128, n0 = blockIdx.y * 128;
  const int wave = tid >> 6, lane = tid & 63;
  const int wr = (wave >> 1) * 64, wc = (wave & 1) * 64;
  const int l16 = lane & 15, lq = lane >> 4;
  f32x4 acc[4][4] = {};
  const int NT = K >> 5;

  auto stage = [&](int buf, int kt) {
    const int k0 = kt * 32;
    #pragma unroll
    for (int i = 0; i < 2; ++i) {
      int t2 = tid + i * 256;
      int r = t2 >> 2, c = (t2 & 3) * 8;
      gload_lds16(Ab + (size_t)(m0 + r) * K + k0 + c, &As[buf][t2 * 8]);
    }
    #pragma unroll
    for (int i = 0; i < 2; ++i) {
      int t2 = tid + i * 256;
      int r = t2 >> 2, c = (t2 & 3) * 8;
      gload_lds16(Bb + (size_t)(n0 + r) * K + k0 + c, &Bs[buf][t2 * 8]);
    }
  };

  stage(0, 0);
  __syncthreads();
  int buf = 0;
  for (int kt = 0; kt < NT; ++kt) {
    if (kt + 1 < NT) stage(buf ^ 1, kt + 1);
    bf16x8 af[4], bfr[4];
    #pragma unroll
    for (int m = 0; m < 4; ++m)
      af[m] = *reinterpret_cast<const bf16x8*>(&As[buf][(wr + m * 16 + l16) * 32 + lq * 8]);
    #pragma unroll
    for (int n = 0; n < 4; ++n)
      bfr[n] = *reinterpret_cast<const bf16x8*>(&Bs[buf][(wc + n * 16 + l16) * 32 + lq * 8]);
    #pragma unroll
    for (int m = 0; m < 4; ++m)
      #pragma unroll
      for (int n = 0; n < 4; ++n)
        acc[m][n] = __builtin_amdgcn_mfma_f32_16x16x32_bf16(af[m], bfr[n], acc[m][n], 0, 0, 0);
    __syncthreads();
    buf ^= 1;
  }
  #pragma unroll
  for (int m = 0; m < 4; ++m) {
    #pragma unroll
    for (int n = 0; n < 4; ++n) {
      int col = n0 + wc + n * 16 + l16;
      float cd = coldiv ? fmaxf(coldiv[col], 1.f) : 1.f;
      #pragma unroll
      for (int q = 0; q < 4; ++q) {
        int row = m0 + wr + m * 16 + lq * 4 + q;
        size_t idx = (size_t)row * N + col;
        float v = acc[m][n][q];
        if (coldiv) v /= cd;
        if (beta) v += Cin[idx];
        Cp[idx] = v;
      }
    }
  }
}

// ---------------- bf16 MFMA GEMM, 64x64 tile, BK=64, split-K via atomicAdd ----------------
// C must be pre-zeroed. grid = (M/64, N/64, K/KS)
__global__ __launch_bounds__(256) void gemm64s_bt_bf16(
    const unsigned short* __restrict__ Ab,   // [M][K] bf16
    const unsigned short* __restrict__ Bb,   // [N][K] bf16
    float* __restrict__ Cp, int M, int N, int K, int KS)
{
  __shared__ unsigned short As[2][64 * 64];
  __shared__ unsigned short Bs[2][64 * 64];
  const int tid = threadIdx.x;
  const int m0 = blockIdx.x * 64, n0 = blockIdx.y * 64;
  const int kbase = blockIdx.z * KS;
  const int wave = tid >> 6, lane = tid & 63;
  const int wr = (wave >> 1) * 32, wc = (wave & 1) * 32;
  const int l16 = lane & 15, lq = lane >> 4;
  f32x4 acc[2][2] = {};
  const int NT = KS >> 6;

  auto stage = [&](int buf, int kt) {
    const int k0 = kbase + kt * 64;
    #pragma unroll
    for (int i = 0; i < 2; ++i) {
      int t2 = tid + i * 256;
      int r = t2 >> 3, c = (t2 & 7) * 8;
      gload_lds16(Ab + (size_t)(m0 + r) * K + k0 + c, &As[buf][t2 * 8]);
    }
    #pragma unroll
    for (int i = 0; i < 2; ++i) {
      int t2 = tid + i * 256;
      int r = t2 >> 3, c = (t2 & 7) * 8;
      gload_lds16(Bb + (size_t)(n0 + r) * K + k0 + c, &Bs[buf][t2 * 8]);
    }
  };

  stage(0, 0);
  __syncthreads();
  int buf = 0;
  for (int kt = 0; kt < NT; ++kt) {
    if (kt + 1 < NT) stage(buf ^ 1, kt + 1);
    bf16x8 af[2][2], bfr[2][2];
    #pragma unroll
    for (int m = 0; m < 2; ++m)
      #pragma unroll
      for (int ks = 0; ks < 2; ++ks)
        af[m][ks] = *reinterpret_cast<const bf16x8*>(
            &As[buf][(wr + m * 16 + l16) * 64 + ks * 32 + lq * 8]);
    #pragma unroll
    for (int n = 0; n < 2; ++n)
      #pragma unroll
      for (int ks = 0; ks < 2; ++ks)
        bfr[n][ks] = *reinterpret_cast<const bf16x8*>(
            &Bs[buf][(wc + n * 16 + l16) * 64 + ks * 32 + lq * 8]);
    #pragma unroll
    for (int m = 0; m < 2; ++m)
      #pragma unroll
      for (int n = 0; n < 2; ++n)
        #pragma unroll
        for (int ks = 0; ks < 2; ++ks)
          acc[m][n] = __builtin_amdgcn_mfma_f32_16x16x32_bf16(af[m][ks], bfr[n][ks], acc[m][n], 0, 0, 0);
    __syncthreads();
    buf ^= 1;
  }
  #pragma unroll
  for (int m = 0; m < 2; ++m)
    #pragma unroll
    for (int n = 0; n < 2; ++n) {
      int col = n0 + wc + n * 16 + l16;
      #pragma unroll
      for (int q = 0; q < 4; ++q) {
        int row = m0 + wr + m * 16 + lq * 4 + q;
        atomicAdd(&Cp[(size_t)row * N + col], acc[m][n][q]);
      }
    }
}

// ---------------- f32 -> bf16 convert ----------------
__global__ __launch_bounds__(256) void cvt_bf16_k(const float* __restrict__ in,
                                                  unsigned short* __restrict__ out, long n) {
  long i = ((long)blockIdx.x * 256 + threadIdx.x) * 8;
  if (i + 8 > n) return;
  float4 a = *reinterpret_cast<const float4*>(&in[i]);
  float4 b = *reinterpret_cast<const float4*>(&in[i + 4]);
  u16x8 o;
  o[0] = f2bf(a.x); o[1] = f2bf(a.y); o[2] = f2bf(a.z); o[3] = f2bf(a.w);
  o[4] = f2bf(b.x); o[5] = f2bf(b.y); o[6] = f2bf(b.z); o[7] = f2bf(b.w);
  *reinterpret_cast<u16x8*>(&out[i]) = o;
}

// ---------------- transpose-convert f32 [R][C] -> bf16 [C][R] ----------------
__global__ __launch_bounds__(256) void tcvt_k(const float* __restrict__ in,
                                              unsigned short* __restrict__ outT, int R, int C) {
  __shared__ unsigned short tile[64][65];
  int r0 = blockIdx.x * 64, c0 = blockIdx.y * 64;
  int t = threadIdx.x & 63, q = threadIdx.x >> 6;
  for (int rr = q; rr < 64; rr += 4)
    tile[t][rr] = f2bf(in[(long)(r0 + rr) * C + c0 + t]);
  __syncthreads();
  for (int cc = q; cc < 64; cc += 4)
    outT[(long)(c0 + cc) * R + r0 + t] = tile[cc][t];
}

// ---------------- elu elementwise ----------------
__global__ __launch_bounds__(256) void elu_k(float* __restrict__ p, long n) {
  long i = ((long)blockIdx.x * 256 + threadIdx.x) * 4;
  if (i + 4 > n) return;
  float4 v = *reinterpret_cast<const float4*>(&p[i]);
  v.x = v.x > 0.f ? v.x : expm1f(v.x);
  v.y = v.y > 0.f ? v.y : expm1f(v.y);
  v.z = v.z > 0.f ? v.z : expm1f(v.z);
  v.w = v.w > 0.f ? v.w : expm1f(v.w);
  *reinterpret_cast<float4*>(&p[i]) = v;
}

// ---------------- generic strided GEMM, 64x64 tile (f32) ----------------
__global__ __launch_bounds__(256) void gemm64_k(
    const float* __restrict__ Ap, const float* __restrict__ Bp, float* __restrict__ Cp,
    int M, int N, int K, int Asm, int Ask, int Bsk, int Bsn,
    float alpha, const float* __restrict__ coldiv, int beta, int do_elu)
{
  __shared__ alignas(16) float As[16][68];
  __shared__ alignas(16) float Bs[16][68];
  const int tid = threadIdx.x;
  const int tx = tid & 15, ty = tid >> 4;
  const int m0 = blockIdx.x * 64, n0 = blockIdx.y * 64;
  float acc[4][4] = {};
  for (int k0 = 0; k0 < K; k0 += 16) {
    if (Ask == 1) {
      int mm = tid >> 2, kk = (tid & 3) << 2;
      float4 v = *reinterpret_cast<const float4*>(&Ap[(long)(m0 + mm) * Asm + k0 + kk]);
      As[kk + 0][mm] = v.x; As[kk + 1][mm] = v.y; As[kk + 2][mm] = v.z; As[kk + 3][mm] = v.w;
    } else {
      int kk = tid >> 4, mm = (tid & 15) << 2;
      *reinterpret_cast<float4*>(&As[kk][mm]) =
          *reinterpret_cast<const float4*>(&Ap[(long)(k0 + kk) * Ask + m0 + mm]);
    }
    if (Bsn == 1) {
      int kk = tid >> 4, nn = (tid & 15) << 2;
      *reinterpret_cast<float4*>(&Bs[kk][nn]) =
          *reinterpret_cast<const float4*>(&Bp[(long)(k0 + kk) * Bsk + n0 + nn]);
    } else {
      int nn = tid >> 2, kk = (tid & 3) << 2;
      float4 v = *reinterpret_cast<const float4*>(&Bp[(long)(n0 + nn) * Bsn + k0 + kk]);
      Bs[kk + 0][nn] = v.x; Bs[kk + 1][nn] = v.y; Bs[kk + 2][nn] = v.z; Bs[kk + 3][nn] = v.w;
    }
    __syncthreads();
    #pragma unroll
    for (int kk = 0; kk < 16; ++kk) {
      float4 av = *reinterpret_cast<const float4*>(&As[kk][ty << 2]);
      float4 bv = *reinterpret_cast<const float4*>(&Bs[kk][tx << 2]);
      float a[4] = {av.x, av.y, av.z, av.w};
      float b[4] = {bv.x, bv.y, bv.z, bv.w};
      #pragma unroll
      for (int r = 0; r < 4; ++r)
        #pragma unroll
        for (int c = 0; c < 4; ++c) acc[r][c] = fmaf(a[r], b[c], acc[r][c]);
    }
    __syncthreads();
  }
  #pragma unroll
  for (int r = 0; r < 4; ++r) {
    int row = m0 + (ty << 2) + r;
    int col = n0 + (tx << 2);
    long base = (long)row * N + col;
    float vv[4];
    #pragma unroll
    for (int c = 0; c < 4; ++c) vv[c] = acc[r][c] * alpha;
    if (coldiv) {
      #pragma unroll
      for (int c = 0; c < 4; ++c) vv[c] /= fmaxf(coldiv[col + c], 1.f);
    }
    if (beta) {
      float4 p = *reinterpret_cast<const float4*>(&Cp[base]);
      vv[0] += p.x; vv[1] += p.y; vv[2] += p.z; vv[3] += p.w;
    }
    if (do_elu) {
      #pragma unroll
      for (int c = 0; c < 4; ++c) vv[c] = vv[c] > 0.f ? vv[c] : expm1f(vv[c]);
    }
    float4 o = {vv[0], vv[1], vv[2], vv[3]};
    *reinterpret_cast<float4*>(&Cp[base]) = o;
  }
}

// ---------------- generic strided GEMM, 128x128 tile (f32) ----------------
__global__ __launch_bounds__(256) void gemm128_k(
    const float* __restrict__ Ap, const float* __restrict__ Bp, float* __restrict__ Cp,
    int M, int N, int K, int Asm, int Ask, int Bsk, int Bsn,
    float alpha, const float* __restrict__ coldiv, int beta, int do_elu)
{
  __shared__ alignas(16) float As[16][132];
  __shared__ alignas(16) float Bs[16][132];
  const int tid = threadIdx.x;
  const int tx = tid & 15, ty = tid >> 4;
  const int m0 = blockIdx.x * 128, n0 = blockIdx.y * 128;
  float acc[2][2][4][4] = {};
  for (int k0 = 0; k0 < K; k0 += 16) {
    if (Ask == 1) {
      int mm = tid >> 2, kk = (tid & 3) << 2;
      #pragma unroll
      for (int h = 0; h < 2; ++h) {
        float4 v = *reinterpret_cast<const float4*>(&Ap[(long)(m0 + mm + 64 * h) * Asm + k0 + kk]);
        As[kk + 0][mm + 64 * h] = v.x; As[kk + 1][mm + 64 * h] = v.y;
        As[kk + 2][mm + 64 * h] = v.z; As[kk + 3][mm + 64 * h] = v.w;
      }
    } else {
      int kk = tid >> 4, mm = (tid & 15) << 2;
      #pragma unroll
      for (int h = 0; h < 2; ++h)
        *reinterpret_cast<float4*>(&As[kk][mm + 64 * h]) =
            *reinterpret_cast<const float4*>(&Ap[(long)(k0 + kk) * Ask + m0 + mm + 64 * h]);
    }
    if (Bsn == 1) {
      int kk = tid >> 4, nn = (tid & 15) << 2;
      #pragma unroll
      for (int h = 0; h < 2; ++h)
        *reinterpret_cast<float4*>(&Bs[kk][nn + 64 * h]) =
            *reinterpret_cast<const float4*>(&Bp[(long)(k0 + kk) * Bsk + n0 + nn + 64 * h]);
    } else {
      int nn = tid >> 2, kk = (tid & 3) << 2;
      #pragma unroll
      for (int h = 0; h < 2; ++h) {
        float4 v = *reinterpret_cast<const float4*>(&Bp[(long)(n0 + nn + 64 * h) * Bsn + k0 + kk]);
        Bs[kk + 0][nn + 64 * h] = v.x; Bs[kk + 1][nn + 64 * h] = v.y;
        Bs[kk + 2][nn + 64 * h] = v.z; Bs[kk + 3][nn + 64 * h] = v.w;
      }
    }
    __syncthreads();
    #pragma unroll
    for (int kk = 0; kk < 16; ++kk) {
      float a[2][4], b[2][4];
      #pragma unroll
      for (int h = 0; h < 2; ++h) {
        float4 av = *reinterpret_cast<const float4*>(&As[kk][(ty << 2) + 64 * h]);
        a[h][0] = av.x; a[h][1] = av.y; a[h][2] = av.z; a[h][3] = av.w;
        float4 bv = *reinterpret_cast<const float4*>(&Bs[kk][(tx << 2) + 64 * h]);
        b[h][0] = bv.x; b[h][1] = bv.y; b[h][2] = bv.z; b[h][3] = bv.w;
      }
      #pragma unroll
      for (int i = 0; i < 2; ++i)
        #pragma unroll
        for (int j = 0; j < 2; ++j)
          #pragma unroll
          for (int r = 0; r < 4; ++r)
            #pragma unroll
            for (int c = 0; c < 4; ++c)
              acc[i][j][r][c] = fmaf(a[i][r], b[j][c], acc[i][j][r][c]);
    }
    __syncthreads();
  }
  #pragma unroll
  for (int i = 0; i < 2; ++i) {
    #pragma unroll
    for (int r = 0; r < 4; ++r) {
      int row = m0 + 64 * i + (ty << 2) + r;
      #pragma unroll
      for (int j = 0; j < 2; ++j) {
        int col = n0 + 64 * j + (tx << 2);
        long base = (long)row * N + col;
        float vv[4];
        #pragma unroll
        for (int c = 0; c < 4; ++c) vv[c] = acc[i][j][r][c] * alpha;
        if (coldiv) {
          #pragma unroll
          for (int c = 0; c < 4; ++c) vv[c] /= fmaxf(coldiv[col + c], 1.f);
        }
        if (beta) {
          float4 p = *reinterpret_cast<const float4*>(&Cp[base]);
          vv[0] += p.x; vv[1] += p.y; vv[2] += p.z; vv[3] += p.w;
        }
        if (do_elu) {
          #pragma unroll
          for (int c = 0; c < 4; ++c) vv[c] = vv[c] > 0.f ? vv[c] : expm1f(vv[c]);
        }
        float4 o = {vv[0], vv[1], vv[2], vv[3]};
        *reinterpret_cast<float4*>(&Cp[base]) = o;
      }
    }
  }
}

// ---------------- sc/s1/s2 row dots ----------------
__global__ __launch_bounds__(256) void rowdots_k(
    const float* __restrict__ h_he, const float* __restrict__ h_g,
    const float* __restrict__ u, const float* __restrict__ a_g,
    float* __restrict__ esc, float* __restrict__ s1, float* __restrict__ s2)
{
  int i = blockIdx.x, t = threadIdx.x;
  float hh = h_he[(long)i * Dd + t];
  float hg = h_g[(long)i * Dd + t];
  float d0 = block_reduce_sum(hh * u[t]);
  float d1 = block_reduce_sum(hg * a_g[t]);
  float d2 = block_reduce_sum(hg * a_g[Dd + t]);
  if (t == 0) {
    esc[i] = expf(d0 * 0.0625f);
    s1[i] = d1;
    s2[i] = d2;
  }
}

// ---------------- column softmax stats for A ----------------
__global__ __launch_bounds__(256) void colstats_k(
    const float* __restrict__ H, const float* __restrict__ esc,
    float* __restrict__ colden, float* __restrict__ cnt)
{
  int e = blockIdx.x * 256 + threadIdx.x;
  int r0 = blockIdx.y * 128;
  float d = 0.f, c = 0.f;
  for (int r = r0; r < r0 + 128; ++r) {
    float h = H[(long)r * Ee + e];
    if (h > 0.f) { d += esc[r]; c += 1.f; }
  }
  atomicAdd(&colden[e], d);
  atomicAdd(&cnt[e], c);
}

// ---------------- A = maskH * exp(sc)/colden ----------------
__global__ __launch_bounds__(256) void fillA_k(
    const float* __restrict__ H, const float* __restrict__ esc,
    const float* __restrict__ colden, float* __restrict__ A)
{
  long base = ((long)blockIdx.x * 256 + threadIdx.x) * 4;
  int r = (int)(base >> 10);
  int e = (int)(base & 1023);
  float4 h = *reinterpret_cast<const float4*>(&H[base]);
  float4 cd = *reinterpret_cast<const float4*>(&colden[e]);
  float er = esc[r];
  float4 o;
  o.x = h.x > 0.f ? er / cd.x : 0.f;
  o.y = h.y > 0.f ? er / cd.y : 0.f;
  o.z = h.z > 0.f ? er / cd.z : 0.f;
  o.w = h.w > 0.f ? er / cd.w : 0.f;
  *reinterpret_cast<float4*>(&A[base]) = o;
}

// ---------------- B row softmax ----------------
__global__ __launch_bounds__(256) void brow_k(float* __restrict__ Bbuf,
                                              const float* __restrict__ H)
{
  int i = blockIdx.x, t = threadIdx.x;
  long base = (long)i * Ee + t * 4;
  float4 raw = *reinterpret_cast<const float4*>(&Bbuf[base]);
  float4 h = *reinterpret_cast<const float4*>(&H[base]);
  float rr[4] = {raw.x, raw.y, raw.z, raw.w}, hh[4] = {h.x, h.y, h.z, h.w};
  float p[4]; float s = 0.f;
  #pragma unroll
  for (int k = 0; k < 4; ++k) { p[k] = hh[k] > 0.f ? expf(rr[k]) : 0.f; s += p[k]; }
  float den = block_reduce_sum(s);
  float inv = den > 0.f ? 1.f / den : 0.f;
  float4 o = {p[0] * inv, p[1] * inv, p[2] * inv, p[3] * inv};
  *reinterpret_cast<float4*>(&Bbuf[base]) = o;
}

// ---------------- G fill ----------------
__global__ __launch_bounds__(256) void gfill_k(
    const float* __restrict__ adj, const float* __restrict__ s1,
    const float* __restrict__ s2, float* __restrict__ G)
{
  int i = blockIdx.x, t = threadIdx.x;
  float s1i = s1[i];
  float p[16]; float sum = 0.f;
  #pragma unroll
  for (int c = 0; c < 4; ++c) {
    int j = c * 1024 + t * 4;
    float4 a = *reinterpret_cast<const float4*>(&adj[(long)i * Nn + j]);
    float4 sv = *reinterpret_cast<const float4*>(&s2[j]);
    float aa[4] = {a.x, a.y, a.z, a.w}, ss[4] = {sv.x, sv.y, sv.z, sv.w};
    #pragma unroll
    for (int k = 0; k < 4; ++k) {
      float f = (aa[k] > 0.f ? 1.f : 0.f) + ((j + k) == i ? 1.f : 0.f);
      float l = s1i + ss[k];
      l = l > 0.f ? l : 0.2f * l;
      float val = l * f - 1e9f * fmaxf(1.f - f, 0.f);
      float pp = expf(val);
      p[c * 4 + k] = pp; sum += pp;
    }
  }
  float den = block_reduce_sum(sum);
  float inv = 1.f / den;
  #pragma unroll
  for (int c = 0; c < 4; ++c) {
    int j = c * 1024 + t * 4;
    float4 o = {p[c * 4] * inv, p[c * 4 + 1] * inv, p[c * 4 + 2] * inv, p[c * 4 + 3] * inv};
    *reinterpret_cast<float4*>(&G[(long)i * Nn + j]) = o;
  }
}

// ---------------- A_hat denominators ----------------
__global__ __launch_bounds__(256) void amstats_k(
    const float* __restrict__ A, const float* __restrict__ Mm, float* __restrict__ aden)
{
  int e = blockIdx.x * 256 + threadIdx.x;
  int r0 = blockIdx.y * 128;
  float d = 0.f;
  for (int r = r0; r < r0 + 128; ++r) {
    long idx = (long)r * Ee + e;
    d += expf(A[idx] + Mm[idx]);
  }
  atomicAdd(&aden[e], d);
}

// ---------------- A_hat fill (transpose to [E,N]) ----------------
__global__ __launch_bounds__(256) void ahat_k(
    const float* __restrict__ Abuf, const float* __restrict__ Mm,
    const float* __restrict__ H, const float* __restrict__ aden, float* __restrict__ Ahat)
{
  __shared__ float tile[64][65];
  int j0 = blockIdx.x * 64, e0 = blockIdx.y * 64;
  int te = threadIdx.x & 63;
  int tq = threadIdx.x >> 6;
  int e = e0 + te;
  float inv = 1.f / aden[e];
  for (int jj = tq; jj < 64; jj += 4) {
    long idx = (long)(j0 + jj) * Ee + e;
    float val = (H[idx] > 0.f) ? expf(Abuf[idx] + Mm[idx]) * inv : 0.f;
    tile[te][jj] = val;
  }
  __syncthreads();
  for (int ee = tq; ee < 64; ee += 4) {
    Ahat[(long)(e0 + ee) * Nn + j0 + te] = tile[ee][te];
  }
}

// ---------------- B_hat ----------------
__global__ __launch_bounds__(256) void bhat_k(float* __restrict__ Bbuf,
                                              const float* __restrict__ Mm,
                                              const float* __restrict__ H)
{
  int i = blockIdx.x, t = threadIdx.x;
  long base = (long)i * Ee + t * 4;
  float4 b = *reinterpret_cast<const float4*>(&Bbuf[base]);
  float4 m = *reinterpret_cast<const float4*>(&Mm[base]);
  float4 h = *reinterpret_cast<const float4*>(&H[base]);
  float bb[4] = {b.x, b.y, b.z, b.w}, mm2[4] = {m.x, m.y, m.z, m.w}, hh[4] = {h.x, h.y, h.z, h.w};
  float p[4]; float s = 0.f;
  #pragma unroll
  for (int k = 0; k < 4; ++k) { p[k] = expf(bb[k] + mm2[k]); s += p[k]; }
  float den = block_reduce_sum(s);
  float inv = 1.f / den;
  #pragma unroll
  for (int k = 0; k < 4; ++k) p[k] = hh[k] > 0.f ? p[k] * inv : 0.f;
  float4 o = {p[0], p[1], p[2], p[3]};
  *reinterpret_cast<float4*>(&Bbuf[base]) = o;
}

// ---------------- G_hat row softmax ----------------
__global__ __launch_bounds__(256) void ghat_k(float* __restrict__ G)
{
  int i = blockIdx.x, t = threadIdx.x;
  float p[16]; float s = 0.f;
  #pragma unroll
  for (int c = 0; c < 4; ++c) {
    long base = (long)i * Nn + c * 1024 + t * 4;
    float4 v = *reinterpret_cast<const float4*>(&G[base]);
    float vv[4] = {v.x, v.y, v.z, v.w};
    #pragma unroll
    for (int k = 0; k < 4; ++k) { float pe = expf(vv[k]); p[c * 4 + k] = pe; s += pe; }
  }
  float den = block_reduce_sum(s);
  float inv = 1.f / den;
  #pragma unroll
  for (int c = 0; c < 4; ++c) {
    long base = (long)i * Nn + c * 1024 + t * 4;
    float4 o = {p[c * 4] * inv, p[c * 4 + 1] * inv, p[c * 4 + 2] * inv, p[c * 4 + 3] * inv};
    *reinterpret_cast<float4*>(&G[base]) = o;
  }
}

// ---------------- launcher ----------------
extern "C" void kernel_launch(void* const* d_in, const int* in_sizes, int n_in,
                              void* d_out, int out_size, void* d_ws, size_t ws_size,
                              hipStream_t stream) {
  const float* x    = (const float*)d_in[0];
  const float* H    = (const float*)d_in[1];
  const float* adj  = (const float*)d_in[2];
  const float* W_he = (const float*)d_in[3];
  const float* u    = (const float*)d_in[4];
  const float* W_e  = (const float*)d_in[5];
  const float* W_n  = (const float*)d_in[6];
  const float* W_g  = (const float*)d_in[7];
  const float* a_g  = (const float*)d_in[8];
  float* out = (float*)d_out;
  float* ws  = (float*)d_ws;

  size_t off = 0;
  auto alloc = [&](size_t n) { float* p = ws + off; off += n; return p; };
  float* h_he   = alloc((size_t)Nn * Dd);
  float* hn     = alloc((size_t)Nn * Dd);
  float* h_g    = alloc((size_t)Nn * Dd);
  float* esc    = alloc(Nn);
  float* s1     = alloc(Nn);
  float* s2     = alloc(Nn);
  float* colden = alloc(Ee);
  float* cnt    = alloc(Ee);
  float* aden   = alloc(Ee);
  float* e_repr = alloc((size_t)Ee * Dd);   // e_repr & e_mix contiguous: one memset
  float* e_mix  = alloc((size_t)Ee * Dd);
  float* heb    = alloc((size_t)Ee * Dd);
  float* tmp_ew = alloc((size_t)Ee * Dd);
  float* Abuf   = alloc((size_t)Nn * Ee);
  float* Bbuf   = alloc((size_t)Nn * Ee);
  float* Mm     = alloc((size_t)Nn * Ee);
  float* Ahat   = alloc((size_t)Ee * Nn);
  float* G      = alloc((size_t)Nn * Nn);
  // bf16 scratch
  unsigned short* Gb   = (unsigned short*)alloc((size_t)Nn * Nn / 2);
  unsigned short* Hbt  = (unsigned short*)alloc((size_t)Ee * Nn / 2);
  unsigned short* Ab2  = (unsigned short*)alloc((size_t)Nn * Ee / 2);
  unsigned short* Bb2  = (unsigned short*)alloc((size_t)Nn * Ee / 2);
  unsigned short* AbT  = (unsigned short*)alloc((size_t)Ee * Nn / 2);  // A^T bf16 [Ee][Nn]
  unsigned short* AhB  = (unsigned short*)alloc((size_t)Ee * Nn / 2);  // A_hat bf16
  unsigned short* hheT = (unsigned short*)alloc((size_t)Dd * Nn / 2);  // h_he^T bf16 [Dd][Nn]
  unsigned short* hgT  = (unsigned short*)alloc((size_t)Dd * Nn / 2);  // h_g^T bf16
  unsigned short* tewT = (unsigned short*)alloc((size_t)Dd * Ee / 2);  // tmp_ew^T bf16 [Dd][Ee]
  size_t need_bytes = off * sizeof(float);
  const bool use_mfma = ws_size >= need_bytes;
  (void)in_sizes; (void)n_in; (void)out_size;

  hipMemsetAsync(colden, 0, 3 * Ee * sizeof(float), stream);
  if (use_mfma) {
    hipMemsetAsync(e_repr, 0, 2 * (size_t)Ee * Dd * sizeof(float), stream);
    hipMemsetAsync(out, 0, 2 * (size_t)Nn * Dd * sizeof(float), stream);
  }

  auto g64 = [&](const float* A, const float* B, float* C, int M, int N, int K,
                 int Asm, int Ask, int Bsk, int Bsn, float alpha,
                 const float* cd, int beta, int elu) {
    gemm64_k<<<dim3(M / 64, N / 64), 256, 0, stream>>>(A, B, C, M, N, K, Asm, Ask, Bsk, Bsn,
                                                       alpha, cd, beta, elu);
  };
  auto g128 = [&](const float* A, const float* B, float* C, int M, int N, int K,
                  int Asm, int Ask, int Bsk, int Bsn, float alpha,
                  const float* cd, int beta, int elu) {
    gemm128_k<<<dim3(M / 128, N / 128), 256, 0, stream>>>(A, B, C, M, N, K, Asm, Ask, Bsk, Bsn,
                                                          alpha, cd, beta, elu);
  };
  auto gbt = [&](const unsigned short* A, const unsigned short* B, float* C, const float* Cin,
                 int M, int N, int K, const float* cd, int beta) {
    gemm_bt_bf16<<<dim3(M / 128, N / 128), 256, 0, stream>>>(A, B, C, Cin, M, N, K, cd, beta);
  };
  auto gs64 = [&](const unsigned short* A, const unsigned short* B, float* C,
                  int M, int N, int K, int KS) {
    gemm64s_bt_bf16<<<dim3(M / 64, N / 64, K / KS), 256, 0, stream>>>(A, B, C, M, N, K, KS);
  };
  auto cvt = [&](const float* in, unsigned short* o, long n) {
    cvt_bf16_k<<<(int)(n / 2048), 256, 0, stream>>>(in, o, n);
  };
  auto tcvt = [&](const float* in, unsigned short* o, int R, int C) {
    tcvt_k<<<dim3(R / 64, C / 64), 256, 0, stream>>>(in, o, R, C);
  };

  // projections (f32)
  g64(x, W_he, h_he, Nn, Dd, Dd, Dd, 1, Dd, 1, 1.f, nullptr, 0, 0);
  g64(x, W_n, hn, Nn, Dd, Dd, Dd, 1, Dd, 1, 1.f, nullptr, 0, 0);
  g64(x, W_g, h_g, Nn, Dd, Dd, Dd, 1, Dd, 1, 1.f, nullptr, 0, 0);
  rowdots_k<<<Nn, 256, 0, stream>>>(h_he, h_g, u, a_g, esc, s1, s2);
  // A column softmax
  colstats_k<<<dim3(Ee / 256, 32), 256, 0, stream>>>(H, esc, colden, cnt);
  fillA_k<<<(Nn * Ee) / 1024, 256, 0, stream>>>(H, esc, colden, Abuf);

  if (use_mfma) {
    // e_repr = A^T @ h_he  (bf16 MFMA, split-K=4)
    tcvt(Abuf, AbT, Nn, Ee);
    tcvt(h_he, hheT, Nn, Dd);
    gs64(AbT, hheT, e_repr, Ee, Dd, Nn, 1024);
  } else {
    g64(Abuf, h_he, e_repr, Ee, Dd, Nn, 1, Ee, Dd, 1, 1.f, nullptr, 0, 0);
  }
  g64(e_repr, W_e, heb, Ee, Dd, Dd, Dd, 1, Dd, 1, 1.f, nullptr, 0, 0);
  // B = rowsoftmax(mask(hn @ he^T / 16))  (f32)
  g128(hn, heb, Bbuf, Nn, Ee, Dd, Dd, 1, 1, Dd, 0.0625f, nullptr, 0, 0);
  brow_k<<<Nn, 256, 0, stream>>>(Bbuf, H);
  // G (normalized softmax)
  gfill_k<<<Nn, 256, 0, stream>>>(adj, s1, s2, G);

  if (use_mfma) {
    tcvt(H, Hbt, Nn, Ee);
    cvt(G, Gb, (long)Nn * Nn);
    cvt(Abuf, Ab2, (long)Nn * Ee);
    cvt(Bbuf, Bb2, (long)Nn * Ee);
    gbt(Gb, Hbt, Mm, nullptr, Nn, Ee, Nn, cnt, 0);     // M = (G @ H) / he_sz
    gbt(Bb2, Bb2, G, G, Nn, Nn, Ee, nullptr, 1);       // G += B B^T
    gbt(Ab2, Ab2, G, G, Nn, Nn, Ee, nullptr, 1);       // G += A A^T
  } else {
    g128(G, H, Mm, Nn, Ee, Nn, Nn, 1, Ee, 1, 1.f, cnt, 0, 0);
    g128(Bbuf, Bbuf, G, Nn, Nn, Ee, Ee, 1, 1, Ee, 1.f, nullptr, 1, 0);
    g128(Abuf, Abuf, G, Nn, Nn, Ee, Ee, 1, 1, Ee, 1.f, nullptr, 1, 0);
  }

  // A_hat
  amstats_k<<<dim3(Ee / 256, 32), 256, 0, stream>>>(Abuf, Mm, aden);
  ahat_k<<<dim3(Nn / 64, Ee / 64), 256, 0, stream>>>(Abuf, Mm, H, aden, Ahat);

  if (use_mfma) {
    // e_mix = A_hat @ h_he (bf16 MFMA, split-K=4)
    cvt(Ahat, AhB, (long)Ee * Nn);
    gs64(AhB, hheT, e_mix, Ee, Dd, Nn, 1024);
  } else {
    g64(Ahat, h_he, e_mix, Ee, Dd, Nn, Nn, 1, Dd, 1, 1.f, nullptr, 0, 0);
  }
  g64(e_mix, W_e, tmp_ew, Ee, Dd, Dd, Dd, 1, Dd, 1, 1.f, nullptr, 0, 0);
  // B_hat, z_h
  bhat_k<<<Nn, 256, 0, stream>>>(Bbuf, Mm, H);
  if (use_mfma) {
    tcvt(tmp_ew, tewT, Ee, Dd);
    cvt(Bbuf, Bb2, (long)Nn * Ee);                    // B_hat bf16 (reuse Bb2)
    gs64(Bb2, tewT, out, Nn, Dd, Ee, Ee);             // z_h (pre-elu)
  } else {
    g64(Bbuf, tmp_ew, out, Nn, Dd, Ee, Ee, 1, Dd, 1, 1.f, nullptr, 0, 1);
  }
  // G_hat, z_g
  ghat_k<<<Nn, 256, 0, stream>>>(G);
  if (use_mfma) {
    cvt(G, Gb, (long)Nn * Nn);                        // G_hat bf16 (reuse Gb)
    tcvt(h_g, hgT, Nn, Dd);
    gs64(Gb, hgT, out + (size_t)Nn * Dd, Nn, Dd, Nn, 2048);  // z_g (pre-elu)
    elu_k<<<(2 * Nn * Dd) / 1024, 256, 0, stream>>>(out, 2L * Nn * Dd);
  } else {
    g64(G, h_g, out + (size_t)Nn * Dd, Nn, Dd, Nn, Nn, 1, Dd, 1, 1.f, nullptr, 0, 1);
  }
}

// Round 4
// 710.918 us; speedup vs baseline: 3.8258x; 1.1813x over previous
//
#include <hip/hip_runtime.h>
#include <math.h>
#include <stdint.h>

#define Nn 4096
#define Ee 1024
#define Dd 256

typedef __attribute__((ext_vector_type(8))) __bf16 bf16x8;
typedef __attribute__((ext_vector_type(4))) float f32x4;
typedef __attribute__((ext_vector_type(8))) unsigned short u16x8;

__device__ __forceinline__ unsigned short f2bf(float f) {
  unsigned int u = __float_as_uint(f);
  unsigned int r = (u + 0x7fffu + ((u >> 16) & 1u)) >> 16;
  return (unsigned short)r;
}

__device__ __forceinline__ void gload_lds16(const void* g, void* l) {
  __builtin_amdgcn_global_load_lds(
      (__attribute__((address_space(1))) void*)const_cast<void*>(g),
      (__attribute__((address_space(3))) void*)l, 16, 0, 0);
}

__device__ __forceinline__ float block_reduce_sum(float v) {
  __shared__ float sh[4];
  #pragma unroll
  for (int o = 32; o > 0; o >>= 1) v += __shfl_down(v, o);
  int lane = threadIdx.x & 63, w = threadIdx.x >> 6;
  if (lane == 0) sh[w] = v;
  __syncthreads();
  float s = sh[0] + sh[1] + sh[2] + sh[3];
  __syncthreads();
  return s;
}

// ---------------- bf16 MFMA GEMM: C = A * B^T, 128x128 tile, BK=32 (M-gemm) ----------------
__global__ __launch_bounds__(256) void gemm_bt_bf16(
    const unsigned short* __restrict__ Ab, const unsigned short* __restrict__ Bb,
    float* __restrict__ Cp, int M, int N, int K, const float* __restrict__ coldiv)
{
  __shared__ unsigned short As[2][128 * 32];
  __shared__ unsigned short Bs[2][128 * 32];
  const int tid = threadIdx.x;
  const int m0 = blockIdx.x * 128, n0 = blockIdx.y * 128;
  const int wave = tid >> 6, lane = tid & 63;
  const int wr = (wave >> 1) * 64, wc = (wave & 1) * 64;
  const int l16 = lane & 15, lq = lane >> 4;
  f32x4 acc[4][4] = {};
  const int NT = K >> 5;

  auto stage = [&](int buf, int kt) {
    const int k0 = kt * 32;
    #pragma unroll
    for (int i = 0; i < 2; ++i) {
      int t2 = tid + i * 256;
      int r = t2 >> 2, c = (t2 & 3) * 8;
      gload_lds16(Ab + (size_t)(m0 + r) * K + k0 + c, &As[buf][t2 * 8]);
    }
    #pragma unroll
    for (int i = 0; i < 2; ++i) {
      int t2 = tid + i * 256;
      int r = t2 >> 2, c = (t2 & 3) * 8;
      gload_lds16(Bb + (size_t)(n0 + r) * K + k0 + c, &Bs[buf][t2 * 8]);
    }
  };

  stage(0, 0);
  __syncthreads();
  int buf = 0;
  for (int kt = 0; kt < NT; ++kt) {
    if (kt + 1 < NT) stage(buf ^ 1, kt + 1);
    bf16x8 af[4], bfr[4];
    #pragma unroll
    for (int m = 0; m < 4; ++m)
      af[m] = *reinterpret_cast<const bf16x8*>(&As[buf][(wr + m * 16 + l16) * 32 + lq * 8]);
    #pragma unroll
    for (int n = 0; n < 4; ++n)
      bfr[n] = *reinterpret_cast<const bf16x8*>(&Bs[buf][(wc + n * 16 + l16) * 32 + lq * 8]);
    #pragma unroll
    for (int m = 0; m < 4; ++m)
      #pragma unroll
      for (int n = 0; n < 4; ++n)
        acc[m][n] = __builtin_amdgcn_mfma_f32_16x16x32_bf16(af[m], bfr[n], acc[m][n], 0, 0, 0);
    __syncthreads();
    buf ^= 1;
  }
  #pragma unroll
  for (int m = 0; m < 4; ++m)
    #pragma unroll
    for (int n = 0; n < 4; ++n) {
      int col = n0 + wc + n * 16 + l16;
      float cd = coldiv ? fmaxf(coldiv[col], 1.f) : 1.f;
      #pragma unroll
      for (int q = 0; q < 4; ++q) {
        int row = m0 + wr + m * 16 + lq * 4 + q;
        Cp[(size_t)row * N + col] = acc[m][n][q] / cd;
      }
    }
}

// ---------------- fused Gram: expG = exp(G + CAT*CAT^T), rowsum atomics ----------------
__global__ __launch_bounds__(256) void gemm_gram_k(
    const unsigned short* __restrict__ CAT,   // [Nn][2048] bf16
    float* __restrict__ G,                    // in: logits G; out: exp(logit)
    float* __restrict__ rowsum)               // pre-zeroed [Nn]
{
  const int K = 2048, N = Nn;
  __shared__ unsigned short As[2][128 * 32];
  __shared__ unsigned short Bs[2][128 * 32];
  const int tid = threadIdx.x;
  const int m0 = blockIdx.x * 128, n0 = blockIdx.y * 128;
  const int wave = tid >> 6, lane = tid & 63;
  const int wr = (wave >> 1) * 64, wc = (wave & 1) * 64;
  const int l16 = lane & 15, lq = lane >> 4;
  f32x4 acc[4][4] = {};
  const int NT = K >> 5;

  auto stage = [&](int buf, int kt) {
    const int k0 = kt * 32;
    #pragma unroll
    for (int i = 0; i < 2; ++i) {
      int t2 = tid + i * 256;
      int r = t2 >> 2, c = (t2 & 3) * 8;
      gload_lds16(CAT + (size_t)(m0 + r) * K + k0 + c, &As[buf][t2 * 8]);
    }
    #pragma unroll
    for (int i = 0; i < 2; ++i) {
      int t2 = tid + i * 256;
      int r = t2 >> 2, c = (t2 & 3) * 8;
      gload_lds16(CAT + (size_t)(n0 + r) * K + k0 + c, &Bs[buf][t2 * 8]);
    }
  };

  stage(0, 0);
  __syncthreads();
  int buf = 0;
  for (int kt = 0; kt < NT; ++kt) {
    if (kt + 1 < NT) stage(buf ^ 1, kt + 1);
    bf16x8 af[4], bfr[4];
    #pragma unroll
    for (int m = 0; m < 4; ++m)
      af[m] = *reinterpret_cast<const bf16x8*>(&As[buf][(wr + m * 16 + l16) * 32 + lq * 8]);
    #pragma unroll
    for (int n = 0; n < 4; ++n)
      bfr[n] = *reinterpret_cast<const bf16x8*>(&Bs[buf][(wc + n * 16 + l16) * 32 + lq * 8]);
    #pragma unroll
    for (int m = 0; m < 4; ++m)
      #pragma unroll
      for (int n = 0; n < 4; ++n)
        acc[m][n] = __builtin_amdgcn_mfma_f32_16x16x32_bf16(af[m], bfr[n], acc[m][n], 0, 0, 0);
    __syncthreads();
    buf ^= 1;
  }
  // epilogue: v = G + gram; expv -> G; rowsum += expv
  #pragma unroll
  for (int m = 0; m < 4; ++m)
    #pragma unroll
    for (int q = 0; q < 4; ++q) {
      int row = m0 + wr + m * 16 + lq * 4 + q;
      float s = 0.f;
      #pragma unroll
      for (int n = 0; n < 4; ++n) {
        int col = n0 + wc + n * 16 + l16;
        size_t idx = (size_t)row * N + col;
        float e = expf(G[idx] + acc[m][n][q]);
        G[idx] = e;
        s += e;
      }
      s += __shfl_xor(s, 1); s += __shfl_xor(s, 2);
      s += __shfl_xor(s, 4); s += __shfl_xor(s, 8);
      if (l16 == 0) atomicAdd(&rowsum[row], s);
    }
}

// ---------------- bf16 MFMA GEMM, 64x64 tile, BK=64, split-K via atomicAdd ----------------
__global__ __launch_bounds__(256) void gemm64s_bt_bf16(
    const unsigned short* __restrict__ Ab, const unsigned short* __restrict__ Bb,
    float* __restrict__ Cp, int M, int N, int K, int KS)
{
  __shared__ unsigned short As[2][64 * 64];
  __shared__ unsigned short Bs[2][64 * 64];
  const int tid = threadIdx.x;
  const int m0 = blockIdx.x * 64, n0 = blockIdx.y * 64;
  const int kbase = blockIdx.z * KS;
  const int wave = tid >> 6, lane = tid & 63;
  const int wr = (wave >> 1) * 32, wc = (wave & 1) * 32;
  const int l16 = lane & 15, lq = lane >> 4;
  f32x4 acc[2][2] = {};
  const int NT = KS >> 6;

  auto stage = [&](int buf, int kt) {
    const int k0 = kbase + kt * 64;
    #pragma unroll
    for (int i = 0; i < 2; ++i) {
      int t2 = tid + i * 256;
      int r = t2 >> 3, c = (t2 & 7) * 8;
      gload_lds16(Ab + (size_t)(m0 + r) * K + k0 + c, &As[buf][t2 * 8]);
    }
    #pragma unroll
    for (int i = 0; i < 2; ++i) {
      int t2 = tid + i * 256;
      int r = t2 >> 3, c = (t2 & 7) * 8;
      gload_lds16(Bb + (size_t)(n0 + r) * K + k0 + c, &Bs[buf][t2 * 8]);
    }
  };

  stage(0, 0);
  __syncthreads();
  int buf = 0;
  for (int kt = 0; kt < NT; ++kt) {
    if (kt + 1 < NT) stage(buf ^ 1, kt + 1);
    bf16x8 af[2][2], bfr[2][2];
    #pragma unroll
    for (int m = 0; m < 2; ++m)
      #pragma unroll
      for (int ks = 0; ks < 2; ++ks)
        af[m][ks] = *reinterpret_cast<const bf16x8*>(
            &As[buf][(wr + m * 16 + l16) * 64 + ks * 32 + lq * 8]);
    #pragma unroll
    for (int n = 0; n < 2; ++n)
      #pragma unroll
      for (int ks = 0; ks < 2; ++ks)
        bfr[n][ks] = *reinterpret_cast<const bf16x8*>(
            &Bs[buf][(wc + n * 16 + l16) * 64 + ks * 32 + lq * 8]);
    #pragma unroll
    for (int m = 0; m < 2; ++m)
      #pragma unroll
      for (int n = 0; n < 2; ++n)
        #pragma unroll
        for (int ks = 0; ks < 2; ++ks)
          acc[m][n] = __builtin_amdgcn_mfma_f32_16x16x32_bf16(af[m][ks], bfr[n][ks], acc[m][n], 0, 0, 0);
    __syncthreads();
    buf ^= 1;
  }
  #pragma unroll
  for (int m = 0; m < 2; ++m)
    #pragma unroll
    for (int n = 0; n < 2; ++n) {
      int col = n0 + wc + n * 16 + l16;
      #pragma unroll
      for (int q = 0; q < 4; ++q) {
        int row = m0 + wr + m * 16 + lq * 4 + q;
        atomicAdd(&Cp[(size_t)row * N + col], acc[m][n][q]);
      }
    }
}

// ---------------- transpose-convert f32 [R][S-strided] block -> bf16 [C][R] ----------------
__global__ __launch_bounds__(256) void tcvt_k(const float* __restrict__ in,
                                              unsigned short* __restrict__ outT, int R, int S) {
  __shared__ unsigned short tile[64][65];
  int r0 = blockIdx.x * 64, c0 = blockIdx.y * 64;
  int t = threadIdx.x & 63, q = threadIdx.x >> 6;
  for (int rr = q; rr < 64; rr += 4)
    tile[t][rr] = f2bf(in[(long)(r0 + rr) * S + c0 + t]);
  __syncthreads();
  for (int cc = q; cc < 64; cc += 4)
    outT[(long)(c0 + cc) * R + r0 + t] = tile[cc][t];
}

// ---------------- elu ----------------
__global__ __launch_bounds__(256) void elu_k(float* __restrict__ p, long n) {
  long i = ((long)blockIdx.x * 256 + threadIdx.x) * 4;
  if (i + 4 > n) return;
  float4 v = *reinterpret_cast<const float4*>(&p[i]);
  v.x = v.x > 0.f ? v.x : expm1f(v.x);
  v.y = v.y > 0.f ? v.y : expm1f(v.y);
  v.z = v.z > 0.f ? v.z : expm1f(v.z);
  v.w = v.w > 0.f ? v.w : expm1f(v.w);
  *reinterpret_cast<float4*>(&p[i]) = v;
}

// ---------------- W concat: Wcat[k][s*256+j] = W_s[k][j] ----------------
__global__ __launch_bounds__(256) void wcat_k(const float* __restrict__ W0,
                                              const float* __restrict__ W1,
                                              const float* __restrict__ W2,
                                              float* __restrict__ Wcat) {
  int k = blockIdx.x, s = blockIdx.y, t = threadIdx.x;
  const float* W = s == 0 ? W0 : (s == 1 ? W1 : W2);
  Wcat[(long)k * 768 + s * 256 + t] = W[(long)k * 256 + t];
}

// ---------------- generic strided f32 GEMM, 64x64 tile ----------------
__global__ __launch_bounds__(256) void gemm64_k(
    const float* __restrict__ Ap, const float* __restrict__ Bp, float* __restrict__ Cp,
    int M, int N, int K, int Asm, int Ask, int Bsk, int Bsn)
{
  __shared__ alignas(16) float As[16][68];
  __shared__ alignas(16) float Bs[16][68];
  const int tid = threadIdx.x;
  const int tx = tid & 15, ty = tid >> 4;
  const int m0 = blockIdx.x * 64, n0 = blockIdx.y * 64;
  float acc[4][4] = {};
  for (int k0 = 0; k0 < K; k0 += 16) {
    if (Ask == 1) {
      int mm = tid >> 2, kk = (tid & 3) << 2;
      float4 v = *reinterpret_cast<const float4*>(&Ap[(long)(m0 + mm) * Asm + k0 + kk]);
      As[kk + 0][mm] = v.x; As[kk + 1][mm] = v.y; As[kk + 2][mm] = v.z; As[kk + 3][mm] = v.w;
    } else {
      int kk = tid >> 4, mm = (tid & 15) << 2;
      *reinterpret_cast<float4*>(&As[kk][mm]) =
          *reinterpret_cast<const float4*>(&Ap[(long)(k0 + kk) * Ask + m0 + mm]);
    }
    if (Bsn == 1) {
      int kk = tid >> 4, nn = (tid & 15) << 2;
      *reinterpret_cast<float4*>(&Bs[kk][nn]) =
          *reinterpret_cast<const float4*>(&Bp[(long)(k0 + kk) * Bsk + n0 + nn]);
    } else {
      int nn = tid >> 2, kk = (tid & 3) << 2;
      float4 v = *reinterpret_cast<const float4*>(&Bp[(long)(n0 + nn) * Bsn + k0 + kk]);
      Bs[kk + 0][nn] = v.x; Bs[kk + 1][nn] = v.y; Bs[kk + 2][nn] = v.z; Bs[kk + 3][nn] = v.w;
    }
    __syncthreads();
    #pragma unroll
    for (int kk = 0; kk < 16; ++kk) {
      float4 av = *reinterpret_cast<const float4*>(&As[kk][ty << 2]);
      float4 bv = *reinterpret_cast<const float4*>(&Bs[kk][tx << 2]);
      float a[4] = {av.x, av.y, av.z, av.w};
      float b[4] = {bv.x, bv.y, bv.z, bv.w};
      #pragma unroll
      for (int r = 0; r < 4; ++r)
        #pragma unroll
        for (int c = 0; c < 4; ++c) acc[r][c] = fmaf(a[r], b[c], acc[r][c]);
    }
    __syncthreads();
  }
  #pragma unroll
  for (int r = 0; r < 4; ++r) {
    long base = (long)(m0 + (ty << 2) + r) * N + n0 + (tx << 2);
    float4 o = {acc[r][0], acc[r][1], acc[r][2], acc[r][3]};
    *reinterpret_cast<float4*>(&Cp[base]) = o;
  }
}

// ---------------- f32 128x128 GEMM (Bsc logits only) ----------------
__global__ __launch_bounds__(256) void gemm128_k(
    const float* __restrict__ Ap, const float* __restrict__ Bp, float* __restrict__ Cp,
    int M, int N, int K, int Asm, int Bsn, float alpha)
{
  __shared__ alignas(16) float As[16][132];
  __shared__ alignas(16) float Bs[16][132];
  const int tid = threadIdx.x;
  const int tx = tid & 15, ty = tid >> 4;
  const int m0 = blockIdx.x * 128, n0 = blockIdx.y * 128;
  float acc[2][2][4][4] = {};
  for (int k0 = 0; k0 < K; k0 += 16) {
    {
      int mm = tid >> 2, kk = (tid & 3) << 2;
      #pragma unroll
      for (int h = 0; h < 2; ++h) {
        float4 v = *reinterpret_cast<const float4*>(&Ap[(long)(m0 + mm + 64 * h) * Asm + k0 + kk]);
        As[kk + 0][mm + 64 * h] = v.x; As[kk + 1][mm + 64 * h] = v.y;
        As[kk + 2][mm + 64 * h] = v.z; As[kk + 3][mm + 64 * h] = v.w;
      }
    }
    {
      int nn = tid >> 2, kk = (tid & 3) << 2;
      #pragma unroll
      for (int h = 0; h < 2; ++h) {
        float4 v = *reinterpret_cast<const float4*>(&Bp[(long)(n0 + nn + 64 * h) * Bsn + k0 + kk]);
        Bs[kk + 0][nn + 64 * h] = v.x; Bs[kk + 1][nn + 64 * h] = v.y;
        Bs[kk + 2][nn + 64 * h] = v.z; Bs[kk + 3][nn + 64 * h] = v.w;
      }
    }
    __syncthreads();
    #pragma unroll
    for (int kk = 0; kk < 16; ++kk) {
      float a[2][4], b[2][4];
      #pragma unroll
      for (int h = 0; h < 2; ++h) {
        float4 av = *reinterpret_cast<const float4*>(&As[kk][(ty << 2) + 64 * h]);
        a[h][0] = av.x; a[h][1] = av.y; a[h][2] = av.z; a[h][3] = av.w;
        float4 bv = *reinterpret_cast<const float4*>(&Bs[kk][(tx << 2) + 64 * h]);
        b[h][0] = bv.x; b[h][1] = bv.y; b[h][2] = bv.z; b[h][3] = bv.w;
      }
      #pragma unroll
      for (int i = 0; i < 2; ++i)
        #pragma unroll
        for (int j = 0; j < 2; ++j)
          #pragma unroll
          for (int r = 0; r < 4; ++r)
            #pragma unroll
            for (int c = 0; c < 4; ++c)
              acc[i][j][r][c] = fmaf(a[i][r], b[j][c], acc[i][j][r][c]);
    }
    __syncthreads();
  }
  #pragma unroll
  for (int i = 0; i < 2; ++i)
    #pragma unroll
    for (int r = 0; r < 4; ++r) {
      int row = m0 + 64 * i + (ty << 2) + r;
      #pragma unroll
      for (int j = 0; j < 2; ++j) {
        long base = (long)row * N + n0 + 64 * j + (tx << 2);
        float4 o = {acc[i][j][r][0] * alpha, acc[i][j][r][1] * alpha,
                    acc[i][j][r][2] * alpha, acc[i][j][r][3] * alpha};
        *reinterpret_cast<float4*>(&Cp[base]) = o;
      }
    }
}

// ---------------- sc/s1/s2 row dots (hcat stride 768) ----------------
__global__ __launch_bounds__(256) void rowdots_k(
    const float* __restrict__ hcat, const float* __restrict__ u, const float* __restrict__ a_g,
    float* __restrict__ esc, float* __restrict__ s1, float* __restrict__ s2)
{
  int i = blockIdx.x, t = threadIdx.x;
  float hh = hcat[(long)i * 768 + t];
  float hg = hcat[(long)i * 768 + 512 + t];
  float d0 = block_reduce_sum(hh * u[t]);
  float d1 = block_reduce_sum(hg * a_g[t]);
  float d2 = block_reduce_sum(hg * a_g[Dd + t]);
  if (t == 0) {
    esc[i] = expf(d0 * 0.0625f);
    s1[i] = d1;
    s2[i] = d2;
  }
}

// ---------------- column softmax stats for A ----------------
__global__ __launch_bounds__(256) void colstats_k(
    const float* __restrict__ H, const float* __restrict__ esc,
    float* __restrict__ colden, float* __restrict__ cnt)
{
  int e = blockIdx.x * 256 + threadIdx.x;
  int r0 = blockIdx.y * 128;
  float d = 0.f, c = 0.f;
  for (int r = r0; r < r0 + 128; ++r) {
    float h = H[(long)r * Ee + e];
    if (h > 0.f) { d += esc[r]; c += 1.f; }
  }
  atomicAdd(&colden[e], d);
  atomicAdd(&cnt[e], c);
}

// ---------------- A fill: Abuf f32 + CAT A-half bf16 ----------------
__global__ __launch_bounds__(256) void fillA_k(
    const float* __restrict__ H, const float* __restrict__ esc,
    const float* __restrict__ colden, float* __restrict__ A,
    unsigned short* __restrict__ CAT)
{
  long base = ((long)blockIdx.x * 256 + threadIdx.x) * 4;
  int r = (int)(base >> 10);
  int e = (int)(base & 1023);
  float4 h = *reinterpret_cast<const float4*>(&H[base]);
  float4 cd = *reinterpret_cast<const float4*>(&colden[e]);
  float er = esc[r];
  float4 o;
  o.x = h.x > 0.f ? er / cd.x : 0.f;
  o.y = h.y > 0.f ? er / cd.y : 0.f;
  o.z = h.z > 0.f ? er / cd.z : 0.f;
  o.w = h.w > 0.f ? er / cd.w : 0.f;
  *reinterpret_cast<float4*>(&A[base]) = o;
  ushort4 ob = {f2bf(o.x), f2bf(o.y), f2bf(o.z), f2bf(o.w)};
  *reinterpret_cast<ushort4*>(&CAT[(long)r * 2048 + 1024 + e]) = ob;
}

// ---------------- B row softmax: Bbuf in place + CAT B-half bf16 ----------------
__global__ __launch_bounds__(256) void brow_k(float* __restrict__ Bbuf,
                                              const float* __restrict__ H,
                                              unsigned short* __restrict__ CAT)
{
  int i = blockIdx.x, t = threadIdx.x;
  long base = (long)i * Ee + t * 4;
  float4 raw = *reinterpret_cast<const float4*>(&Bbuf[base]);
  float4 h = *reinterpret_cast<const float4*>(&H[base]);
  float rr[4] = {raw.x, raw.y, raw.z, raw.w}, hh[4] = {h.x, h.y, h.z, h.w};
  float p[4]; float s = 0.f;
  #pragma unroll
  for (int k = 0; k < 4; ++k) { p[k] = hh[k] > 0.f ? expf(rr[k]) : 0.f; s += p[k]; }
  float den = block_reduce_sum(s);
  float inv = den > 0.f ? 1.f / den : 0.f;
  float4 o = {p[0] * inv, p[1] * inv, p[2] * inv, p[3] * inv};
  *reinterpret_cast<float4*>(&Bbuf[base]) = o;
  ushort4 ob = {f2bf(o.x), f2bf(o.y), f2bf(o.z), f2bf(o.w)};
  *reinterpret_cast<ushort4*>(&CAT[(long)i * 2048 + t * 4]) = ob;
}

// ---------------- G fill: G f32 + Gb bf16 ----------------
__global__ __launch_bounds__(256) void gfill_k(
    const float* __restrict__ adj, const float* __restrict__ s1,
    const float* __restrict__ s2, float* __restrict__ G, unsigned short* __restrict__ Gb)
{
  int i = blockIdx.x, t = threadIdx.x;
  float s1i = s1[i];
  float p[16]; float sum = 0.f;
  #pragma unroll
  for (int c = 0; c < 4; ++c) {
    int j = c * 1024 + t * 4;
    float4 a = *reinterpret_cast<const float4*>(&adj[(long)i * Nn + j]);
    float4 sv = *reinterpret_cast<const float4*>(&s2[j]);
    float aa[4] = {a.x, a.y, a.z, a.w}, ss[4] = {sv.x, sv.y, sv.z, sv.w};
    #pragma unroll
    for (int k = 0; k < 4; ++k) {
      float f = (aa[k] > 0.f ? 1.f : 0.f) + ((j + k) == i ? 1.f : 0.f);
      float l = s1i + ss[k];
      l = l > 0.f ? l : 0.2f * l;
      float val = l * f - 1e9f * fmaxf(1.f - f, 0.f);
      float pp = expf(val);
      p[c * 4 + k] = pp; sum += pp;
    }
  }
  float den = block_reduce_sum(sum);
  float inv = 1.f / den;
  #pragma unroll
  for (int c = 0; c < 4; ++c) {
    int j = c * 1024 + t * 4;
    float4 o = {p[c * 4] * inv, p[c * 4 + 1] * inv, p[c * 4 + 2] * inv, p[c * 4 + 3] * inv};
    *reinterpret_cast<float4*>(&G[(long)i * Nn + j]) = o;
    ushort4 ob = {f2bf(o.x), f2bf(o.y), f2bf(o.z), f2bf(o.w)};
    *reinterpret_cast<ushort4*>(&Gb[(long)i * Nn + j]) = ob;
  }
}

// ---------------- G_hat finalize: Gb = bf16(expG * 1/rowsum) ----------------
__global__ __launch_bounds__(256) void gscale_k(const float* __restrict__ expG,
                                                const float* __restrict__ rowsum,
                                                unsigned short* __restrict__ Gb)
{
  long i = ((long)blockIdx.x * 256 + threadIdx.x) * 8;
  int row = (int)(i >> 12);
  float inv = 1.f / rowsum[row];
  float4 a = *reinterpret_cast<const float4*>(&expG[i]);
  float4 b = *reinterpret_cast<const float4*>(&expG[i + 4]);
  u16x8 o;
  o[0] = f2bf(a.x * inv); o[1] = f2bf(a.y * inv); o[2] = f2bf(a.z * inv); o[3] = f2bf(a.w * inv);
  o[4] = f2bf(b.x * inv); o[5] = f2bf(b.y * inv); o[6] = f2bf(b.z * inv); o[7] = f2bf(b.w * inv);
  *reinterpret_cast<u16x8*>(&Gb[i]) = o;
}

// ---------------- A_hat denominators ----------------
__global__ __launch_bounds__(256) void amstats_k(
    const float* __restrict__ A, const float* __restrict__ Mm, float* __restrict__ aden)
{
  int e = blockIdx.x * 256 + threadIdx.x;
  int r0 = blockIdx.y * 128;
  float d = 0.f;
  for (int r = r0; r < r0 + 128; ++r) {
    long idx = (long)r * Ee + e;
    d += expf(A[idx] + Mm[idx]);
  }
  atomicAdd(&aden[e], d);
}

// ---------------- A_hat fill (transpose, bf16 out) ----------------
__global__ __launch_bounds__(256) void ahat_k(
    const float* __restrict__ Abuf, const float* __restrict__ Mm,
    const float* __restrict__ H, const float* __restrict__ aden,
    unsigned short* __restrict__ AhB)
{
  __shared__ float tile[64][65];
  int j0 = blockIdx.x * 64, e0 = blockIdx.y * 64;
  int te = threadIdx.x & 63;
  int tq = threadIdx.x >> 6;
  int e = e0 + te;
  float inv = 1.f / aden[e];
  for (int jj = tq; jj < 64; jj += 4) {
    long idx = (long)(j0 + jj) * Ee + e;
    float val = (H[idx] > 0.f) ? expf(Abuf[idx] + Mm[idx]) * inv : 0.f;
    tile[te][jj] = val;
  }
  __syncthreads();
  for (int ee = tq; ee < 64; ee += 4)
    AhB[(long)(e0 + ee) * Nn + j0 + te] = f2bf(tile[ee][te]);
}

// ---------------- B_hat: bf16 out ----------------
__global__ __launch_bounds__(256) void bhat_k(const float* __restrict__ Bbuf,
                                              const float* __restrict__ Mm,
                                              const float* __restrict__ H,
                                              unsigned short* __restrict__ Bb2)
{
  int i = blockIdx.x, t = threadIdx.x;
  long base = (long)i * Ee + t * 4;
  float4 b = *reinterpret_cast<const float4*>(&Bbuf[base]);
  float4 m = *reinterpret_cast<const float4*>(&Mm[base]);
  float4 h = *reinterpret_cast<const float4*>(&H[base]);
  float bb[4] = {b.x, b.y, b.z, b.w}, mm2[4] = {m.x, m.y, m.z, m.w}, hh[4] = {h.x, h.y, h.z, h.w};
  float p[4]; float s = 0.f;
  #pragma unroll
  for (int k = 0; k < 4; ++k) { p[k] = expf(bb[k] + mm2[k]); s += p[k]; }
  float den = block_reduce_sum(s);
  float inv = 1.f / den;
  #pragma unroll
  for (int k = 0; k < 4; ++k) p[k] = hh[k] > 0.f ? p[k] * inv : 0.f;
  ushort4 ob = {f2bf(p[0]), f2bf(p[1]), f2bf(p[2]), f2bf(p[3])};
  *reinterpret_cast<ushort4*>(&Bb2[base]) = ob;
}

// ---------------- launcher ----------------
extern "C" void kernel_launch(void* const* d_in, const int* in_sizes, int n_in,
                              void* d_out, int out_size, void* d_ws, size_t ws_size,
                              hipStream_t stream) {
  const float* x    = (const float*)d_in[0];
  const float* H    = (const float*)d_in[1];
  const float* adj  = (const float*)d_in[2];
  const float* W_he = (const float*)d_in[3];
  const float* u    = (const float*)d_in[4];
  const float* W_e  = (const float*)d_in[5];
  const float* W_n  = (const float*)d_in[6];
  const float* W_g  = (const float*)d_in[7];
  const float* a_g  = (const float*)d_in[8];
  float* out = (float*)d_out;
  float* ws  = (float*)d_ws;
  (void)in_sizes; (void)n_in; (void)out_size; (void)ws_size;

  size_t off = 0;
  auto alloc = [&](size_t n) { float* p = ws + off; off += n; return p; };
  float* hcat   = alloc((size_t)Nn * 768);   // [h_he | hn | h_g]
  float* Wcat   = alloc((size_t)Dd * 768);
  float* esc    = alloc(Nn);
  float* s1     = alloc(Nn);
  float* s2     = alloc(Nn);
  float* colden = alloc(Ee);   // colden,cnt,aden,rowsum contiguous -> one memset
  float* cnt    = alloc(Ee);
  float* aden   = alloc(Ee);
  float* rowsum = alloc(Nn);
  float* e_repr = alloc((size_t)Ee * Dd);    // e_repr,e_mix contiguous -> one memset
  float* e_mix  = alloc((size_t)Ee * Dd);
  float* heb    = alloc((size_t)Ee * Dd);
  float* tmp_ew = alloc((size_t)Ee * Dd);
  float* Abuf   = alloc((size_t)Nn * Ee);
  float* Bbuf   = alloc((size_t)Nn * Ee);
  float* Mm     = alloc((size_t)Nn * Ee);
  float* G      = alloc((size_t)Nn * Nn);
  unsigned short* Gb   = (unsigned short*)alloc((size_t)Nn * Nn / 2);
  unsigned short* CAT  = (unsigned short*)alloc((size_t)Nn * 2048 / 2);
  unsigned short* Hbt  = (unsigned short*)alloc((size_t)Ee * Nn / 2);
  unsigned short* AbT  = (unsigned short*)alloc((size_t)Ee * Nn / 2);
  unsigned short* AhB  = (unsigned short*)alloc((size_t)Ee * Nn / 2);
  unsigned short* hheT = (unsigned short*)alloc((size_t)Dd * Nn / 2);
  unsigned short* hgT  = (unsigned short*)alloc((size_t)Dd * Nn / 2);
  unsigned short* tewT = (unsigned short*)alloc((size_t)Dd * Ee / 2);
  unsigned short* Bb2  = (unsigned short*)alloc((size_t)Nn * Ee / 2);

  hipMemsetAsync(colden, 0, (3 * Ee + Nn) * sizeof(float), stream);
  hipMemsetAsync(e_repr, 0, 2 * (size_t)Ee * Dd * sizeof(float), stream);
  hipMemsetAsync(out, 0, 2 * (size_t)Nn * Dd * sizeof(float), stream);

  auto gs64 = [&](const unsigned short* A, const unsigned short* B, float* C,
                  int M, int N, int K, int KS) {
    gemm64s_bt_bf16<<<dim3(M / 64, N / 64, K / KS), 256, 0, stream>>>(A, B, C, M, N, K, KS);
  };
  auto tcvt = [&](const float* in, unsigned short* o, int R, int S, int cols) {
    tcvt_k<<<dim3(R / 64, cols / 64), 256, 0, stream>>>(in, o, R, S);
  };

  // fused projections: hcat = x @ [W_he|W_n|W_g]
  wcat_k<<<dim3(Dd, 3), 256, 0, stream>>>(W_he, W_n, W_g, Wcat);
  gemm64_k<<<dim3(Nn / 64, 768 / 64), 256, 0, stream>>>(x, Wcat, hcat, Nn, 768, Dd, Dd, 1, 768, 1);
  rowdots_k<<<Nn, 256, 0, stream>>>(hcat, u, a_g, esc, s1, s2);
  // A column softmax
  colstats_k<<<dim3(Ee / 256, 32), 256, 0, stream>>>(H, esc, colden, cnt);
  fillA_k<<<(Nn * Ee) / 1024, 256, 0, stream>>>(H, esc, colden, Abuf, CAT);
  // e_repr = A^T @ h_he
  tcvt(Abuf, AbT, Nn, Ee, Ee);
  tcvt(hcat, hheT, Nn, 768, Dd);
  gs64(AbT, hheT, e_repr, Ee, Dd, Nn, 1024);
  // heb = e_repr @ W_e
  gemm64_k<<<dim3(Ee / 64, Dd / 64), 256, 0, stream>>>(e_repr, W_e, heb, Ee, Dd, Dd, Dd, 1, Dd, 1);
  // B = rowsoftmax(mask(hn @ heb^T / 16))
  gemm128_k<<<dim3(Nn / 128, Ee / 128), 256, 0, stream>>>(hcat + 256, heb, Bbuf, Nn, Ee, Dd, 768, Dd, 0.0625f);
  brow_k<<<Nn, 256, 0, stream>>>(Bbuf, H, CAT);
  // G softmax (f32 + bf16)
  gfill_k<<<Nn, 256, 0, stream>>>(adj, s1, s2, G, Gb);
  // M = (G @ H) / he_sz
  tcvt(H, Hbt, Nn, Ee, Ee);
  gemm_bt_bf16<<<dim3(Nn / 128, Ee / 128), 256, 0, stream>>>(Gb, Hbt, Mm, Nn, Ee, Nn, cnt);
  // fused: expG = exp(G + BB^T + AA^T), rowsum
  gemm_gram_k<<<dim3(Nn / 128, Nn / 128), 256, 0, stream>>>(CAT, G, rowsum);
  gscale_k<<<(int)(((size_t)Nn * Nn) / 2048), 256, 0, stream>>>(G, rowsum, Gb);
  // A_hat
  amstats_k<<<dim3(Ee / 256, 32), 256, 0, stream>>>(Abuf, Mm, aden);
  ahat_k<<<dim3(Nn / 64, Ee / 64), 256, 0, stream>>>(Abuf, Mm, H, aden, AhB);
  // e_mix = A_hat @ h_he ; tmp_ew = e_mix @ W_e
  gs64(AhB, hheT, e_mix, Ee, Dd, Nn, 1024);
  gemm64_k<<<dim3(Ee / 64, Dd / 64), 256, 0, stream>>>(e_mix, W_e, tmp_ew, Ee, Dd, Dd, Dd, 1, Dd, 1);
  // B_hat, z_h
  bhat_k<<<Nn, 256, 0, stream>>>(Bbuf, Mm, H, Bb2);
  tcvt(tmp_ew, tewT, Ee, Dd, Dd);
  gs64(Bb2, tewT, out, Nn, Dd, Ee, Ee);
  // z_g
  tcvt(hcat + 512, hgT, Nn, 768, Dd);
  gs64(Gb, hgT, out + (size_t)Nn * Dd, Nn, Dd, Nn, 2048);
  elu_k<<<(2 * Nn * Dd) / 1024, 256, 0, stream>>>(out, 2L * Nn * Dd);
}

// Round 5
// 665.375 us; speedup vs baseline: 4.0877x; 1.0684x over previous
//
#include <hip/hip_runtime.h>
#include <math.h>
#include <stdint.h>

#define Nn 4096
#define Ee 1024
#define Dd 256

typedef __attribute__((ext_vector_type(8))) __bf16 bf16x8;
typedef __attribute__((ext_vector_type(4))) float f32x4;
typedef __attribute__((ext_vector_type(8))) unsigned short u16x8;

__device__ __forceinline__ unsigned short f2bf(float f) {
  unsigned int u = __float_as_uint(f);
  unsigned int r = (u + 0x7fffu + ((u >> 16) & 1u)) >> 16;
  return (unsigned short)r;
}
__device__ __forceinline__ float bf2f(unsigned short u) {
  return __uint_as_float(((unsigned int)u) << 16);
}

__device__ __forceinline__ void gload_lds16(const void* g, void* l) {
  __builtin_amdgcn_global_load_lds(
      (__attribute__((address_space(1))) void*)const_cast<void*>(g),
      (__attribute__((address_space(3))) void*)l, 16, 0, 0);
}

__device__ __forceinline__ float block_reduce_sum(float v) {
  __shared__ float sh[4];
  #pragma unroll
  for (int o = 32; o > 0; o >>= 1) v += __shfl_down(v, o);
  int lane = threadIdx.x & 63, w = threadIdx.x >> 6;
  if (lane == 0) sh[w] = v;
  __syncthreads();
  float s = sh[0] + sh[1] + sh[2] + sh[3];
  __syncthreads();
  return s;
}

// ---------------- bf16 MFMA GEMM: C = alpha*(A*B^T)[/coldiv], 128x128, BK=32 ----------------
// A: [M rows, lda stride] bf16 ; B: [N rows, ldb stride] bf16 ; C f32 [M][N] (+opt bf16 Cb)
__global__ __launch_bounds__(256) void gemm_bt_bf16(
    const unsigned short* __restrict__ Ab, const unsigned short* __restrict__ Bb,
    float* __restrict__ Cp, unsigned short* __restrict__ Cb,
    int M, int N, int K, int lda, int ldb, float alpha,
    const float* __restrict__ coldiv)
{
  __shared__ unsigned short As[2][128 * 32];
  __shared__ unsigned short Bs[2][128 * 32];
  const int tid = threadIdx.x;
  const int m0 = blockIdx.x * 128, n0 = blockIdx.y * 128;
  const int wave = tid >> 6, lane = tid & 63;
  const int wr = (wave >> 1) * 64, wc = (wave & 1) * 64;
  const int l16 = lane & 15, lq = lane >> 4;
  f32x4 acc[4][4] = {};
  const int NT = K >> 5;

  auto stage = [&](int buf, int kt) {
    const int k0 = kt * 32;
    #pragma unroll
    for (int i = 0; i < 2; ++i) {
      int t2 = tid + i * 256;
      int r = t2 >> 2, c = (t2 & 3) * 8;
      gload_lds16(Ab + (size_t)(m0 + r) * lda + k0 + c, &As[buf][t2 * 8]);
    }
    #pragma unroll
    for (int i = 0; i < 2; ++i) {
      int t2 = tid + i * 256;
      int r = t2 >> 2, c = (t2 & 3) * 8;
      gload_lds16(Bb + (size_t)(n0 + r) * ldb + k0 + c, &Bs[buf][t2 * 8]);
    }
  };

  stage(0, 0);
  __syncthreads();
  int buf = 0;
  for (int kt = 0; kt < NT; ++kt) {
    if (kt + 1 < NT) stage(buf ^ 1, kt + 1);
    bf16x8 af[4], bfr[4];
    #pragma unroll
    for (int m = 0; m < 4; ++m)
      af[m] = *reinterpret_cast<const bf16x8*>(&As[buf][(wr + m * 16 + l16) * 32 + lq * 8]);
    #pragma unroll
    for (int n = 0; n < 4; ++n)
      bfr[n] = *reinterpret_cast<const bf16x8*>(&Bs[buf][(wc + n * 16 + l16) * 32 + lq * 8]);
    #pragma unroll
    for (int m = 0; m < 4; ++m)
      #pragma unroll
      for (int n = 0; n < 4; ++n)
        acc[m][n] = __builtin_amdgcn_mfma_f32_16x16x32_bf16(af[m], bfr[n], acc[m][n], 0, 0, 0);
    __syncthreads();
    buf ^= 1;
  }
  #pragma unroll
  for (int m = 0; m < 4; ++m)
    #pragma unroll
    for (int n = 0; n < 4; ++n) {
      int col = n0 + wc + n * 16 + l16;
      float cd = coldiv ? fmaxf(coldiv[col], 1.f) : 1.f;
      #pragma unroll
      for (int q = 0; q < 4; ++q) {
        int row = m0 + wr + m * 16 + lq * 4 + q;
        size_t idx = (size_t)row * N + col;
        float v = acc[m][n][q] * alpha / cd;
        Cp[idx] = v;
        if (Cb) Cb[idx] = f2bf(v);
      }
    }
}

// ---------------- symmetric fused Gram: Gb = exp(G + CAT*CAT^T) (bf16), rowsum ----------------
// grid (32,32); blocks bx>by exit. Off-diag blocks write both (r,c) and (c,r) tiles;
// mirrored logits read from Gb (gfill's bf16 logits) via LDS transpose. Race-free:
// lower-triangle Gb region (R>C) is read+written only by block (C/128, R/128).
__global__ __launch_bounds__(256) void gemm_gram_k(
    const unsigned short* __restrict__ CAT,   // [Nn][2048] bf16
    const float* __restrict__ G,              // f32 logits (gfill)
    unsigned short* __restrict__ Gb,          // in: bf16 logits; out: exp(logit)
    float* __restrict__ rowsum)               // pre-zeroed [Nn]
{
  const int bx = blockIdx.x, by = blockIdx.y;
  if (bx > by) return;
  const int K = 2048;
  __shared__ unsigned short SM[17024];
  unsigned short* Asb = SM;          // [2][4096]
  unsigned short* Bsb = SM + 8192;   // [2][4096]
  const int tid = threadIdx.x;
  const int m0 = bx * 128, n0 = by * 128;
  const int wave = tid >> 6, lane = tid & 63;
  const int wr = (wave >> 1) * 64, wc = (wave & 1) * 64;
  const int l16 = lane & 15, lq = lane >> 4;
  f32x4 acc[4][4] = {};
  const int NT = K >> 5;

  auto stage = [&](int buf, int kt) {
    const int k0 = kt * 32;
    #pragma unroll
    for (int i = 0; i < 2; ++i) {
      int t2 = tid + i * 256;
      int r = t2 >> 2, c = (t2 & 3) * 8;
      gload_lds16(CAT + (size_t)(m0 + r) * K + k0 + c, Asb + buf * 4096 + t2 * 8);
    }
    #pragma unroll
    for (int i = 0; i < 2; ++i) {
      int t2 = tid + i * 256;
      int r = t2 >> 2, c = (t2 & 3) * 8;
      gload_lds16(CAT + (size_t)(n0 + r) * K + k0 + c, Bsb + buf * 4096 + t2 * 8);
    }
  };

  stage(0, 0);
  __syncthreads();
  int buf = 0;
  for (int kt = 0; kt < NT; ++kt) {
    if (kt + 1 < NT) stage(buf ^ 1, kt + 1);
    bf16x8 af[4], bfr[4];
    #pragma unroll
    for (int m = 0; m < 4; ++m)
      af[m] = *reinterpret_cast<const bf16x8*>(Asb + buf * 4096 + (wr + m * 16 + l16) * 32 + lq * 8);
    #pragma unroll
    for (int n = 0; n < 4; ++n)
      bfr[n] = *reinterpret_cast<const bf16x8*>(Bsb + buf * 4096 + (wc + n * 16 + l16) * 32 + lq * 8);
    #pragma unroll
    for (int m = 0; m < 4; ++m)
      #pragma unroll
      for (int n = 0; n < 4; ++n)
        acc[m][n] = __builtin_amdgcn_mfma_f32_16x16x32_bf16(af[m], bfr[n], acc[m][n], 0, 0, 0);
    __syncthreads();
    buf ^= 1;
  }
  // normal epilogue: rows m-panel, cols n-panel (upper/diag region)
  #pragma unroll
  for (int m = 0; m < 4; ++m)
    #pragma unroll
    for (int q = 0; q < 4; ++q) {
      int row = m0 + wr + m * 16 + lq * 4 + q;
      float s = 0.f;
      #pragma unroll
      for (int n = 0; n < 4; ++n) {
        int col = n0 + wc + n * 16 + l16;
        size_t idx = (size_t)row * Nn + col;
        float e = expf(G[idx] + acc[m][n][q]);
        Gb[idx] = f2bf(e);
        s += e;
      }
      s += __shfl_xor(s, 1); s += __shfl_xor(s, 2);
      s += __shfl_xor(s, 4); s += __shfl_xor(s, 8);
      if (l16 == 0) atomicAdd(&rowsum[row], s);
    }
  if (bx == by) return;

  // transposed epilogue: rows n-panel, cols m-panel (lower region)
  __syncthreads();
  unsigned short* Tg = SM;  // [128][132] bf16, reuses As/Bs space
  {
    int cc = tid >> 1, r0 = (tid & 1) * 64;
    const unsigned short* src = Gb + (size_t)(n0 + cc) * Nn + m0 + r0;
    unsigned short* dst = Tg + cc * 132 + r0;
    #pragma unroll
    for (int v = 0; v < 8; ++v)
      *reinterpret_cast<u16x8*>(dst + v * 8) = *reinterpret_cast<const u16x8*>(src + v * 8);
  }
  __syncthreads();
  #pragma unroll
  for (int n = 0; n < 4; ++n) {
    int ccl = wc + n * 16 + l16;
    float cs = 0.f;
    #pragma unroll
    for (int m = 0; m < 4; ++m) {
      int sa = ccl * 132 + wr + m * 16 + lq * 4;
      ushort4 lg = *reinterpret_cast<const ushort4*>(&Tg[sa]);
      ushort4 eo;
      float e0 = expf(bf2f(lg.x) + acc[m][n][0]); eo.x = f2bf(e0); cs += e0;
      float e1 = expf(bf2f(lg.y) + acc[m][n][1]); eo.y = f2bf(e1); cs += e1;
      float e2 = expf(bf2f(lg.z) + acc[m][n][2]); eo.z = f2bf(e2); cs += e2;
      float e3 = expf(bf2f(lg.w) + acc[m][n][3]); eo.w = f2bf(e3); cs += e3;
      *reinterpret_cast<ushort4*>(&Tg[sa]) = eo;
    }
    cs += __shfl_xor(cs, 16); cs += __shfl_xor(cs, 32);
    if (lq == 0) atomicAdd(&rowsum[n0 + ccl], cs);
  }
  __syncthreads();
  {
    int cc = tid >> 1, r0 = (tid & 1) * 64;
    const unsigned short* src = Tg + cc * 132 + r0;
    unsigned short* dst = Gb + (size_t)(n0 + cc) * Nn + m0 + r0;
    #pragma unroll
    for (int v = 0; v < 8; ++v)
      *reinterpret_cast<u16x8*>(dst + v * 8) = *reinterpret_cast<const u16x8*>(src + v * 8);
  }
}

// ---------------- bf16 MFMA GEMM, 64x64 tile, BK=64, split-K via atomicAdd ----------------
__global__ __launch_bounds__(256) void gemm64s_bt_bf16(
    const unsigned short* __restrict__ Ab, const unsigned short* __restrict__ Bb,
    float* __restrict__ Cp, int M, int N, int K, int KS)
{
  __shared__ unsigned short As[2][64 * 64];
  __shared__ unsigned short Bs[2][64 * 64];
  const int tid = threadIdx.x;
  const int m0 = blockIdx.x * 64, n0 = blockIdx.y * 64;
  const int kbase = blockIdx.z * KS;
  const int wave = tid >> 6, lane = tid & 63;
  const int wr = (wave >> 1) * 32, wc = (wave & 1) * 32;
  const int l16 = lane & 15, lq = lane >> 4;
  f32x4 acc[2][2] = {};
  const int NT = KS >> 6;

  auto stage = [&](int buf, int kt) {
    const int k0 = kbase + kt * 64;
    #pragma unroll
    for (int i = 0; i < 2; ++i) {
      int t2 = tid + i * 256;
      int r = t2 >> 3, c = (t2 & 7) * 8;
      gload_lds16(Ab + (size_t)(m0 + r) * K + k0 + c, &As[buf][t2 * 8]);
    }
    #pragma unroll
    for (int i = 0; i < 2; ++i) {
      int t2 = tid + i * 256;
      int r = t2 >> 3, c = (t2 & 7) * 8;
      gload_lds16(Bb + (size_t)(n0 + r) * K + k0 + c, &Bs[buf][t2 * 8]);
    }
  };

  stage(0, 0);
  __syncthreads();
  int buf = 0;
  for (int kt = 0; kt < NT; ++kt) {
    if (kt + 1 < NT) stage(buf ^ 1, kt + 1);
    bf16x8 af[2][2], bfr[2][2];
    #pragma unroll
    for (int m = 0; m < 2; ++m)
      #pragma unroll
      for (int ks = 0; ks < 2; ++ks)
        af[m][ks] = *reinterpret_cast<const bf16x8*>(
            &As[buf][(wr + m * 16 + l16) * 64 + ks * 32 + lq * 8]);
    #pragma unroll
    for (int n = 0; n < 2; ++n)
      #pragma unroll
      for (int ks = 0; ks < 2; ++ks)
        bfr[n][ks] = *reinterpret_cast<const bf16x8*>(
            &Bs[buf][(wc + n * 16 + l16) * 64 + ks * 32 + lq * 8]);
    #pragma unroll
    for (int m = 0; m < 2; ++m)
      #pragma unroll
      for (int n = 0; n < 2; ++n)
        #pragma unroll
        for (int ks = 0; ks < 2; ++ks)
          acc[m][n] = __builtin_amdgcn_mfma_f32_16x16x32_bf16(af[m][ks], bfr[n][ks], acc[m][n], 0, 0, 0);
    __syncthreads();
    buf ^= 1;
  }
  #pragma unroll
  for (int m = 0; m < 2; ++m)
    #pragma unroll
    for (int n = 0; n < 2; ++n) {
      int col = n0 + wc + n * 16 + l16;
      #pragma unroll
      for (int q = 0; q < 4; ++q) {
        int row = m0 + wr + m * 16 + lq * 4 + q;
        atomicAdd(&Cp[(size_t)row * N + col], acc[m][n][q]);
      }
    }
}

// ---------------- f32 -> bf16 convert ----------------
__global__ __launch_bounds__(256) void cvt_bf16_k(const float* __restrict__ in,
                                                  unsigned short* __restrict__ out, long n) {
  long i = ((long)blockIdx.x * 256 + threadIdx.x) * 8;
  if (i + 8 > n) return;
  float4 a = *reinterpret_cast<const float4*>(&in[i]);
  float4 b = *reinterpret_cast<const float4*>(&in[i + 4]);
  u16x8 o;
  o[0] = f2bf(a.x); o[1] = f2bf(a.y); o[2] = f2bf(a.z); o[3] = f2bf(a.w);
  o[4] = f2bf(b.x); o[5] = f2bf(b.y); o[6] = f2bf(b.z); o[7] = f2bf(b.w);
  *reinterpret_cast<u16x8*>(&out[i]) = o;
}

// ---------------- transpose-convert f32 [R rows, S stride] -> bf16 [C][R] ----------------
__global__ __launch_bounds__(256) void tcvt_k(const float* __restrict__ in,
                                              unsigned short* __restrict__ outT, int R, int S) {
  __shared__ unsigned short tile[64][65];
  int r0 = blockIdx.x * 64, c0 = blockIdx.y * 64;
  int t = threadIdx.x & 63, q = threadIdx.x >> 6;
  for (int rr = q; rr < 64; rr += 4)
    tile[t][rr] = f2bf(in[(long)(r0 + rr) * S + c0 + t]);
  __syncthreads();
  for (int cc = q; cc < 64; cc += 4)
    outT[(long)(c0 + cc) * R + r0 + t] = tile[cc][t];
}

// ---------------- final: scale z_g rows by 1/rowsum, elu both halves ----------------
__global__ __launch_bounds__(256) void elu_rows_k(float* __restrict__ p,
                                                  const float* __restrict__ rowsum) {
  long i = ((long)blockIdx.x * 256 + threadIdx.x) * 4;
  float4 v = *reinterpret_cast<const float4*>(&p[i]);
  float sc = 1.f;
  long half = (long)Nn * Dd;
  if (i >= half) sc = 1.f / rowsum[(i - half) >> 8];
  v.x *= sc; v.y *= sc; v.z *= sc; v.w *= sc;
  v.x = v.x > 0.f ? v.x : expm1f(v.x);
  v.y = v.y > 0.f ? v.y : expm1f(v.y);
  v.z = v.z > 0.f ? v.z : expm1f(v.z);
  v.w = v.w > 0.f ? v.w : expm1f(v.w);
  *reinterpret_cast<float4*>(&p[i]) = v;
}

// ---------------- generic strided f32 GEMM, 64x64 tile (+opt bf16 out) ----------------
__global__ __launch_bounds__(256) void gemm64_k(
    const float* __restrict__ Ap, const float* __restrict__ Bp, float* __restrict__ Cp,
    unsigned short* __restrict__ Cb,
    int M, int N, int K, int Asm, int Ask, int Bsk, int Bsn)
{
  __shared__ alignas(16) float As[16][68];
  __shared__ alignas(16) float Bs[16][68];
  const int tid = threadIdx.x;
  const int tx = tid & 15, ty = tid >> 4;
  const int m0 = blockIdx.x * 64, n0 = blockIdx.y * 64;
  float acc[4][4] = {};
  for (int k0 = 0; k0 < K; k0 += 16) {
    if (Ask == 1) {
      int mm = tid >> 2, kk = (tid & 3) << 2;
      float4 v = *reinterpret_cast<const float4*>(&Ap[(long)(m0 + mm) * Asm + k0 + kk]);
      As[kk + 0][mm] = v.x; As[kk + 1][mm] = v.y; As[kk + 2][mm] = v.z; As[kk + 3][mm] = v.w;
    } else {
      int kk = tid >> 4, mm = (tid & 15) << 2;
      *reinterpret_cast<float4*>(&As[kk][mm]) =
          *reinterpret_cast<const float4*>(&Ap[(long)(k0 + kk) * Ask + m0 + mm]);
    }
    if (Bsn == 1) {
      int kk = tid >> 4, nn = (tid & 15) << 2;
      *reinterpret_cast<float4*>(&Bs[kk][nn]) =
          *reinterpret_cast<const float4*>(&Bp[(long)(k0 + kk) * Bsk + n0 + nn]);
    } else {
      int nn = tid >> 2, kk = (tid & 3) << 2;
      float4 v = *reinterpret_cast<const float4*>(&Bp[(long)(n0 + nn) * Bsn + k0 + kk]);
      Bs[kk + 0][nn] = v.x; Bs[kk + 1][nn] = v.y; Bs[kk + 2][nn] = v.z; Bs[kk + 3][nn] = v.w;
    }
    __syncthreads();
    #pragma unroll
    for (int kk = 0; kk < 16; ++kk) {
      float4 av = *reinterpret_cast<const float4*>(&As[kk][ty << 2]);
      float4 bv = *reinterpret_cast<const float4*>(&Bs[kk][tx << 2]);
      float a[4] = {av.x, av.y, av.z, av.w};
      float b[4] = {bv.x, bv.y, bv.z, bv.w};
      #pragma unroll
      for (int r = 0; r < 4; ++r)
        #pragma unroll
        for (int c = 0; c < 4; ++c) acc[r][c] = fmaf(a[r], b[c], acc[r][c]);
    }
    __syncthreads();
  }
  #pragma unroll
  for (int r = 0; r < 4; ++r) {
    long base = (long)(m0 + (ty << 2) + r) * N + n0 + (tx << 2);
    float4 o = {acc[r][0], acc[r][1], acc[r][2], acc[r][3]};
    *reinterpret_cast<float4*>(&Cp[base]) = o;
    if (Cb) {
      ushort4 ob = {f2bf(o.x), f2bf(o.y), f2bf(o.z), f2bf(o.w)};
      *reinterpret_cast<ushort4*>(&Cb[base]) = ob;
    }
  }
}

// ---------------- sc/s1/s2 row dots (hcat stride 768) ----------------
__global__ __launch_bounds__(256) void rowdots_k(
    const float* __restrict__ hcat, const float* __restrict__ u, const float* __restrict__ a_g,
    float* __restrict__ esc, float* __restrict__ s1, float* __restrict__ s2)
{
  int i = blockIdx.x, t = threadIdx.x;
  float hh = hcat[(long)i * 768 + t];
  float hg = hcat[(long)i * 768 + 512 + t];
  float d0 = block_reduce_sum(hh * u[t]);
  float d1 = block_reduce_sum(hg * a_g[t]);
  float d2 = block_reduce_sum(hg * a_g[Dd + t]);
  if (t == 0) {
    esc[i] = expf(d0 * 0.0625f);
    s1[i] = d1;
    s2[i] = d2;
  }
}

// ---------------- column softmax stats for A ----------------
__global__ __launch_bounds__(256) void colstats_k(
    const float* __restrict__ H, const float* __restrict__ esc,
    float* __restrict__ colden, float* __restrict__ cnt)
{
  int e = blockIdx.x * 256 + threadIdx.x;
  int r0 = blockIdx.y * 128;
  float d = 0.f, c = 0.f;
  for (int r = r0; r < r0 + 128; ++r) {
    float h = H[(long)r * Ee + e];
    if (h > 0.f) { d += esc[r]; c += 1.f; }
  }
  atomicAdd(&colden[e], d);
  atomicAdd(&cnt[e], c);
}

// ---------------- A fill (tile): Abuf f32 + CAT A-half bf16 + AbT bf16 ----------------
__global__ __launch_bounds__(256) void fillA_k(
    const float* __restrict__ H, const float* __restrict__ esc,
    const float* __restrict__ colden, float* __restrict__ A,
    unsigned short* __restrict__ CAT, unsigned short* __restrict__ AbT)
{
  __shared__ unsigned short tile[64][68];
  int r0 = blockIdx.x * 64, e0 = blockIdx.y * 64;
  int te = threadIdx.x & 63, tq = threadIdx.x >> 6;
  float cd = colden[e0 + te];
  for (int rr = tq; rr < 64; rr += 4) {
    long idx = (long)(r0 + rr) * Ee + e0 + te;
    float h = H[idx];
    float val = h > 0.f ? esc[r0 + rr] / cd : 0.f;
    A[idx] = val;
    unsigned short vb = f2bf(val);
    CAT[(long)(r0 + rr) * 2048 + 1024 + e0 + te] = vb;
    tile[te][rr] = vb;
  }
  __syncthreads();
  for (int ee = tq; ee < 64; ee += 4)
    AbT[(long)(e0 + ee) * Nn + r0 + te] = tile[ee][te];
}

// ---------------- B row softmax: Bbuf in place + CAT B-half bf16 ----------------
__global__ __launch_bounds__(256) void brow_k(float* __restrict__ Bbuf,
                                              const float* __restrict__ H,
                                              unsigned short* __restrict__ CAT)
{
  int i = blockIdx.x, t = threadIdx.x;
  long base = (long)i * Ee + t * 4;
  float4 raw = *reinterpret_cast<const float4*>(&Bbuf[base]);
  float4 h = *reinterpret_cast<const float4*>(&H[base]);
  float rr[4] = {raw.x, raw.y, raw.z, raw.w}, hh[4] = {h.x, h.y, h.z, h.w};
  float p[4]; float s = 0.f;
  #pragma unroll
  for (int k = 0; k < 4; ++k) { p[k] = hh[k] > 0.f ? expf(rr[k]) : 0.f; s += p[k]; }
  float den = block_reduce_sum(s);
  float inv = den > 0.f ? 1.f / den : 0.f;
  float4 o = {p[0] * inv, p[1] * inv, p[2] * inv, p[3] * inv};
  *reinterpret_cast<float4*>(&Bbuf[base]) = o;
  ushort4 ob = {f2bf(o.x), f2bf(o.y), f2bf(o.z), f2bf(o.w)};
  *reinterpret_cast<ushort4*>(&CAT[(long)i * 2048 + t * 4]) = ob;
}

// ---------------- G fill: G f32 + Gb bf16 (logits = row-softmax probs) ----------------
__global__ __launch_bounds__(256) void gfill_k(
    const float* __restrict__ adj, const float* __restrict__ s1,
    const float* __restrict__ s2, float* __restrict__ G, unsigned short* __restrict__ Gb)
{
  int i = blockIdx.x, t = threadIdx.x;
  float s1i = s1[i];
  float p[16]; float sum = 0.f;
  #pragma unroll
  for (int c = 0; c < 4; ++c) {
    int j = c * 1024 + t * 4;
    float4 a = *reinterpret_cast<const float4*>(&adj[(long)i * Nn + j]);
    float4 sv = *reinterpret_cast<const float4*>(&s2[j]);
    float aa[4] = {a.x, a.y, a.z, a.w}, ss[4] = {sv.x, sv.y, sv.z, sv.w};
    #pragma unroll
    for (int k = 0; k < 4; ++k) {
      float f = (aa[k] > 0.f ? 1.f : 0.f) + ((j + k) == i ? 1.f : 0.f);
      float l = s1i + ss[k];
      l = l > 0.f ? l : 0.2f * l;
      float val = l * f - 1e9f * fmaxf(1.f - f, 0.f);
      float pp = expf(val);
      p[c * 4 + k] = pp; sum += pp;
    }
  }
  float den = block_reduce_sum(sum);
  float inv = 1.f / den;
  #pragma unroll
  for (int c = 0; c < 4; ++c) {
    int j = c * 1024 + t * 4;
    float4 o = {p[c * 4] * inv, p[c * 4 + 1] * inv, p[c * 4 + 2] * inv, p[c * 4 + 3] * inv};
    *reinterpret_cast<float4*>(&G[(long)i * Nn + j]) = o;
    ushort4 ob = {f2bf(o.x), f2bf(o.y), f2bf(o.z), f2bf(o.w)};
    *reinterpret_cast<ushort4*>(&Gb[(long)i * Nn + j]) = ob;
  }
}

// ---------------- A_hat denominators ----------------
__global__ __launch_bounds__(256) void amstats_k(
    const float* __restrict__ A, const float* __restrict__ Mm, float* __restrict__ aden)
{
  int e = blockIdx.x * 256 + threadIdx.x;
  int r0 = blockIdx.y * 128;
  float d = 0.f;
  for (int r = r0; r < r0 + 128; ++r) {
    long idx = (long)r * Ee + e;
    d += expf(A[idx] + Mm[idx]);
  }
  atomicAdd(&aden[e], d);
}

// ---------------- A_hat fill (transpose, bf16 out) ----------------
__global__ __launch_bounds__(256) void ahat_k(
    const float* __restrict__ Abuf, const float* __restrict__ Mm,
    const float* __restrict__ H, const float* __restrict__ aden,
    unsigned short* __restrict__ AhB)
{
  __shared__ float tile[64][65];
  int j0 = blockIdx.x * 64, e0 = blockIdx.y * 64;
  int te = threadIdx.x & 63;
  int tq = threadIdx.x >> 6;
  int e = e0 + te;
  float inv = 1.f / aden[e];
  for (int jj = tq; jj < 64; jj += 4) {
    long idx = (long)(j0 + jj) * Ee + e;
    float val = (H[idx] > 0.f) ? expf(Abuf[idx] + Mm[idx]) * inv : 0.f;
    tile[te][jj] = val;
  }
  __syncthreads();
  for (int ee = tq; ee < 64; ee += 4)
    AhB[(long)(e0 + ee) * Nn + j0 + te] = f2bf(tile[ee][te]);
}

// ---------------- B_hat: bf16 out ----------------
__global__ __launch_bounds__(256) void bhat_k(const float* __restrict__ Bbuf,
                                              const float* __restrict__ Mm,
                                              const float* __restrict__ H,
                                              unsigned short* __restrict__ Bb2)
{
  int i = blockIdx.x, t = threadIdx.x;
  long base = (long)i * Ee + t * 4;
  float4 b = *reinterpret_cast<const float4*>(&Bbuf[base]);
  float4 m = *reinterpret_cast<const float4*>(&Mm[base]);
  float4 h = *reinterpret_cast<const float4*>(&H[base]);
  float bb[4] = {b.x, b.y, b.z, b.w}, mm2[4] = {m.x, m.y, m.z, m.w}, hh[4] = {h.x, h.y, h.z, h.w};
  float p[4]; float s = 0.f;
  #pragma unroll
  for (int k = 0; k < 4; ++k) { p[k] = expf(bb[k] + mm2[k]); s += p[k]; }
  float den = block_reduce_sum(s);
  float inv = 1.f / den;
  #pragma unroll
  for (int k = 0; k < 4; ++k) p[k] = hh[k] > 0.f ? p[k] * inv : 0.f;
  ushort4 ob = {f2bf(p[0]), f2bf(p[1]), f2bf(p[2]), f2bf(p[3])};
  *reinterpret_cast<ushort4*>(&Bb2[base]) = ob;
}

// ---------------- launcher ----------------
extern "C" void kernel_launch(void* const* d_in, const int* in_sizes, int n_in,
                              void* d_out, int out_size, void* d_ws, size_t ws_size,
                              hipStream_t stream) {
  const float* x    = (const float*)d_in[0];
  const float* H    = (const float*)d_in[1];
  const float* adj  = (const float*)d_in[2];
  const float* W_he = (const float*)d_in[3];
  const float* u    = (const float*)d_in[4];
  const float* W_e  = (const float*)d_in[5];
  const float* W_n  = (const float*)d_in[6];
  const float* W_g  = (const float*)d_in[7];
  const float* a_g  = (const float*)d_in[8];
  float* out = (float*)d_out;
  float* ws  = (float*)d_ws;
  (void)in_sizes; (void)n_in; (void)out_size; (void)ws_size;

  size_t off = 0;
  auto alloc = [&](size_t n) { float* p = ws + off; off += n; return p; };
  float* hcat   = alloc((size_t)Nn * 768);
  float* esc    = alloc(Nn);
  float* s1     = alloc(Nn);
  float* s2     = alloc(Nn);
  float* colden = alloc(Ee);   // colden,cnt,aden,rowsum contiguous -> one memset
  float* cnt    = alloc(Ee);
  float* aden   = alloc(Ee);
  float* rowsum = alloc(Nn);
  float* e_repr = alloc((size_t)Ee * Dd);   // e_repr,e_mix contiguous -> one memset
  float* e_mix  = alloc((size_t)Ee * Dd);
  float* heb    = alloc((size_t)Ee * Dd);
  float* tmp_ew = alloc((size_t)Ee * Dd);
  float* Abuf   = alloc((size_t)Nn * Ee);
  float* Bbuf   = alloc((size_t)Nn * Ee);
  float* Mm     = alloc((size_t)Nn * Ee);
  float* G      = alloc((size_t)Nn * Nn);
  unsigned short* Gb    = (unsigned short*)alloc((size_t)Nn * Nn / 2);
  unsigned short* CAT   = (unsigned short*)alloc((size_t)Nn * 2048 / 2);
  unsigned short* Hbt   = (unsigned short*)alloc((size_t)Ee * Nn / 2);
  unsigned short* AbT   = (unsigned short*)alloc((size_t)Ee * Nn / 2);
  unsigned short* AhB   = (unsigned short*)alloc((size_t)Ee * Nn / 2);
  unsigned short* hheT  = (unsigned short*)alloc((size_t)Dd * Nn / 2);
  unsigned short* hgT   = (unsigned short*)alloc((size_t)Dd * Nn / 2);
  unsigned short* tewT  = (unsigned short*)alloc((size_t)Dd * Ee / 2);
  unsigned short* Bb2   = (unsigned short*)alloc((size_t)Nn * Ee / 2);
  unsigned short* xb    = (unsigned short*)alloc((size_t)Nn * Dd / 2);
  unsigned short* WcTb  = (unsigned short*)alloc((size_t)768 * Dd / 2);
  unsigned short* hcatB = (unsigned short*)alloc((size_t)Nn * 768 / 2);
  unsigned short* hebB  = (unsigned short*)alloc((size_t)Ee * Dd / 2);

  hipMemsetAsync(colden, 0, (3 * Ee + Nn) * sizeof(float), stream);
  hipMemsetAsync(e_repr, 0, 2 * (size_t)Ee * Dd * sizeof(float), stream);
  hipMemsetAsync(out, 0, 2 * (size_t)Nn * Dd * sizeof(float), stream);

  auto gbt = [&](const unsigned short* A, const unsigned short* B, float* C, unsigned short* Cb,
                 int M, int N, int K, int lda, int ldb, float alpha, const float* cd) {
    gemm_bt_bf16<<<dim3(M / 128, N / 128), 256, 0, stream>>>(A, B, C, Cb, M, N, K, lda, ldb,
                                                             alpha, cd);
  };
  auto gs64 = [&](const unsigned short* A, const unsigned short* B, float* C,
                  int M, int N, int K, int KS) {
    gemm64s_bt_bf16<<<dim3(M / 64, N / 64, K / KS), 256, 0, stream>>>(A, B, C, M, N, K, KS);
  };
  auto tcvt = [&](const float* in, unsigned short* o, int R, int S, int cols) {
    tcvt_k<<<dim3(R / 64, cols / 64), 256, 0, stream>>>(in, o, R, S);
  };

  // bf16 copies of x and W^T slices
  cvt_bf16_k<<<(Nn * Dd) / 2048, 256, 0, stream>>>(x, xb, (long)Nn * Dd);
  tcvt(W_he, WcTb, Dd, Dd, Dd);
  tcvt(W_n, WcTb + 256 * 256, Dd, Dd, Dd);
  tcvt(W_g, WcTb + 2 * 256 * 256, Dd, Dd, Dd);
  // fused projections: hcat(+hcatB) = x @ [W_he|W_n|W_g]  (bf16 MFMA)
  gbt(xb, WcTb, hcat, hcatB, Nn, 768, Dd, Dd, Dd, 1.f, nullptr);
  rowdots_k<<<Nn, 256, 0, stream>>>(hcat, u, a_g, esc, s1, s2);
  // A column softmax
  colstats_k<<<dim3(Ee / 256, 32), 256, 0, stream>>>(H, esc, colden, cnt);
  fillA_k<<<dim3(Nn / 64, Ee / 64), 256, 0, stream>>>(H, esc, colden, Abuf, CAT, AbT);
  // e_repr = A^T @ h_he
  tcvt(hcat, hheT, Nn, 768, Dd);
  gs64(AbT, hheT, e_repr, Ee, Dd, Nn, 1024);
  // heb = e_repr @ W_e (f32, + bf16 copy)
  gemm64_k<<<dim3(Ee / 64, Dd / 64), 256, 0, stream>>>(e_repr, W_e, heb, hebB, Ee, Dd, Dd, Dd, 1, Dd, 1);
  // Bsc = (hn @ heb^T)/16 (bf16 MFMA), then row softmax
  gbt(hcatB + 256, hebB, Bbuf, nullptr, Nn, Ee, Dd, 768, Dd, 0.0625f, nullptr);
  brow_k<<<Nn, 256, 0, stream>>>(Bbuf, H, CAT);
  // G softmax (f32 + bf16)
  gfill_k<<<Nn, 256, 0, stream>>>(adj, s1, s2, G, Gb);
  // M = (G @ H) / he_sz
  tcvt(H, Hbt, Nn, Ee, Ee);
  gbt(Gb, Hbt, Mm, nullptr, Nn, Ee, Nn, Nn, Nn, 1.f, cnt);
  // symmetric fused Gram: Gb = exp(G + BB^T + AA^T) (unnormalized), rowsum
  gemm_gram_k<<<dim3(Nn / 128, Nn / 128), 256, 0, stream>>>(CAT, G, Gb, rowsum);
  // A_hat
  amstats_k<<<dim3(Ee / 256, 32), 256, 0, stream>>>(Abuf, Mm, aden);
  ahat_k<<<dim3(Nn / 64, Ee / 64), 256, 0, stream>>>(Abuf, Mm, H, aden, AhB);
  // e_mix = A_hat @ h_he ; tmp_ew = e_mix @ W_e
  gs64(AhB, hheT, e_mix, Ee, Dd, Nn, 1024);
  gemm64_k<<<dim3(Ee / 64, Dd / 64), 256, 0, stream>>>(e_mix, W_e, tmp_ew, nullptr, Ee, Dd, Dd, Dd, 1, Dd, 1);
  // B_hat, z_h
  bhat_k<<<Nn, 256, 0, stream>>>(Bbuf, Mm, H, Bb2);
  tcvt(tmp_ew, tewT, Ee, Dd, Dd);
  gs64(Bb2, tewT, out, Nn, Dd, Ee, 1024);
  // z_g (unnormalized), then row-scale + elu
  tcvt(hcat + 512, hgT, Nn, 768, Dd);
  gs64(Gb, hgT, out + (size_t)Nn * Dd, Nn, Dd, Nn, 2048);
  elu_rows_k<<<(2 * Nn * Dd) / 1024, 256, 0, stream>>>(out, rowsum);
}

// Round 6
// 618.180 us; speedup vs baseline: 4.3997x; 1.0763x over previous
//
#include <hip/hip_runtime.h>
#include <math.h>
#include <stdint.h>

#define Nn 4096
#define Ee 1024
#define Dd 256

typedef __attribute__((ext_vector_type(8))) __bf16 bf16x8;
typedef __attribute__((ext_vector_type(4))) float f32x4;
typedef __attribute__((ext_vector_type(8))) unsigned short u16x8;

__device__ __forceinline__ unsigned short f2bf(float f) {
  unsigned int u = __float_as_uint(f);
  unsigned int r = (u + 0x7fffu + ((u >> 16) & 1u)) >> 16;
  return (unsigned short)r;
}
__device__ __forceinline__ float bf2f(unsigned short u) {
  return __uint_as_float(((unsigned int)u) << 16);
}

__device__ __forceinline__ void gload_lds16(const void* g, void* l) {
  __builtin_amdgcn_global_load_lds(
      (__attribute__((address_space(1))) void*)const_cast<void*>(g),
      (__attribute__((address_space(3))) void*)l, 16, 0, 0);
}

__device__ __forceinline__ float block_reduce_sum(float v) {
  __shared__ float sh[4];
  #pragma unroll
  for (int o = 32; o > 0; o >>= 1) v += __shfl_down(v, o);
  int lane = threadIdx.x & 63, w = threadIdx.x >> 6;
  if (lane == 0) sh[w] = v;
  __syncthreads();
  float s = sh[0] + sh[1] + sh[2] + sh[3];
  __syncthreads();
  return s;
}

// ---------------- bf16 MFMA GEMM: C = alpha*(A*B^T), 128x128, BK=32 (+opt bf16 out) ----------------
__global__ __launch_bounds__(256) void gemm_bt_bf16(
    const unsigned short* __restrict__ Ab, const unsigned short* __restrict__ Bb,
    float* __restrict__ Cp, unsigned short* __restrict__ Cb,
    int M, int N, int K, int lda, int ldb, float alpha)
{
  __shared__ unsigned short As[2][128 * 32];
  __shared__ unsigned short Bs[2][128 * 32];
  const int tid = threadIdx.x;
  const int m0 = blockIdx.x * 128, n0 = blockIdx.y * 128;
  const int wave = tid >> 6, lane = tid & 63;
  const int wr = (wave >> 1) * 64, wc = (wave & 1) * 64;
  const int l16 = lane & 15, lq = lane >> 4;
  f32x4 acc[4][4] = {};
  const int NT = K >> 5;

  auto stage = [&](int buf, int kt) {
    const int k0 = kt * 32;
    #pragma unroll
    for (int i = 0; i < 2; ++i) {
      int t2 = tid + i * 256;
      int r = t2 >> 2, c = (t2 & 3) * 8;
      gload_lds16(Ab + (size_t)(m0 + r) * lda + k0 + c, &As[buf][t2 * 8]);
    }
    #pragma unroll
    for (int i = 0; i < 2; ++i) {
      int t2 = tid + i * 256;
      int r = t2 >> 2, c = (t2 & 3) * 8;
      gload_lds16(Bb + (size_t)(n0 + r) * ldb + k0 + c, &Bs[buf][t2 * 8]);
    }
  };

  stage(0, 0);
  __syncthreads();
  int buf = 0;
  for (int kt = 0; kt < NT; ++kt) {
    if (kt + 1 < NT) stage(buf ^ 1, kt + 1);
    bf16x8 af[4], bfr[4];
    #pragma unroll
    for (int m = 0; m < 4; ++m)
      af[m] = *reinterpret_cast<const bf16x8*>(&As[buf][(wr + m * 16 + l16) * 32 + lq * 8]);
    #pragma unroll
    for (int n = 0; n < 4; ++n)
      bfr[n] = *reinterpret_cast<const bf16x8*>(&Bs[buf][(wc + n * 16 + l16) * 32 + lq * 8]);
    #pragma unroll
    for (int m = 0; m < 4; ++m)
      #pragma unroll
      for (int n = 0; n < 4; ++n)
        acc[m][n] = __builtin_amdgcn_mfma_f32_16x16x32_bf16(af[m], bfr[n], acc[m][n], 0, 0, 0);
    __syncthreads();
    buf ^= 1;
  }
  #pragma unroll
  for (int m = 0; m < 4; ++m)
    #pragma unroll
    for (int n = 0; n < 4; ++n) {
      int col = n0 + wc + n * 16 + l16;
      #pragma unroll
      for (int q = 0; q < 4; ++q) {
        int row = m0 + wr + m * 16 + lq * 4 + q;
        size_t idx = (size_t)row * N + col;
        float v = acc[m][n][q] * alpha;
        Cp[idx] = v;
        if (Cb) Cb[idx] = f2bf(v);
      }
    }
}

// ---------------- bf16 MFMA GEMM, 128x128 tile, BK=32, split-K atomicAdd ----------------
__global__ __launch_bounds__(256) void gemm_bts_bf16(
    const unsigned short* __restrict__ Ab, const unsigned short* __restrict__ Bb,
    float* __restrict__ Cp, int M, int N, int K, int lda, int ldb, int KS)
{
  __shared__ unsigned short As[2][128 * 32];
  __shared__ unsigned short Bs[2][128 * 32];
  const int tid = threadIdx.x;
  const int m0 = blockIdx.x * 128, n0 = blockIdx.y * 128;
  const int kbase = blockIdx.z * KS;
  const int wave = tid >> 6, lane = tid & 63;
  const int wr = (wave >> 1) * 64, wc = (wave & 1) * 64;
  const int l16 = lane & 15, lq = lane >> 4;
  f32x4 acc[4][4] = {};
  const int NT = KS >> 5;

  auto stage = [&](int buf, int kt) {
    const int k0 = kbase + kt * 32;
    #pragma unroll
    for (int i = 0; i < 2; ++i) {
      int t2 = tid + i * 256;
      int r = t2 >> 2, c = (t2 & 3) * 8;
      gload_lds16(Ab + (size_t)(m0 + r) * lda + k0 + c, &As[buf][t2 * 8]);
    }
    #pragma unroll
    for (int i = 0; i < 2; ++i) {
      int t2 = tid + i * 256;
      int r = t2 >> 2, c = (t2 & 3) * 8;
      gload_lds16(Bb + (size_t)(n0 + r) * ldb + k0 + c, &Bs[buf][t2 * 8]);
    }
  };

  stage(0, 0);
  __syncthreads();
  int buf = 0;
  for (int kt = 0; kt < NT; ++kt) {
    if (kt + 1 < NT) stage(buf ^ 1, kt + 1);
    bf16x8 af[4], bfr[4];
    #pragma unroll
    for (int m = 0; m < 4; ++m)
      af[m] = *reinterpret_cast<const bf16x8*>(&As[buf][(wr + m * 16 + l16) * 32 + lq * 8]);
    #pragma unroll
    for (int n = 0; n < 4; ++n)
      bfr[n] = *reinterpret_cast<const bf16x8*>(&Bs[buf][(wc + n * 16 + l16) * 32 + lq * 8]);
    #pragma unroll
    for (int m = 0; m < 4; ++m)
      #pragma unroll
      for (int n = 0; n < 4; ++n)
        acc[m][n] = __builtin_amdgcn_mfma_f32_16x16x32_bf16(af[m], bfr[n], acc[m][n], 0, 0, 0);
    __syncthreads();
    buf ^= 1;
  }
  #pragma unroll
  for (int m = 0; m < 4; ++m)
    #pragma unroll
    for (int n = 0; n < 4; ++n) {
      int col = n0 + wc + n * 16 + l16;
      #pragma unroll
      for (int q = 0; q < 4; ++q) {
        int row = m0 + wr + m * 16 + lq * 4 + q;
        atomicAdd(&Cp[(size_t)row * N + col], acc[m][n][q]);
      }
    }
}

// ---------------- symmetric fused Gram: Gb = exp(Gb_logit + CAT*CAT^T), rowsum ----------------
__global__ __launch_bounds__(256) void gemm_gram_k(
    const unsigned short* __restrict__ CAT,   // [Nn][2048] bf16
    unsigned short* __restrict__ Gb,          // in: bf16 logits; out: exp(logit)
    float* __restrict__ rowsum)               // pre-zeroed [Nn]
{
  const int bx = blockIdx.x, by = blockIdx.y;
  if (bx > by) return;
  const int K = 2048;
  __shared__ unsigned short SM[17024];
  unsigned short* Asb = SM;
  unsigned short* Bsb = SM + 8192;
  const int tid = threadIdx.x;
  const int m0 = bx * 128, n0 = by * 128;
  const int wave = tid >> 6, lane = tid & 63;
  const int wr = (wave >> 1) * 64, wc = (wave & 1) * 64;
  const int l16 = lane & 15, lq = lane >> 4;
  f32x4 acc[4][4] = {};
  const int NT = K >> 5;

  auto stage = [&](int buf, int kt) {
    const int k0 = kt * 32;
    #pragma unroll
    for (int i = 0; i < 2; ++i) {
      int t2 = tid + i * 256;
      int r = t2 >> 2, c = (t2 & 3) * 8;
      gload_lds16(CAT + (size_t)(m0 + r) * K + k0 + c, Asb + buf * 4096 + t2 * 8);
    }
    #pragma unroll
    for (int i = 0; i < 2; ++i) {
      int t2 = tid + i * 256;
      int r = t2 >> 2, c = (t2 & 3) * 8;
      gload_lds16(CAT + (size_t)(n0 + r) * K + k0 + c, Bsb + buf * 4096 + t2 * 8);
    }
  };

  stage(0, 0);
  __syncthreads();
  int buf = 0;
  for (int kt = 0; kt < NT; ++kt) {
    if (kt + 1 < NT) stage(buf ^ 1, kt + 1);
    bf16x8 af[4], bfr[4];
    #pragma unroll
    for (int m = 0; m < 4; ++m)
      af[m] = *reinterpret_cast<const bf16x8*>(Asb + buf * 4096 + (wr + m * 16 + l16) * 32 + lq * 8);
    #pragma unroll
    for (int n = 0; n < 4; ++n)
      bfr[n] = *reinterpret_cast<const bf16x8*>(Bsb + buf * 4096 + (wc + n * 16 + l16) * 32 + lq * 8);
    #pragma unroll
    for (int m = 0; m < 4; ++m)
      #pragma unroll
      for (int n = 0; n < 4; ++n)
        acc[m][n] = __builtin_amdgcn_mfma_f32_16x16x32_bf16(af[m], bfr[n], acc[m][n], 0, 0, 0);
    __syncthreads();
    buf ^= 1;
  }
  // normal epilogue (upper/diag region): read bf16 logit, write exp
  #pragma unroll
  for (int m = 0; m < 4; ++m)
    #pragma unroll
    for (int q = 0; q < 4; ++q) {
      int row = m0 + wr + m * 16 + lq * 4 + q;
      float s = 0.f;
      #pragma unroll
      for (int n = 0; n < 4; ++n) {
        int col = n0 + wc + n * 16 + l16;
        size_t idx = (size_t)row * Nn + col;
        float e = expf(bf2f(Gb[idx]) + acc[m][n][q]);
        Gb[idx] = f2bf(e);
        s += e;
      }
      s += __shfl_xor(s, 1); s += __shfl_xor(s, 2);
      s += __shfl_xor(s, 4); s += __shfl_xor(s, 8);
      if (l16 == 0) atomicAdd(&rowsum[row], s);
    }
  if (bx == by) return;

  // transposed epilogue (lower region): mirror tile via LDS
  __syncthreads();
  unsigned short* Tg = SM;  // [128][132]
  {
    int cc = tid >> 1, r0 = (tid & 1) * 64;
    const unsigned short* src = Gb + (size_t)(n0 + cc) * Nn + m0 + r0;
    unsigned short* dst = Tg + cc * 132 + r0;
    #pragma unroll
    for (int v = 0; v < 8; ++v)
      *reinterpret_cast<u16x8*>(dst + v * 8) = *reinterpret_cast<const u16x8*>(src + v * 8);
  }
  __syncthreads();
  #pragma unroll
  for (int n = 0; n < 4; ++n) {
    int ccl = wc + n * 16 + l16;
    float cs = 0.f;
    #pragma unroll
    for (int m = 0; m < 4; ++m) {
      int sa = ccl * 132 + wr + m * 16 + lq * 4;
      ushort4 lg = *reinterpret_cast<const ushort4*>(&Tg[sa]);
      ushort4 eo;
      float e0 = expf(bf2f(lg.x) + acc[m][n][0]); eo.x = f2bf(e0); cs += e0;
      float e1 = expf(bf2f(lg.y) + acc[m][n][1]); eo.y = f2bf(e1); cs += e1;
      float e2 = expf(bf2f(lg.z) + acc[m][n][2]); eo.z = f2bf(e2); cs += e2;
      float e3 = expf(bf2f(lg.w) + acc[m][n][3]); eo.w = f2bf(e3); cs += e3;
      *reinterpret_cast<ushort4*>(&Tg[sa]) = eo;
    }
    cs += __shfl_xor(cs, 16); cs += __shfl_xor(cs, 32);
    if (lq == 0) atomicAdd(&rowsum[n0 + ccl], cs);
  }
  __syncthreads();
  {
    int cc = tid >> 1, r0 = (tid & 1) * 64;
    const unsigned short* src = Tg + cc * 132 + r0;
    unsigned short* dst = Gb + (size_t)(n0 + cc) * Nn + m0 + r0;
    #pragma unroll
    for (int v = 0; v < 8; ++v)
      *reinterpret_cast<u16x8*>(dst + v * 8) = *reinterpret_cast<const u16x8*>(src + v * 8);
  }
}

// ---------------- bf16 MFMA GEMM, 64x64 tile, BK=64, split-K via atomicAdd ----------------
__global__ __launch_bounds__(256) void gemm64s_bt_bf16(
    const unsigned short* __restrict__ Ab, const unsigned short* __restrict__ Bb,
    float* __restrict__ Cp, int M, int N, int K, int KS)
{
  __shared__ unsigned short As[2][64 * 64];
  __shared__ unsigned short Bs[2][64 * 64];
  const int tid = threadIdx.x;
  const int m0 = blockIdx.x * 64, n0 = blockIdx.y * 64;
  const int kbase = blockIdx.z * KS;
  const int wave = tid >> 6, lane = tid & 63;
  const int wr = (wave >> 1) * 32, wc = (wave & 1) * 32;
  const int l16 = lane & 15, lq = lane >> 4;
  f32x4 acc[2][2] = {};
  const int NT = KS >> 6;

  auto stage = [&](int buf, int kt) {
    const int k0 = kbase + kt * 64;
    #pragma unroll
    for (int i = 0; i < 2; ++i) {
      int t2 = tid + i * 256;
      int r = t2 >> 3, c = (t2 & 7) * 8;
      gload_lds16(Ab + (size_t)(m0 + r) * K + k0 + c, &As[buf][t2 * 8]);
    }
    #pragma unroll
    for (int i = 0; i < 2; ++i) {
      int t2 = tid + i * 256;
      int r = t2 >> 3, c = (t2 & 7) * 8;
      gload_lds16(Bb + (size_t)(n0 + r) * K + k0 + c, &Bs[buf][t2 * 8]);
    }
  };

  stage(0, 0);
  __syncthreads();
  int buf = 0;
  for (int kt = 0; kt < NT; ++kt) {
    if (kt + 1 < NT) stage(buf ^ 1, kt + 1);
    bf16x8 af[2][2], bfr[2][2];
    #pragma unroll
    for (int m = 0; m < 2; ++m)
      #pragma unroll
      for (int ks = 0; ks < 2; ++ks)
        af[m][ks] = *reinterpret_cast<const bf16x8*>(
            &As[buf][(wr + m * 16 + l16) * 64 + ks * 32 + lq * 8]);
    #pragma unroll
    for (int n = 0; n < 2; ++n)
      #pragma unroll
      for (int ks = 0; ks < 2; ++ks)
        bfr[n][ks] = *reinterpret_cast<const bf16x8*>(
            &Bs[buf][(wc + n * 16 + l16) * 64 + ks * 32 + lq * 8]);
    #pragma unroll
    for (int m = 0; m < 2; ++m)
      #pragma unroll
      for (int n = 0; n < 2; ++n)
        #pragma unroll
        for (int ks = 0; ks < 2; ++ks)
          acc[m][n] = __builtin_amdgcn_mfma_f32_16x16x32_bf16(af[m][ks], bfr[n][ks], acc[m][n], 0, 0, 0);
    __syncthreads();
    buf ^= 1;
  }
  #pragma unroll
  for (int m = 0; m < 2; ++m)
    #pragma unroll
    for (int n = 0; n < 2; ++n) {
      int col = n0 + wc + n * 16 + l16;
      #pragma unroll
      for (int q = 0; q < 4; ++q) {
        int row = m0 + wr + m * 16 + lq * 4 + q;
        atomicAdd(&Cp[(size_t)row * N + col], acc[m][n][q]);
      }
    }
}

// ---------------- f32 -> bf16 convert ----------------
__global__ __launch_bounds__(256) void cvt_bf16_k(const float* __restrict__ in,
                                                  unsigned short* __restrict__ out, long n) {
  long i = ((long)blockIdx.x * 256 + threadIdx.x) * 8;
  if (i + 8 > n) return;
  float4 a = *reinterpret_cast<const float4*>(&in[i]);
  float4 b = *reinterpret_cast<const float4*>(&in[i + 4]);
  u16x8 o;
  o[0] = f2bf(a.x); o[1] = f2bf(a.y); o[2] = f2bf(a.z); o[3] = f2bf(a.w);
  o[4] = f2bf(b.x); o[5] = f2bf(b.y); o[6] = f2bf(b.z); o[7] = f2bf(b.w);
  *reinterpret_cast<u16x8*>(&out[i]) = o;
}

// ---------------- transpose-convert f32 [R rows, S stride] -> bf16 [C][R], opt col scale ----------------
__global__ __launch_bounds__(256) void tcvt_k(const float* __restrict__ in,
                                              unsigned short* __restrict__ outT, int R, int S,
                                              const float* __restrict__ coldiv) {
  __shared__ unsigned short tile[64][65];
  int r0 = blockIdx.x * 64, c0 = blockIdx.y * 64;
  int t = threadIdx.x & 63, q = threadIdx.x >> 6;
  float sc = coldiv ? 1.f / fmaxf(coldiv[c0 + t], 1.f) : 1.f;
  for (int rr = q; rr < 64; rr += 4)
    tile[t][rr] = f2bf(in[(long)(r0 + rr) * S + c0 + t] * sc);
  __syncthreads();
  for (int cc = q; cc < 64; cc += 4)
    outT[(long)(c0 + cc) * R + r0 + t] = tile[cc][t];
}

// ---------------- final: scale z_g rows by 1/rowsum, elu both halves ----------------
__global__ __launch_bounds__(256) void elu_rows_k(float* __restrict__ p,
                                                  const float* __restrict__ rowsum) {
  long i = ((long)blockIdx.x * 256 + threadIdx.x) * 4;
  float4 v = *reinterpret_cast<const float4*>(&p[i]);
  float sc = 1.f;
  long half = (long)Nn * Dd;
  if (i >= half) sc = 1.f / rowsum[(i - half) >> 8];
  v.x *= sc; v.y *= sc; v.z *= sc; v.w *= sc;
  v.x = v.x > 0.f ? v.x : expm1f(v.x);
  v.y = v.y > 0.f ? v.y : expm1f(v.y);
  v.z = v.z > 0.f ? v.z : expm1f(v.z);
  v.w = v.w > 0.f ? v.w : expm1f(v.w);
  *reinterpret_cast<float4*>(&p[i]) = v;
}

// ---------------- generic strided f32 GEMM, 64x64 tile (+opt bf16 out) ----------------
__global__ __launch_bounds__(256) void gemm64_k(
    const float* __restrict__ Ap, const float* __restrict__ Bp, float* __restrict__ Cp,
    unsigned short* __restrict__ Cb,
    int M, int N, int K, int Asm, int Ask, int Bsk, int Bsn)
{
  __shared__ alignas(16) float As[16][68];
  __shared__ alignas(16) float Bs[16][68];
  const int tid = threadIdx.x;
  const int tx = tid & 15, ty = tid >> 4;
  const int m0 = blockIdx.x * 64, n0 = blockIdx.y * 64;
  float acc[4][4] = {};
  for (int k0 = 0; k0 < K; k0 += 16) {
    if (Ask == 1) {
      int mm = tid >> 2, kk = (tid & 3) << 2;
      float4 v = *reinterpret_cast<const float4*>(&Ap[(long)(m0 + mm) * Asm + k0 + kk]);
      As[kk + 0][mm] = v.x; As[kk + 1][mm] = v.y; As[kk + 2][mm] = v.z; As[kk + 3][mm] = v.w;
    } else {
      int kk = tid >> 4, mm = (tid & 15) << 2;
      *reinterpret_cast<float4*>(&As[kk][mm]) =
          *reinterpret_cast<const float4*>(&Ap[(long)(k0 + kk) * Ask + m0 + mm]);
    }
    if (Bsn == 1) {
      int kk = tid >> 4, nn = (tid & 15) << 2;
      *reinterpret_cast<float4*>(&Bs[kk][nn]) =
          *reinterpret_cast<const float4*>(&Bp[(long)(k0 + kk) * Bsk + n0 + nn]);
    } else {
      int nn = tid >> 2, kk = (tid & 3) << 2;
      float4 v = *reinterpret_cast<const float4*>(&Bp[(long)(n0 + nn) * Bsn + k0 + kk]);
      Bs[kk + 0][nn] = v.x; Bs[kk + 1][nn] = v.y; Bs[kk + 2][nn] = v.z; Bs[kk + 3][nn] = v.w;
    }
    __syncthreads();
    #pragma unroll
    for (int kk = 0; kk < 16; ++kk) {
      float4 av = *reinterpret_cast<const float4*>(&As[kk][ty << 2]);
      float4 bv = *reinterpret_cast<const float4*>(&Bs[kk][tx << 2]);
      float a[4] = {av.x, av.y, av.z, av.w};
      float b[4] = {bv.x, bv.y, bv.z, bv.w};
      #pragma unroll
      for (int r = 0; r < 4; ++r)
        #pragma unroll
        for (int c = 0; c < 4; ++c) acc[r][c] = fmaf(a[r], b[c], acc[r][c]);
    }
    __syncthreads();
  }
  #pragma unroll
  for (int r = 0; r < 4; ++r) {
    long base = (long)(m0 + (ty << 2) + r) * N + n0 + (tx << 2);
    float4 o = {acc[r][0], acc[r][1], acc[r][2], acc[r][3]};
    *reinterpret_cast<float4*>(&Cp[base]) = o;
    if (Cb) {
      ushort4 ob = {f2bf(o.x), f2bf(o.y), f2bf(o.z), f2bf(o.w)};
      *reinterpret_cast<ushort4*>(&Cb[base]) = ob;
    }
  }
}

// ---------------- sc/s1/s2 row dots (hcat stride 768) ----------------
__global__ __launch_bounds__(256) void rowdots_k(
    const float* __restrict__ hcat, const float* __restrict__ u, const float* __restrict__ a_g,
    float* __restrict__ esc, float* __restrict__ s1, float* __restrict__ s2)
{
  int i = blockIdx.x, t = threadIdx.x;
  float hh = hcat[(long)i * 768 + t];
  float hg = hcat[(long)i * 768 + 512 + t];
  float d0 = block_reduce_sum(hh * u[t]);
  float d1 = block_reduce_sum(hg * a_g[t]);
  float d2 = block_reduce_sum(hg * a_g[Dd + t]);
  if (t == 0) {
    esc[i] = expf(d0 * 0.0625f);
    s1[i] = d1;
    s2[i] = d2;
  }
}

// ---------------- column softmax stats for A ----------------
__global__ __launch_bounds__(256) void colstats_k(
    const float* __restrict__ H, const float* __restrict__ esc,
    float* __restrict__ colden, float* __restrict__ cnt)
{
  int e = blockIdx.x * 256 + threadIdx.x;
  int r0 = blockIdx.y * 128;
  float d = 0.f, c = 0.f;
  for (int r = r0; r < r0 + 128; ++r) {
    float h = H[(long)r * Ee + e];
    if (h > 0.f) { d += esc[r]; c += 1.f; }
  }
  atomicAdd(&colden[e], d);
  atomicAdd(&cnt[e], c);
}

// ---------------- A fill (tile): Abuf f32 + CAT A-half bf16 + AbT bf16 ----------------
__global__ __launch_bounds__(256) void fillA_k(
    const float* __restrict__ H, const float* __restrict__ esc,
    const float* __restrict__ colden, float* __restrict__ A,
    unsigned short* __restrict__ CAT, unsigned short* __restrict__ AbT)
{
  __shared__ unsigned short tile[64][68];
  int r0 = blockIdx.x * 64, e0 = blockIdx.y * 64;
  int te = threadIdx.x & 63, tq = threadIdx.x >> 6;
  float cd = colden[e0 + te];
  for (int rr = tq; rr < 64; rr += 4) {
    long idx = (long)(r0 + rr) * Ee + e0 + te;
    float h = H[idx];
    float val = h > 0.f ? esc[r0 + rr] / cd : 0.f;
    A[idx] = val;
    unsigned short vb = f2bf(val);
    CAT[(long)(r0 + rr) * 2048 + 1024 + e0 + te] = vb;
    tile[te][rr] = vb;
  }
  __syncthreads();
  for (int ee = tq; ee < 64; ee += 4)
    AbT[(long)(e0 + ee) * Nn + r0 + te] = tile[ee][te];
}

// ---------------- B row softmax: Bbuf in place + CAT B-half bf16 ----------------
__global__ __launch_bounds__(256) void brow_k(float* __restrict__ Bbuf,
                                              const float* __restrict__ H,
                                              unsigned short* __restrict__ CAT)
{
  int i = blockIdx.x, t = threadIdx.x;
  long base = (long)i * Ee + t * 4;
  float4 raw = *reinterpret_cast<const float4*>(&Bbuf[base]);
  float4 h = *reinterpret_cast<const float4*>(&H[base]);
  float rr[4] = {raw.x, raw.y, raw.z, raw.w}, hh[4] = {h.x, h.y, h.z, h.w};
  float p[4]; float s = 0.f;
  #pragma unroll
  for (int k = 0; k < 4; ++k) { p[k] = hh[k] > 0.f ? expf(rr[k]) : 0.f; s += p[k]; }
  float den = block_reduce_sum(s);
  float inv = den > 0.f ? 1.f / den : 0.f;
  float4 o = {p[0] * inv, p[1] * inv, p[2] * inv, p[3] * inv};
  *reinterpret_cast<float4*>(&Bbuf[base]) = o;
  ushort4 ob = {f2bf(o.x), f2bf(o.y), f2bf(o.z), f2bf(o.w)};
  *reinterpret_cast<ushort4*>(&CAT[(long)i * 2048 + t * 4]) = ob;
}

// ---------------- G fill: bf16 logits only ----------------
__global__ __launch_bounds__(256) void gfill_k(
    const float* __restrict__ adj, const float* __restrict__ s1,
    const float* __restrict__ s2, unsigned short* __restrict__ Gb)
{
  int i = blockIdx.x, t = threadIdx.x;
  float s1i = s1[i];
  float p[16]; float sum = 0.f;
  #pragma unroll
  for (int c = 0; c < 4; ++c) {
    int j = c * 1024 + t * 4;
    float4 a = *reinterpret_cast<const float4*>(&adj[(long)i * Nn + j]);
    float4 sv = *reinterpret_cast<const float4*>(&s2[j]);
    float aa[4] = {a.x, a.y, a.z, a.w}, ss[4] = {sv.x, sv.y, sv.z, sv.w};
    #pragma unroll
    for (int k = 0; k < 4; ++k) {
      float f = (aa[k] > 0.f ? 1.f : 0.f) + ((j + k) == i ? 1.f : 0.f);
      float l = s1i + ss[k];
      l = l > 0.f ? l : 0.2f * l;
      float val = l * f - 1e9f * fmaxf(1.f - f, 0.f);
      float pp = expf(val);
      p[c * 4 + k] = pp; sum += pp;
    }
  }
  float den = block_reduce_sum(sum);
  float inv = 1.f / den;
  #pragma unroll
  for (int c = 0; c < 4; ++c) {
    int j = c * 1024 + t * 4;
    ushort4 ob = {f2bf(p[c * 4] * inv), f2bf(p[c * 4 + 1] * inv),
                  f2bf(p[c * 4 + 2] * inv), f2bf(p[c * 4 + 3] * inv)};
    *reinterpret_cast<ushort4*>(&Gb[(long)i * Nn + j]) = ob;
  }
}

// ---------------- A_hat denominators ----------------
__global__ __launch_bounds__(256) void amstats_k(
    const float* __restrict__ A, const float* __restrict__ Mm, float* __restrict__ aden)
{
  int e = blockIdx.x * 256 + threadIdx.x;
  int r0 = blockIdx.y * 128;
  float d = 0.f;
  for (int r = r0; r < r0 + 128; ++r) {
    long idx = (long)r * Ee + e;
    d += expf(A[idx] + Mm[idx]);
  }
  atomicAdd(&aden[e], d);
}

// ---------------- A_hat fill (transpose, bf16 out) ----------------
__global__ __launch_bounds__(256) void ahat_k(
    const float* __restrict__ Abuf, const float* __restrict__ Mm,
    const float* __restrict__ H, const float* __restrict__ aden,
    unsigned short* __restrict__ AhB)
{
  __shared__ float tile[64][65];
  int j0 = blockIdx.x * 64, e0 = blockIdx.y * 64;
  int te = threadIdx.x & 63;
  int tq = threadIdx.x >> 6;
  int e = e0 + te;
  float inv = 1.f / aden[e];
  for (int jj = tq; jj < 64; jj += 4) {
    long idx = (long)(j0 + jj) * Ee + e;
    float val = (H[idx] > 0.f) ? expf(Abuf[idx] + Mm[idx]) * inv : 0.f;
    tile[te][jj] = val;
  }
  __syncthreads();
  for (int ee = tq; ee < 64; ee += 4)
    AhB[(long)(e0 + ee) * Nn + j0 + te] = f2bf(tile[ee][te]);
}

// ---------------- B_hat: bf16 out ----------------
__global__ __launch_bounds__(256) void bhat_k(const float* __restrict__ Bbuf,
                                              const float* __restrict__ Mm,
                                              const float* __restrict__ H,
                                              unsigned short* __restrict__ Bb2)
{
  int i = blockIdx.x, t = threadIdx.x;
  long base = (long)i * Ee + t * 4;
  float4 b = *reinterpret_cast<const float4*>(&Bbuf[base]);
  float4 m = *reinterpret_cast<const float4*>(&Mm[base]);
  float4 h = *reinterpret_cast<const float4*>(&H[base]);
  float bb[4] = {b.x, b.y, b.z, b.w}, mm2[4] = {m.x, m.y, m.z, m.w}, hh[4] = {h.x, h.y, h.z, h.w};
  float p[4]; float s = 0.f;
  #pragma unroll
  for (int k = 0; k < 4; ++k) { p[k] = expf(bb[k] + mm2[k]); s += p[k]; }
  float den = block_reduce_sum(s);
  float inv = 1.f / den;
  #pragma unroll
  for (int k = 0; k < 4; ++k) p[k] = hh[k] > 0.f ? p[k] * inv : 0.f;
  ushort4 ob = {f2bf(p[0]), f2bf(p[1]), f2bf(p[2]), f2bf(p[3])};
  *reinterpret_cast<ushort4*>(&Bb2[base]) = ob;
}

// ---------------- launcher ----------------
extern "C" void kernel_launch(void* const* d_in, const int* in_sizes, int n_in,
                              void* d_out, int out_size, void* d_ws, size_t ws_size,
                              hipStream_t stream) {
  const float* x    = (const float*)d_in[0];
  const float* H    = (const float*)d_in[1];
  const float* adj  = (const float*)d_in[2];
  const float* W_he = (const float*)d_in[3];
  const float* u    = (const float*)d_in[4];
  const float* W_e  = (const float*)d_in[5];
  const float* W_n  = (const float*)d_in[6];
  const float* W_g  = (const float*)d_in[7];
  const float* a_g  = (const float*)d_in[8];
  float* out = (float*)d_out;
  float* ws  = (float*)d_ws;
  (void)in_sizes; (void)n_in; (void)out_size; (void)ws_size;

  size_t off = 0;
  auto alloc = [&](size_t n) { float* p = ws + off; off += n; return p; };
  float* hcat   = alloc((size_t)Nn * 768);
  float* esc    = alloc(Nn);
  float* s1     = alloc(Nn);
  float* s2     = alloc(Nn);
  float* colden = alloc(Ee);   // colden,cnt,aden,rowsum contiguous -> one memset
  float* cnt    = alloc(Ee);
  float* aden   = alloc(Ee);
  float* rowsum = alloc(Nn);
  float* e_repr = alloc((size_t)Ee * Dd);   // e_repr,e_mix contiguous -> one memset
  float* e_mix  = alloc((size_t)Ee * Dd);
  float* heb    = alloc((size_t)Ee * Dd);
  float* tmp_ew = alloc((size_t)Ee * Dd);
  float* Abuf   = alloc((size_t)Nn * Ee);
  float* Bbuf   = alloc((size_t)Nn * Ee);
  float* Mm     = alloc((size_t)Nn * Ee);
  unsigned short* Gb    = (unsigned short*)alloc((size_t)Nn * Nn / 2);
  unsigned short* CAT   = (unsigned short*)alloc((size_t)Nn * 2048 / 2);
  unsigned short* Hbt   = (unsigned short*)alloc((size_t)Ee * Nn / 2);
  unsigned short* AbT   = (unsigned short*)alloc((size_t)Ee * Nn / 2);
  unsigned short* AhB   = (unsigned short*)alloc((size_t)Ee * Nn / 2);
  unsigned short* hheT  = (unsigned short*)alloc((size_t)Dd * Nn / 2);
  unsigned short* hgT   = (unsigned short*)alloc((size_t)Dd * Nn / 2);
  unsigned short* tewT  = (unsigned short*)alloc((size_t)Dd * Ee / 2);
  unsigned short* Bb2   = (unsigned short*)alloc((size_t)Nn * Ee / 2);
  unsigned short* xb    = (unsigned short*)alloc((size_t)Nn * Dd / 2);
  unsigned short* WcTb  = (unsigned short*)alloc((size_t)768 * Dd / 2);
  unsigned short* hcatB = (unsigned short*)alloc((size_t)Nn * 768 / 2);
  unsigned short* hebB  = (unsigned short*)alloc((size_t)Ee * Dd / 2);

  hipMemsetAsync(colden, 0, (3 * Ee + Nn) * sizeof(float), stream);
  hipMemsetAsync(e_repr, 0, 2 * (size_t)Ee * Dd * sizeof(float), stream);
  hipMemsetAsync(Mm, 0, (size_t)Nn * Ee * sizeof(float), stream);
  hipMemsetAsync(out, 0, 2 * (size_t)Nn * Dd * sizeof(float), stream);

  auto gbt = [&](const unsigned short* A, const unsigned short* B, float* C, unsigned short* Cb,
                 int M, int N, int K, int lda, int ldb, float alpha) {
    gemm_bt_bf16<<<dim3(M / 128, N / 128), 256, 0, stream>>>(A, B, C, Cb, M, N, K, lda, ldb, alpha);
  };
  auto gs64 = [&](const unsigned short* A, const unsigned short* B, float* C,
                  int M, int N, int K, int KS) {
    gemm64s_bt_bf16<<<dim3(M / 64, N / 64, K / KS), 256, 0, stream>>>(A, B, C, M, N, K, KS);
  };
  auto tcvt = [&](const float* in, unsigned short* o, int R, int S, int cols, const float* cd) {
    tcvt_k<<<dim3(R / 64, cols / 64), 256, 0, stream>>>(in, o, R, S, cd);
  };

  // bf16 copies of x and W^T slices
  cvt_bf16_k<<<(Nn * Dd) / 2048, 256, 0, stream>>>(x, xb, (long)Nn * Dd);
  tcvt(W_he, WcTb, Dd, Dd, Dd, nullptr);
  tcvt(W_n, WcTb + 256 * 256, Dd, Dd, Dd, nullptr);
  tcvt(W_g, WcTb + 2 * 256 * 256, Dd, Dd, Dd, nullptr);
  // fused projections: hcat(+hcatB) = x @ [W_he|W_n|W_g]  (bf16 MFMA)
  gbt(xb, WcTb, hcat, hcatB, Nn, 768, Dd, Dd, Dd, 1.f);
  rowdots_k<<<Nn, 256, 0, stream>>>(hcat, u, a_g, esc, s1, s2);
  // A column softmax
  colstats_k<<<dim3(Ee / 256, 32), 256, 0, stream>>>(H, esc, colden, cnt);
  fillA_k<<<dim3(Nn / 64, Ee / 64), 256, 0, stream>>>(H, esc, colden, Abuf, CAT, AbT);
  // e_repr = A^T @ h_he  (split-K, 512 blocks)
  tcvt(hcat, hheT, Nn, 768, Dd, nullptr);
  gs64(AbT, hheT, e_repr, Ee, Dd, Nn, 512);
  // heb = e_repr @ W_e (f32, + bf16 copy)
  gemm64_k<<<dim3(Ee / 64, Dd / 64), 256, 0, stream>>>(e_repr, W_e, heb, hebB, Ee, Dd, Dd, Dd, 1, Dd, 1);
  // Bsc = (hn @ heb^T)/16 (bf16 MFMA), then row softmax
  gbt(hcatB + 256, hebB, Bbuf, nullptr, Nn, Ee, Dd, 768, Dd, 0.0625f);
  brow_k<<<Nn, 256, 0, stream>>>(Bbuf, H, CAT);
  // G softmax -> bf16 logits
  gfill_k<<<Nn, 256, 0, stream>>>(adj, s1, s2, Gb);
  // M = G @ (H/he_sz) : pre-scaled Hbt, split-K atomic (512 blocks)
  tcvt(H, Hbt, Nn, Ee, Ee, cnt);
  gemm_bts_bf16<<<dim3(Nn / 128, Ee / 128, 2), 256, 0, stream>>>(Gb, Hbt, Mm, Nn, Ee, Nn, Nn, Nn, 2048);
  // symmetric fused Gram: Gb = exp(Gb + BB^T + AA^T) (unnormalized), rowsum
  gemm_gram_k<<<dim3(Nn / 128, Nn / 128), 256, 0, stream>>>(CAT, Gb, rowsum);
  // A_hat
  amstats_k<<<dim3(Ee / 256, 32), 256, 0, stream>>>(Abuf, Mm, aden);
  ahat_k<<<dim3(Nn / 64, Ee / 64), 256, 0, stream>>>(Abuf, Mm, H, aden, AhB);
  // e_mix = A_hat @ h_he ; tmp_ew = e_mix @ W_e
  gs64(AhB, hheT, e_mix, Ee, Dd, Nn, 512);
  gemm64_k<<<dim3(Ee / 64, Dd / 64), 256, 0, stream>>>(e_mix, W_e, tmp_ew, nullptr, Ee, Dd, Dd, Dd, 1, Dd, 1);
  // B_hat, z_h
  bhat_k<<<Nn, 256, 0, stream>>>(Bbuf, Mm, H, Bb2);
  tcvt(tmp_ew, tewT, Ee, Dd, Dd, nullptr);
  gs64(Bb2, tewT, out, Nn, Dd, Ee, 512);
  // z_g (unnormalized), then row-scale + elu
  tcvt(hcat + 512, hgT, Nn, 768, Dd, nullptr);
  gs64(Gb, hgT, out + (size_t)Nn * Dd, Nn, Dd, Nn, 1024);
  elu_rows_k<<<(2 * Nn * Dd) / 1024, 256, 0, stream>>>(out, rowsum);
}

// Round 7
// 587.309 us; speedup vs baseline: 4.6310x; 1.0526x over previous
//
#include <hip/hip_runtime.h>
#include <math.h>
#include <stdint.h>

#define Nn 4096
#define Ee 1024
#define Dd 256

typedef __attribute__((ext_vector_type(8))) __bf16 bf16x8;
typedef __attribute__((ext_vector_type(4))) float f32x4;
typedef __attribute__((ext_vector_type(8))) unsigned short u16x8;

__device__ __forceinline__ unsigned short f2bf(float f) {
  unsigned int u = __float_as_uint(f);
  unsigned int r = (u + 0x7fffu + ((u >> 16) & 1u)) >> 16;
  return (unsigned short)r;
}
__device__ __forceinline__ float bf2f(unsigned short u) {
  return __uint_as_float(((unsigned int)u) << 16);
}

__device__ __forceinline__ void gload_lds16(const void* g, void* l) {
  __builtin_amdgcn_global_load_lds(
      (__attribute__((address_space(1))) void*)const_cast<void*>(g),
      (__attribute__((address_space(3))) void*)l, 16, 0, 0);
}

__device__ __forceinline__ float block_reduce_sum(float v) {
  __shared__ float sh[4];
  #pragma unroll
  for (int o = 32; o > 0; o >>= 1) v += __shfl_down(v, o);
  int lane = threadIdx.x & 63, w = threadIdx.x >> 6;
  if (lane == 0) sh[w] = v;
  __syncthreads();
  float s = sh[0] + sh[1] + sh[2] + sh[3];
  __syncthreads();
  return s;
}

// ---------------- bf16 MFMA GEMM: C = alpha*(A*B^T), 128x128, BK=32 (+opt bf16 out) ----------------
__global__ __launch_bounds__(256) void gemm_bt_bf16(
    const unsigned short* __restrict__ Ab, const unsigned short* __restrict__ Bb,
    float* __restrict__ Cp, unsigned short* __restrict__ Cb,
    int M, int N, int K, int lda, int ldb, float alpha)
{
  __shared__ unsigned short As[2][128 * 32];
  __shared__ unsigned short Bs[2][128 * 32];
  const int tid = threadIdx.x;
  const int m0 = blockIdx.x * 128, n0 = blockIdx.y * 128;
  const int wave = tid >> 6, lane = tid & 63;
  const int wr = (wave >> 1) * 64, wc = (wave & 1) * 64;
  const int l16 = lane & 15, lq = lane >> 4;
  f32x4 acc[4][4] = {};
  const int NT = K >> 5;

  auto stage = [&](int buf, int kt) {
    const int k0 = kt * 32;
    #pragma unroll
    for (int i = 0; i < 2; ++i) {
      int t2 = tid + i * 256;
      int r = t2 >> 2, c = (t2 & 3) * 8;
      gload_lds16(Ab + (size_t)(m0 + r) * lda + k0 + c, &As[buf][t2 * 8]);
    }
    #pragma unroll
    for (int i = 0; i < 2; ++i) {
      int t2 = tid + i * 256;
      int r = t2 >> 2, c = (t2 & 3) * 8;
      gload_lds16(Bb + (size_t)(n0 + r) * ldb + k0 + c, &Bs[buf][t2 * 8]);
    }
  };

  stage(0, 0);
  __syncthreads();
  int buf = 0;
  for (int kt = 0; kt < NT; ++kt) {
    if (kt + 1 < NT) stage(buf ^ 1, kt + 1);
    bf16x8 af[4], bfr[4];
    #pragma unroll
    for (int m = 0; m < 4; ++m)
      af[m] = *reinterpret_cast<const bf16x8*>(&As[buf][(wr + m * 16 + l16) * 32 + lq * 8]);
    #pragma unroll
    for (int n = 0; n < 4; ++n)
      bfr[n] = *reinterpret_cast<const bf16x8*>(&Bs[buf][(wc + n * 16 + l16) * 32 + lq * 8]);
    #pragma unroll
    for (int m = 0; m < 4; ++m)
      #pragma unroll
      for (int n = 0; n < 4; ++n)
        acc[m][n] = __builtin_amdgcn_mfma_f32_16x16x32_bf16(af[m], bfr[n], acc[m][n], 0, 0, 0);
    __syncthreads();
    buf ^= 1;
  }
  #pragma unroll
  for (int m = 0; m < 4; ++m)
    #pragma unroll
    for (int n = 0; n < 4; ++n) {
      int col = n0 + wc + n * 16 + l16;
      #pragma unroll
      for (int q = 0; q < 4; ++q) {
        int row = m0 + wr + m * 16 + lq * 4 + q;
        size_t idx = (size_t)row * N + col;
        float v = acc[m][n][q] * alpha;
        Cp[idx] = v;
        if (Cb) Cb[idx] = f2bf(v);
      }
    }
}

// ---------------- bf16 MFMA GEMM, 128x128 tile, BK=32, split-K atomicAdd ----------------
__global__ __launch_bounds__(256) void gemm_bts_bf16(
    const unsigned short* __restrict__ Ab, const unsigned short* __restrict__ Bb,
    float* __restrict__ Cp, int M, int N, int K, int lda, int ldb, int KS)
{
  __shared__ unsigned short As[2][128 * 32];
  __shared__ unsigned short Bs[2][128 * 32];
  const int tid = threadIdx.x;
  const int m0 = blockIdx.x * 128, n0 = blockIdx.y * 128;
  const int kbase = blockIdx.z * KS;
  const int wave = tid >> 6, lane = tid & 63;
  const int wr = (wave >> 1) * 64, wc = (wave & 1) * 64;
  const int l16 = lane & 15, lq = lane >> 4;
  f32x4 acc[4][4] = {};
  const int NT = KS >> 5;

  auto stage = [&](int buf, int kt) {
    const int k0 = kbase + kt * 32;
    #pragma unroll
    for (int i = 0; i < 2; ++i) {
      int t2 = tid + i * 256;
      int r = t2 >> 2, c = (t2 & 3) * 8;
      gload_lds16(Ab + (size_t)(m0 + r) * lda + k0 + c, &As[buf][t2 * 8]);
    }
    #pragma unroll
    for (int i = 0; i < 2; ++i) {
      int t2 = tid + i * 256;
      int r = t2 >> 2, c = (t2 & 3) * 8;
      gload_lds16(Bb + (size_t)(n0 + r) * ldb + k0 + c, &Bs[buf][t2 * 8]);
    }
  };

  stage(0, 0);
  __syncthreads();
  int buf = 0;
  for (int kt = 0; kt < NT; ++kt) {
    if (kt + 1 < NT) stage(buf ^ 1, kt + 1);
    bf16x8 af[4], bfr[4];
    #pragma unroll
    for (int m = 0; m < 4; ++m)
      af[m] = *reinterpret_cast<const bf16x8*>(&As[buf][(wr + m * 16 + l16) * 32 + lq * 8]);
    #pragma unroll
    for (int n = 0; n < 4; ++n)
      bfr[n] = *reinterpret_cast<const bf16x8*>(&Bs[buf][(wc + n * 16 + l16) * 32 + lq * 8]);
    #pragma unroll
    for (int m = 0; m < 4; ++m)
      #pragma unroll
      for (int n = 0; n < 4; ++n)
        acc[m][n] = __builtin_amdgcn_mfma_f32_16x16x32_bf16(af[m], bfr[n], acc[m][n], 0, 0, 0);
    __syncthreads();
    buf ^= 1;
  }
  #pragma unroll
  for (int m = 0; m < 4; ++m)
    #pragma unroll
    for (int n = 0; n < 4; ++n) {
      int col = n0 + wc + n * 16 + l16;
      #pragma unroll
      for (int q = 0; q < 4; ++q) {
        int row = m0 + wr + m * 16 + lq * 4 + q;
        atomicAdd(&Cp[(size_t)row * N + col], acc[m][n][q]);
      }
    }
}

// ---------------- symmetric fused Gram (packed triangular grid, 528 blocks) ----------------
__global__ __launch_bounds__(256) void gemm_gram_k(
    const unsigned short* __restrict__ CAT,   // [Nn][2048] bf16
    unsigned short* __restrict__ Gb,          // in: bf16 logits; out: exp(logit)
    float* __restrict__ rowsum)               // pre-zeroed [Nn]
{
  int bid = blockIdx.x;
  int by = (int)((sqrtf(8.f * bid + 1.f) - 1.f) * 0.5f);
  while ((by + 1) * (by + 2) / 2 <= bid) ++by;
  while (by * (by + 1) / 2 > bid) --by;
  int bx = bid - by * (by + 1) / 2;
  const int K = 2048;
  __shared__ unsigned short SM[17024];
  unsigned short* Asb = SM;
  unsigned short* Bsb = SM + 8192;
  const int tid = threadIdx.x;
  const int m0 = bx * 128, n0 = by * 128;
  const int wave = tid >> 6, lane = tid & 63;
  const int wr = (wave >> 1) * 64, wc = (wave & 1) * 64;
  const int l16 = lane & 15, lq = lane >> 4;
  f32x4 acc[4][4] = {};
  const int NT = K >> 5;

  auto stage = [&](int buf, int kt) {
    const int k0 = kt * 32;
    #pragma unroll
    for (int i = 0; i < 2; ++i) {
      int t2 = tid + i * 256;
      int r = t2 >> 2, c = (t2 & 3) * 8;
      gload_lds16(CAT + (size_t)(m0 + r) * K + k0 + c, Asb + buf * 4096 + t2 * 8);
    }
    #pragma unroll
    for (int i = 0; i < 2; ++i) {
      int t2 = tid + i * 256;
      int r = t2 >> 2, c = (t2 & 3) * 8;
      gload_lds16(CAT + (size_t)(n0 + r) * K + k0 + c, Bsb + buf * 4096 + t2 * 8);
    }
  };

  stage(0, 0);
  __syncthreads();
  int buf = 0;
  for (int kt = 0; kt < NT; ++kt) {
    if (kt + 1 < NT) stage(buf ^ 1, kt + 1);
    bf16x8 af[4], bfr[4];
    #pragma unroll
    for (int m = 0; m < 4; ++m)
      af[m] = *reinterpret_cast<const bf16x8*>(Asb + buf * 4096 + (wr + m * 16 + l16) * 32 + lq * 8);
    #pragma unroll
    for (int n = 0; n < 4; ++n)
      bfr[n] = *reinterpret_cast<const bf16x8*>(Bsb + buf * 4096 + (wc + n * 16 + l16) * 32 + lq * 8);
    #pragma unroll
    for (int m = 0; m < 4; ++m)
      #pragma unroll
      for (int n = 0; n < 4; ++n)
        acc[m][n] = __builtin_amdgcn_mfma_f32_16x16x32_bf16(af[m], bfr[n], acc[m][n], 0, 0, 0);
    __syncthreads();
    buf ^= 1;
  }
  // normal epilogue (upper/diag region)
  #pragma unroll
  for (int m = 0; m < 4; ++m)
    #pragma unroll
    for (int q = 0; q < 4; ++q) {
      int row = m0 + wr + m * 16 + lq * 4 + q;
      float s = 0.f;
      #pragma unroll
      for (int n = 0; n < 4; ++n) {
        int col = n0 + wc + n * 16 + l16;
        size_t idx = (size_t)row * Nn + col;
        float e = expf(bf2f(Gb[idx]) + acc[m][n][q]);
        Gb[idx] = f2bf(e);
        s += e;
      }
      s += __shfl_xor(s, 1); s += __shfl_xor(s, 2);
      s += __shfl_xor(s, 4); s += __shfl_xor(s, 8);
      if (l16 == 0) atomicAdd(&rowsum[row], s);
    }
  if (bx == by) return;

  // transposed epilogue (lower region): mirror tile via LDS
  __syncthreads();
  unsigned short* Tg = SM;  // [128][132]
  {
    int cc = tid >> 1, r0 = (tid & 1) * 64;
    const unsigned short* src = Gb + (size_t)(n0 + cc) * Nn + m0 + r0;
    unsigned short* dst = Tg + cc * 132 + r0;
    #pragma unroll
    for (int v = 0; v < 8; ++v)
      *reinterpret_cast<u16x8*>(dst + v * 8) = *reinterpret_cast<const u16x8*>(src + v * 8);
  }
  __syncthreads();
  #pragma unroll
  for (int n = 0; n < 4; ++n) {
    int ccl = wc + n * 16 + l16;
    float cs = 0.f;
    #pragma unroll
    for (int m = 0; m < 4; ++m) {
      int sa = ccl * 132 + wr + m * 16 + lq * 4;
      ushort4 lg = *reinterpret_cast<const ushort4*>(&Tg[sa]);
      ushort4 eo;
      float e0 = expf(bf2f(lg.x) + acc[m][n][0]); eo.x = f2bf(e0); cs += e0;
      float e1 = expf(bf2f(lg.y) + acc[m][n][1]); eo.y = f2bf(e1); cs += e1;
      float e2 = expf(bf2f(lg.z) + acc[m][n][2]); eo.z = f2bf(e2); cs += e2;
      float e3 = expf(bf2f(lg.w) + acc[m][n][3]); eo.w = f2bf(e3); cs += e3;
      *reinterpret_cast<ushort4*>(&Tg[sa]) = eo;
    }
    cs += __shfl_xor(cs, 16); cs += __shfl_xor(cs, 32);
    if (lq == 0) atomicAdd(&rowsum[n0 + ccl], cs);
  }
  __syncthreads();
  {
    int cc = tid >> 1, r0 = (tid & 1) * 64;
    const unsigned short* src = Tg + cc * 132 + r0;
    unsigned short* dst = Gb + (size_t)(n0 + cc) * Nn + m0 + r0;
    #pragma unroll
    for (int v = 0; v < 8; ++v)
      *reinterpret_cast<u16x8*>(dst + v * 8) = *reinterpret_cast<const u16x8*>(src + v * 8);
  }
}

// ---------------- bf16 MFMA GEMM, 64x64 tile, BK=64, split-K via atomicAdd ----------------
__global__ __launch_bounds__(256) void gemm64s_bt_bf16(
    const unsigned short* __restrict__ Ab, const unsigned short* __restrict__ Bb,
    float* __restrict__ Cp, int M, int N, int K, int KS)
{
  __shared__ unsigned short As[2][64 * 64];
  __shared__ unsigned short Bs[2][64 * 64];
  const int tid = threadIdx.x;
  const int m0 = blockIdx.x * 64, n0 = blockIdx.y * 64;
  const int kbase = blockIdx.z * KS;
  const int wave = tid >> 6, lane = tid & 63;
  const int wr = (wave >> 1) * 32, wc = (wave & 1) * 32;
  const int l16 = lane & 15, lq = lane >> 4;
  f32x4 acc[2][2] = {};
  const int NT = KS >> 6;

  auto stage = [&](int buf, int kt) {
    const int k0 = kbase + kt * 64;
    #pragma unroll
    for (int i = 0; i < 2; ++i) {
      int t2 = tid + i * 256;
      int r = t2 >> 3, c = (t2 & 7) * 8;
      gload_lds16(Ab + (size_t)(m0 + r) * K + k0 + c, &As[buf][t2 * 8]);
    }
    #pragma unroll
    for (int i = 0; i < 2; ++i) {
      int t2 = tid + i * 256;
      int r = t2 >> 3, c = (t2 & 7) * 8;
      gload_lds16(Bb + (size_t)(n0 + r) * K + k0 + c, &Bs[buf][t2 * 8]);
    }
  };

  stage(0, 0);
  __syncthreads();
  int buf = 0;
  for (int kt = 0; kt < NT; ++kt) {
    if (kt + 1 < NT) stage(buf ^ 1, kt + 1);
    bf16x8 af[2][2], bfr[2][2];
    #pragma unroll
    for (int m = 0; m < 2; ++m)
      #pragma unroll
      for (int ks = 0; ks < 2; ++ks)
        af[m][ks] = *reinterpret_cast<const bf16x8*>(
            &As[buf][(wr + m * 16 + l16) * 64 + ks * 32 + lq * 8]);
    #pragma unroll
    for (int n = 0; n < 2; ++n)
      #pragma unroll
      for (int ks = 0; ks < 2; ++ks)
        bfr[n][ks] = *reinterpret_cast<const bf16x8*>(
            &Bs[buf][(wc + n * 16 + l16) * 64 + ks * 32 + lq * 8]);
    #pragma unroll
    for (int m = 0; m < 2; ++m)
      #pragma unroll
      for (int n = 0; n < 2; ++n)
        #pragma unroll
        for (int ks = 0; ks < 2; ++ks)
          acc[m][n] = __builtin_amdgcn_mfma_f32_16x16x32_bf16(af[m][ks], bfr[n][ks], acc[m][n], 0, 0, 0);
    __syncthreads();
    buf ^= 1;
  }
  #pragma unroll
  for (int m = 0; m < 2; ++m)
    #pragma unroll
    for (int n = 0; n < 2; ++n) {
      int col = n0 + wc + n * 16 + l16;
      #pragma unroll
      for (int q = 0; q < 4; ++q) {
        int row = m0 + wr + m * 16 + lq * 4 + q;
        atomicAdd(&Cp[(size_t)row * N + col], acc[m][n][q]);
      }
    }
}

// ---------------- f32 -> bf16 convert ----------------
__global__ __launch_bounds__(256) void cvt_bf16_k(const float* __restrict__ in,
                                                  unsigned short* __restrict__ out, long n) {
  long i = ((long)blockIdx.x * 256 + threadIdx.x) * 8;
  if (i + 8 > n) return;
  float4 a = *reinterpret_cast<const float4*>(&in[i]);
  float4 b = *reinterpret_cast<const float4*>(&in[i + 4]);
  u16x8 o;
  o[0] = f2bf(a.x); o[1] = f2bf(a.y); o[2] = f2bf(a.z); o[3] = f2bf(a.w);
  o[4] = f2bf(b.x); o[5] = f2bf(b.y); o[6] = f2bf(b.z); o[7] = f2bf(b.w);
  *reinterpret_cast<u16x8*>(&out[i]) = o;
}

// ---------------- transpose-convert f32 [R rows, S stride] -> bf16 [C][R], opt col scale ----------------
__global__ __launch_bounds__(256) void tcvt_k(const float* __restrict__ in,
                                              unsigned short* __restrict__ outT, int R, int S,
                                              const float* __restrict__ coldiv) {
  __shared__ unsigned short tile[64][65];
  int r0 = blockIdx.x * 64, c0 = blockIdx.y * 64;
  int t = threadIdx.x & 63, q = threadIdx.x >> 6;
  float sc = coldiv ? 1.f / fmaxf(coldiv[c0 + t], 1.f) : 1.f;
  for (int rr = q; rr < 64; rr += 4)
    tile[t][rr] = f2bf(in[(long)(r0 + rr) * S + c0 + t] * sc);
  __syncthreads();
  for (int cc = q; cc < 64; cc += 4)
    outT[(long)(c0 + cc) * R + r0 + t] = tile[cc][t];
}

// ---------------- final: scale z_g rows by 1/rowsum, elu both halves ----------------
__global__ __launch_bounds__(256) void elu_rows_k(float* __restrict__ p,
                                                  const float* __restrict__ rowsum) {
  long i = ((long)blockIdx.x * 256 + threadIdx.x) * 4;
  float4 v = *reinterpret_cast<const float4*>(&p[i]);
  float sc = 1.f;
  long half = (long)Nn * Dd;
  if (i >= half) sc = 1.f / rowsum[(i - half) >> 8];
  v.x *= sc; v.y *= sc; v.z *= sc; v.w *= sc;
  v.x = v.x > 0.f ? v.x : expm1f(v.x);
  v.y = v.y > 0.f ? v.y : expm1f(v.y);
  v.z = v.z > 0.f ? v.z : expm1f(v.z);
  v.w = v.w > 0.f ? v.w : expm1f(v.w);
  *reinterpret_cast<float4*>(&p[i]) = v;
}

// ---------------- generic strided f32 GEMM, 64x64 tile (Wp only) ----------------
__global__ __launch_bounds__(256) void gemm64_k(
    const float* __restrict__ Ap, const float* __restrict__ Bp, float* __restrict__ Cp,
    int M, int N, int K, int Asm, int Ask, int Bsk, int Bsn)
{
  __shared__ alignas(16) float As[16][68];
  __shared__ alignas(16) float Bs[16][68];
  const int tid = threadIdx.x;
  const int tx = tid & 15, ty = tid >> 4;
  const int m0 = blockIdx.x * 64, n0 = blockIdx.y * 64;
  float acc[4][4] = {};
  for (int k0 = 0; k0 < K; k0 += 16) {
    if (Ask == 1) {
      int mm = tid >> 2, kk = (tid & 3) << 2;
      float4 v = *reinterpret_cast<const float4*>(&Ap[(long)(m0 + mm) * Asm + k0 + kk]);
      As[kk + 0][mm] = v.x; As[kk + 1][mm] = v.y; As[kk + 2][mm] = v.z; As[kk + 3][mm] = v.w;
    } else {
      int kk = tid >> 4, mm = (tid & 15) << 2;
      *reinterpret_cast<float4*>(&As[kk][mm]) =
          *reinterpret_cast<const float4*>(&Ap[(long)(k0 + kk) * Ask + m0 + mm]);
    }
    if (Bsn == 1) {
      int kk = tid >> 4, nn = (tid & 15) << 2;
      *reinterpret_cast<float4*>(&Bs[kk][nn]) =
          *reinterpret_cast<const float4*>(&Bp[(long)(k0 + kk) * Bsk + n0 + nn]);
    } else {
      int nn = tid >> 2, kk = (tid & 3) << 2;
      float4 v = *reinterpret_cast<const float4*>(&Bp[(long)(n0 + nn) * Bsn + k0 + kk]);
      Bs[kk + 0][nn] = v.x; Bs[kk + 1][nn] = v.y; Bs[kk + 2][nn] = v.z; Bs[kk + 3][nn] = v.w;
    }
    __syncthreads();
    #pragma unroll
    for (int kk = 0; kk < 16; ++kk) {
      float4 av = *reinterpret_cast<const float4*>(&As[kk][ty << 2]);
      float4 bv = *reinterpret_cast<const float4*>(&Bs[kk][tx << 2]);
      float a[4] = {av.x, av.y, av.z, av.w};
      float b[4] = {bv.x, bv.y, bv.z, bv.w};
      #pragma unroll
      for (int r = 0; r < 4; ++r)
        #pragma unroll
        for (int c = 0; c < 4; ++c) acc[r][c] = fmaf(a[r], b[c], acc[r][c]);
    }
    __syncthreads();
  }
  #pragma unroll
  for (int r = 0; r < 4; ++r) {
    long base = (long)(m0 + (ty << 2) + r) * N + n0 + (tx << 2);
    float4 o = {acc[r][0], acc[r][1], acc[r][2], acc[r][3]};
    *reinterpret_cast<float4*>(&Cp[base]) = o;
  }
}

// ---------------- sc/s1/s2 row dots (hcat4 stride 1024) ----------------
__global__ __launch_bounds__(256) void rowdots_k(
    const float* __restrict__ hcat, const float* __restrict__ u, const float* __restrict__ a_g,
    float* __restrict__ esc, float* __restrict__ s1, float* __restrict__ s2)
{
  int i = blockIdx.x, t = threadIdx.x;
  float hh = hcat[(long)i * 1024 + t];
  float hg = hcat[(long)i * 1024 + 512 + t];
  float d0 = block_reduce_sum(hh * u[t]);
  float d1 = block_reduce_sum(hg * a_g[t]);
  float d2 = block_reduce_sum(hg * a_g[Dd + t]);
  if (t == 0) {
    esc[i] = expf(d0 * 0.0625f);
    s1[i] = d1;
    s2[i] = d2;
  }
}

// ---------------- column softmax stats for A ----------------
__global__ __launch_bounds__(256) void colstats_k(
    const float* __restrict__ H, const float* __restrict__ esc,
    float* __restrict__ colden, float* __restrict__ cnt)
{
  int e = blockIdx.x * 256 + threadIdx.x;
  int r0 = blockIdx.y * 128;
  float d = 0.f, c = 0.f;
  for (int r = r0; r < r0 + 128; ++r) {
    float h = H[(long)r * Ee + e];
    if (h > 0.f) { d += esc[r]; c += 1.f; }
  }
  atomicAdd(&colden[e], d);
  atomicAdd(&cnt[e], c);
}

// ---------------- A fill (tile): CAT A-half bf16 + AbT bf16 (no f32 A) ----------------
__global__ __launch_bounds__(256) void fillA_k(
    const float* __restrict__ H, const float* __restrict__ esc,
    const float* __restrict__ colden,
    unsigned short* __restrict__ CAT, unsigned short* __restrict__ AbT)
{
  __shared__ unsigned short tile[64][68];
  int r0 = blockIdx.x * 64, e0 = blockIdx.y * 64;
  int te = threadIdx.x & 63, tq = threadIdx.x >> 6;
  float cd = colden[e0 + te];
  for (int rr = tq; rr < 64; rr += 4) {
    long idx = (long)(r0 + rr) * Ee + e0 + te;
    float h = H[idx];
    float val = h > 0.f ? esc[r0 + rr] / cd : 0.f;
    unsigned short vb = f2bf(val);
    CAT[(long)(r0 + rr) * 2048 + 1024 + e0 + te] = vb;
    tile[te][rr] = vb;
  }
  __syncthreads();
  for (int ee = tq; ee < 64; ee += 4)
    AbT[(long)(e0 + ee) * Nn + r0 + te] = tile[ee][te];
}

// ---------------- B row softmax: CAT B-half bf16 only ----------------
__global__ __launch_bounds__(256) void brow_k(const float* __restrict__ Bbuf,
                                              const float* __restrict__ H,
                                              unsigned short* __restrict__ CAT)
{
  int i = blockIdx.x, t = threadIdx.x;
  long base = (long)i * Ee + t * 4;
  float4 raw = *reinterpret_cast<const float4*>(&Bbuf[base]);
  float4 h = *reinterpret_cast<const float4*>(&H[base]);
  float rr[4] = {raw.x, raw.y, raw.z, raw.w}, hh[4] = {h.x, h.y, h.z, h.w};
  float p[4]; float s = 0.f;
  #pragma unroll
  for (int k = 0; k < 4; ++k) { p[k] = hh[k] > 0.f ? expf(rr[k]) : 0.f; s += p[k]; }
  float den = block_reduce_sum(s);
  float inv = den > 0.f ? 1.f / den : 0.f;
  ushort4 ob = {f2bf(p[0] * inv), f2bf(p[1] * inv), f2bf(p[2] * inv), f2bf(p[3] * inv)};
  *reinterpret_cast<ushort4*>(&CAT[(long)i * 2048 + t * 4]) = ob;
}

// ---------------- G fill: bf16 logits only ----------------
__global__ __launch_bounds__(256) void gfill_k(
    const float* __restrict__ adj, const float* __restrict__ s1,
    const float* __restrict__ s2, unsigned short* __restrict__ Gb)
{
  int i = blockIdx.x, t = threadIdx.x;
  float s1i = s1[i];
  float p[16]; float sum = 0.f;
  #pragma unroll
  for (int c = 0; c < 4; ++c) {
    int j = c * 1024 + t * 4;
    float4 a = *reinterpret_cast<const float4*>(&adj[(long)i * Nn + j]);
    float4 sv = *reinterpret_cast<const float4*>(&s2[j]);
    float aa[4] = {a.x, a.y, a.z, a.w}, ss[4] = {sv.x, sv.y, sv.z, sv.w};
    #pragma unroll
    for (int k = 0; k < 4; ++k) {
      float f = (aa[k] > 0.f ? 1.f : 0.f) + ((j + k) == i ? 1.f : 0.f);
      float l = s1i + ss[k];
      l = l > 0.f ? l : 0.2f * l;
      float val = l * f - 1e9f * fmaxf(1.f - f, 0.f);
      float pp = expf(val);
      p[c * 4 + k] = pp; sum += pp;
    }
  }
  float den = block_reduce_sum(sum);
  float inv = 1.f / den;
  #pragma unroll
  for (int c = 0; c < 4; ++c) {
    int j = c * 1024 + t * 4;
    ushort4 ob = {f2bf(p[c * 4] * inv), f2bf(p[c * 4 + 1] * inv),
                  f2bf(p[c * 4 + 2] * inv), f2bf(p[c * 4 + 3] * inv)};
    *reinterpret_cast<ushort4*>(&Gb[(long)i * Nn + j]) = ob;
  }
}

// ---------------- A_hat denominators (A from CAT bf16) ----------------
__global__ __launch_bounds__(256) void amstats_k(
    const unsigned short* __restrict__ CAT, const float* __restrict__ Mm,
    float* __restrict__ aden)
{
  int e = blockIdx.x * 256 + threadIdx.x;
  int r0 = blockIdx.y * 128;
  float d = 0.f;
  for (int r = r0; r < r0 + 128; ++r)
    d += expf(bf2f(CAT[(size_t)r * 2048 + 1024 + e]) + Mm[(size_t)r * Ee + e]);
  atomicAdd(&aden[e], d);
}

// ---------------- A_hat fill (A from CAT bf16, transpose, bf16 out) ----------------
__global__ __launch_bounds__(256) void ahat_k(
    const unsigned short* __restrict__ CAT, const float* __restrict__ Mm,
    const float* __restrict__ H, const float* __restrict__ aden,
    unsigned short* __restrict__ AhB)
{
  __shared__ float tile[64][65];
  int j0 = blockIdx.x * 64, e0 = blockIdx.y * 64;
  int te = threadIdx.x & 63;
  int tq = threadIdx.x >> 6;
  int e = e0 + te;
  float inv = 1.f / aden[e];
  for (int jj = tq; jj < 64; jj += 4) {
    long idx = (long)(j0 + jj) * Ee + e;
    float a = bf2f(CAT[(size_t)(j0 + jj) * 2048 + 1024 + e]);
    float val = (H[idx] > 0.f) ? expf(a + Mm[idx]) * inv : 0.f;
    tile[te][jj] = val;
  }
  __syncthreads();
  for (int ee = tq; ee < 64; ee += 4)
    AhB[(long)(e0 + ee) * Nn + j0 + te] = f2bf(tile[ee][te]);
}

// ---------------- B_hat (B from CAT bf16): bf16 out ----------------
__global__ __launch_bounds__(256) void bhat_k(const unsigned short* __restrict__ CAT,
                                              const float* __restrict__ Mm,
                                              const float* __restrict__ H,
                                              unsigned short* __restrict__ Bb2)
{
  int i = blockIdx.x, t = threadIdx.x;
  long base = (long)i * Ee + t * 4;
  ushort4 bu = *reinterpret_cast<const ushort4*>(&CAT[(long)i * 2048 + t * 4]);
  float4 m = *reinterpret_cast<const float4*>(&Mm[base]);
  float4 h = *reinterpret_cast<const float4*>(&H[base]);
  float bb[4] = {bf2f(bu.x), bf2f(bu.y), bf2f(bu.z), bf2f(bu.w)};
  float mm2[4] = {m.x, m.y, m.z, m.w}, hh[4] = {h.x, h.y, h.z, h.w};
  float p[4]; float s = 0.f;
  #pragma unroll
  for (int k = 0; k < 4; ++k) { p[k] = expf(bb[k] + mm2[k]); s += p[k]; }
  float den = block_reduce_sum(s);
  float inv = 1.f / den;
  #pragma unroll
  for (int k = 0; k < 4; ++k) p[k] = hh[k] > 0.f ? p[k] * inv : 0.f;
  ushort4 ob = {f2bf(p[0]), f2bf(p[1]), f2bf(p[2]), f2bf(p[3])};
  *reinterpret_cast<ushort4*>(&Bb2[base]) = ob;
}

// ---------------- launcher ----------------
extern "C" void kernel_launch(void* const* d_in, const int* in_sizes, int n_in,
                              void* d_out, int out_size, void* d_ws, size_t ws_size,
                              hipStream_t stream) {
  const float* x    = (const float*)d_in[0];
  const float* H    = (const float*)d_in[1];
  const float* adj  = (const float*)d_in[2];
  const float* W_he = (const float*)d_in[3];
  const float* u    = (const float*)d_in[4];
  const float* W_e  = (const float*)d_in[5];
  const float* W_n  = (const float*)d_in[6];
  const float* W_g  = (const float*)d_in[7];
  const float* a_g  = (const float*)d_in[8];
  float* out = (float*)d_out;
  float* ws  = (float*)d_ws;
  (void)in_sizes; (void)n_in; (void)out_size; (void)ws_size;

  size_t off = 0;
  auto alloc = [&](size_t n) { float* p = ws + off; off += n; return p; };
  float* hcat4  = alloc((size_t)Nn * 1024);  // [h_he | hn | h_g | hW]
  float* Wp     = alloc((size_t)Dd * Dd);    // W_he @ W_e
  float* esc    = alloc(Nn);
  float* s1     = alloc(Nn);
  float* s2     = alloc(Nn);
  float* colden = alloc(Ee);   // colden,cnt,aden,rowsum contiguous -> one memset
  float* cnt    = alloc(Ee);
  float* aden   = alloc(Ee);
  float* rowsum = alloc(Nn);
  float* heb    = alloc((size_t)Ee * Dd);    // heb,tewTf contiguous -> one memset
  float* tewTf  = alloc((size_t)Dd * Ee);
  float* Bbuf   = alloc((size_t)Nn * Ee);
  float* Mm     = alloc((size_t)Nn * Ee);
  unsigned short* Gb    = (unsigned short*)alloc((size_t)Nn * Nn / 2);
  unsigned short* CAT   = (unsigned short*)alloc((size_t)Nn * 2048 / 2);
  unsigned short* Hbt   = (unsigned short*)alloc((size_t)Ee * Nn / 2);
  unsigned short* AbT   = (unsigned short*)alloc((size_t)Ee * Nn / 2);
  unsigned short* AhB   = (unsigned short*)alloc((size_t)Ee * Nn / 2);
  unsigned short* hWT   = (unsigned short*)alloc((size_t)Dd * Nn / 2);
  unsigned short* hgT   = (unsigned short*)alloc((size_t)Dd * Nn / 2);
  unsigned short* tewT  = (unsigned short*)alloc((size_t)Dd * Ee / 2);
  unsigned short* Bb2   = (unsigned short*)alloc((size_t)Nn * Ee / 2);
  unsigned short* xb    = (unsigned short*)alloc((size_t)Nn * Dd / 2);
  unsigned short* WcTb4 = (unsigned short*)alloc((size_t)1024 * Dd / 2);
  unsigned short* hcatB = (unsigned short*)alloc((size_t)Nn * 1024 / 2);
  unsigned short* hebB  = (unsigned short*)alloc((size_t)Ee * Dd / 2);

  hipMemsetAsync(colden, 0, (3 * Ee + Nn) * sizeof(float), stream);
  hipMemsetAsync(heb, 0, 2 * (size_t)Ee * Dd * sizeof(float), stream);
  hipMemsetAsync(Mm, 0, (size_t)Nn * Ee * sizeof(float), stream);
  hipMemsetAsync(out, 0, 2 * (size_t)Nn * Dd * sizeof(float), stream);

  auto gbt = [&](const unsigned short* A, const unsigned short* B, float* C, unsigned short* Cb,
                 int M, int N, int K, int lda, int ldb, float alpha) {
    gemm_bt_bf16<<<dim3(M / 128, N / 128), 256, 0, stream>>>(A, B, C, Cb, M, N, K, lda, ldb, alpha);
  };
  auto gs64 = [&](const unsigned short* A, const unsigned short* B, float* C,
                  int M, int N, int K, int KS) {
    gemm64s_bt_bf16<<<dim3(M / 64, N / 64, K / KS), 256, 0, stream>>>(A, B, C, M, N, K, KS);
  };
  auto tcvt = [&](const float* in, unsigned short* o, int R, int S, int cols, const float* cd) {
    tcvt_k<<<dim3(R / 64, cols / 64), 256, 0, stream>>>(in, o, R, S, cd);
  };

  // Wp = W_he @ W_e (tiny f32)
  gemm64_k<<<dim3(4, 4), 256, 0, stream>>>(W_he, W_e, Wp, Dd, Dd, Dd, Dd, 1, Dd, 1);
  // bf16 operands
  cvt_bf16_k<<<(Nn * Dd) / 2048, 256, 0, stream>>>(x, xb, (long)Nn * Dd);
  tcvt(W_he, WcTb4, Dd, Dd, Dd, nullptr);
  tcvt(W_n, WcTb4 + 1 * 256 * 256, Dd, Dd, Dd, nullptr);
  tcvt(W_g, WcTb4 + 2 * 256 * 256, Dd, Dd, Dd, nullptr);
  tcvt(Wp, WcTb4 + 3 * 256 * 256, Dd, Dd, Dd, nullptr);
  // fused projections: hcat4(+hcatB) = x @ [W_he|W_n|W_g|Wp]
  gbt(xb, WcTb4, hcat4, hcatB, Nn, 1024, Dd, Dd, Dd, 1.f);
  rowdots_k<<<Nn, 256, 0, stream>>>(hcat4, u, a_g, esc, s1, s2);
  // A column softmax
  colstats_k<<<dim3(Ee / 256, 32), 256, 0, stream>>>(H, esc, colden, cnt);
  fillA_k<<<dim3(Nn / 64, Ee / 64), 256, 0, stream>>>(H, esc, colden, CAT, AbT);
  // heb = A^T @ hW  (split-K, 512 blocks)
  tcvt(hcat4 + 768, hWT, Nn, 1024, Dd, nullptr);
  gs64(AbT, hWT, heb, Ee, Dd, Nn, 512);
  cvt_bf16_k<<<(Ee * Dd) / 2048, 256, 0, stream>>>(heb, hebB, (long)Ee * Dd);
  // Bsc = (hn @ heb^T)/16, row softmax -> CAT B-half
  gbt(hcatB + 256, hebB, Bbuf, nullptr, Nn, Ee, Dd, 1024, Dd, 0.0625f);
  brow_k<<<Nn, 256, 0, stream>>>(Bbuf, H, CAT);
  // G softmax -> bf16 logits
  gfill_k<<<Nn, 256, 0, stream>>>(adj, s1, s2, Gb);
  // M = G @ (H/he_sz) : pre-scaled Hbt, split-K atomic
  tcvt(H, Hbt, Nn, Ee, Ee, cnt);
  gemm_bts_bf16<<<dim3(Nn / 128, Ee / 128, 2), 256, 0, stream>>>(Gb, Hbt, Mm, Nn, Ee, Nn, Nn, Nn, 2048);
  // symmetric fused Gram (packed triangular): Gb = exp(Gb + BB^T + AA^T), rowsum
  gemm_gram_k<<<528, 256, 0, stream>>>(CAT, Gb, rowsum);
  // A_hat
  amstats_k<<<dim3(Ee / 256, 32), 256, 0, stream>>>(CAT, Mm, aden);
  ahat_k<<<dim3(Nn / 64, Ee / 64), 256, 0, stream>>>(CAT, Mm, H, aden, AhB);
  // tewT = (A_hat @ hW)^T = hW^T @ A_hat^T  (split-K, 512 blocks)
  gs64(hWT, AhB, tewTf, Dd, Ee, Nn, 512);
  cvt_bf16_k<<<(Dd * Ee) / 2048, 256, 0, stream>>>(tewTf, tewT, (long)Dd * Ee);
  // B_hat, z_h
  bhat_k<<<Nn, 256, 0, stream>>>(CAT, Mm, H, Bb2);
  gs64(Bb2, tewT, out, Nn, Dd, Ee, 512);
  // z_g (unnormalized), then row-scale + elu
  tcvt(hcat4 + 512, hgT, Nn, 1024, Dd, nullptr);
  gs64(Gb, hgT, out + (size_t)Nn * Dd, Nn, Dd, Nn, 1024);
  elu_rows_k<<<(2 * Nn * Dd) / 1024, 256, 0, stream>>>(out, rowsum);
}

// Round 8
// 586.566 us; speedup vs baseline: 4.6369x; 1.0013x over previous
//
#include <hip/hip_runtime.h>
#include <math.h>
#include <stdint.h>

#define Nn 4096
#define Ee 1024
#define Dd 256

typedef __attribute__((ext_vector_type(8))) __bf16 bf16x8;
typedef __attribute__((ext_vector_type(4))) float f32x4;
typedef __attribute__((ext_vector_type(8))) unsigned short u16x8;

__device__ __forceinline__ unsigned short f2bf(float f) {
  unsigned int u = __float_as_uint(f);
  unsigned int r = (u + 0x7fffu + ((u >> 16) & 1u)) >> 16;
  return (unsigned short)r;
}
__device__ __forceinline__ float bf2f(unsigned short u) {
  return __uint_as_float(((unsigned int)u) << 16);
}

__device__ __forceinline__ void gload_lds16(const void* g, void* l) {
  __builtin_amdgcn_global_load_lds(
      (__attribute__((address_space(1))) void*)const_cast<void*>(g),
      (__attribute__((address_space(3))) void*)l, 16, 0, 0);
}

__device__ __forceinline__ float block_reduce_sum(float v) {
  __shared__ float sh[4];
  #pragma unroll
  for (int o = 32; o > 0; o >>= 1) v += __shfl_down(v, o);
  int lane = threadIdx.x & 63, w = threadIdx.x >> 6;
  if (lane == 0) sh[w] = v;
  __syncthreads();
  float s = sh[0] + sh[1] + sh[2] + sh[3];
  __syncthreads();
  return s;
}

// ---------------- bf16 MFMA GEMM: C = alpha*(A*B^T), 128x128, BK=32 (+opt bf16 out) ----------------
__global__ __launch_bounds__(256) void gemm_bt_bf16(
    const unsigned short* __restrict__ Ab, const unsigned short* __restrict__ Bb,
    float* __restrict__ Cp, unsigned short* __restrict__ Cb,
    int M, int N, int K, int lda, int ldb, float alpha)
{
  __shared__ unsigned short As[2][128 * 32];
  __shared__ unsigned short Bs[2][128 * 32];
  const int tid = threadIdx.x;
  const int m0 = blockIdx.x * 128, n0 = blockIdx.y * 128;
  const int wave = tid >> 6, lane = tid & 63;
  const int wr = (wave >> 1) * 64, wc = (wave & 1) * 64;
  const int l16 = lane & 15, lq = lane >> 4;
  f32x4 acc[4][4] = {};
  const int NT = K >> 5;

  auto stage = [&](int buf, int kt) {
    const int k0 = kt * 32;
    #pragma unroll
    for (int i = 0; i < 2; ++i) {
      int t2 = tid + i * 256;
      int r = t2 >> 2, c = (t2 & 3) * 8;
      gload_lds16(Ab + (size_t)(m0 + r) * lda + k0 + c, &As[buf][t2 * 8]);
    }
    #pragma unroll
    for (int i = 0; i < 2; ++i) {
      int t2 = tid + i * 256;
      int r = t2 >> 2, c = (t2 & 3) * 8;
      gload_lds16(Bb + (size_t)(n0 + r) * ldb + k0 + c, &Bs[buf][t2 * 8]);
    }
  };

  stage(0, 0);
  __syncthreads();
  int buf = 0;
  for (int kt = 0; kt < NT; ++kt) {
    if (kt + 1 < NT) stage(buf ^ 1, kt + 1);
    bf16x8 af[4], bfr[4];
    #pragma unroll
    for (int m = 0; m < 4; ++m)
      af[m] = *reinterpret_cast<const bf16x8*>(&As[buf][(wr + m * 16 + l16) * 32 + lq * 8]);
    #pragma unroll
    for (int n = 0; n < 4; ++n)
      bfr[n] = *reinterpret_cast<const bf16x8*>(&Bs[buf][(wc + n * 16 + l16) * 32 + lq * 8]);
    #pragma unroll
    for (int m = 0; m < 4; ++m)
      #pragma unroll
      for (int n = 0; n < 4; ++n)
        acc[m][n] = __builtin_amdgcn_mfma_f32_16x16x32_bf16(af[m], bfr[n], acc[m][n], 0, 0, 0);
    __syncthreads();
    buf ^= 1;
  }
  #pragma unroll
  for (int m = 0; m < 4; ++m)
    #pragma unroll
    for (int n = 0; n < 4; ++n) {
      int col = n0 + wc + n * 16 + l16;
      #pragma unroll
      for (int q = 0; q < 4; ++q) {
        int row = m0 + wr + m * 16 + lq * 4 + q;
        size_t idx = (size_t)row * N + col;
        float v = acc[m][n][q] * alpha;
        Cp[idx] = v;
        if (Cb) Cb[idx] = f2bf(v);
      }
    }
}

// ---------------- bf16 MFMA GEMM, 128x128 tile, BK=32, split-K atomicAdd ----------------
__global__ __launch_bounds__(256) void gemm_bts_bf16(
    const unsigned short* __restrict__ Ab, const unsigned short* __restrict__ Bb,
    float* __restrict__ Cp, int M, int N, int K, int lda, int ldb, int KS)
{
  __shared__ unsigned short As[2][128 * 32];
  __shared__ unsigned short Bs[2][128 * 32];
  const int tid = threadIdx.x;
  const int m0 = blockIdx.x * 128, n0 = blockIdx.y * 128;
  const int kbase = blockIdx.z * KS;
  const int wave = tid >> 6, lane = tid & 63;
  const int wr = (wave >> 1) * 64, wc = (wave & 1) * 64;
  const int l16 = lane & 15, lq = lane >> 4;
  f32x4 acc[4][4] = {};
  const int NT = KS >> 5;

  auto stage = [&](int buf, int kt) {
    const int k0 = kbase + kt * 32;
    #pragma unroll
    for (int i = 0; i < 2; ++i) {
      int t2 = tid + i * 256;
      int r = t2 >> 2, c = (t2 & 3) * 8;
      gload_lds16(Ab + (size_t)(m0 + r) * lda + k0 + c, &As[buf][t2 * 8]);
    }
    #pragma unroll
    for (int i = 0; i < 2; ++i) {
      int t2 = tid + i * 256;
      int r = t2 >> 2, c = (t2 & 3) * 8;
      gload_lds16(Bb + (size_t)(n0 + r) * ldb + k0 + c, &Bs[buf][t2 * 8]);
    }
  };

  stage(0, 0);
  __syncthreads();
  int buf = 0;
  for (int kt = 0; kt < NT; ++kt) {
    if (kt + 1 < NT) stage(buf ^ 1, kt + 1);
    bf16x8 af[4], bfr[4];
    #pragma unroll
    for (int m = 0; m < 4; ++m)
      af[m] = *reinterpret_cast<const bf16x8*>(&As[buf][(wr + m * 16 + l16) * 32 + lq * 8]);
    #pragma unroll
    for (int n = 0; n < 4; ++n)
      bfr[n] = *reinterpret_cast<const bf16x8*>(&Bs[buf][(wc + n * 16 + l16) * 32 + lq * 8]);
    #pragma unroll
    for (int m = 0; m < 4; ++m)
      #pragma unroll
      for (int n = 0; n < 4; ++n)
        acc[m][n] = __builtin_amdgcn_mfma_f32_16x16x32_bf16(af[m], bfr[n], acc[m][n], 0, 0, 0);
    __syncthreads();
    buf ^= 1;
  }
  #pragma unroll
  for (int m = 0; m < 4; ++m)
    #pragma unroll
    for (int n = 0; n < 4; ++n) {
      int col = n0 + wc + n * 16 + l16;
      #pragma unroll
      for (int q = 0; q < 4; ++q) {
        int row = m0 + wr + m * 16 + lq * 4 + q;
        atomicAdd(&Cp[(size_t)row * N + col], acc[m][n][q]);
      }
    }
}

// ---------------- symmetric fused Gram (packed triangular, XCD-swizzled, 528 blocks) ----------------
__global__ __launch_bounds__(256) void gemm_gram_k(
    const unsigned short* __restrict__ CAT,   // [Nn][2048] bf16
    unsigned short* __restrict__ Gb,          // in: bf16 logits; out: exp(logit)
    float* __restrict__ rowsum)               // pre-zeroed [Nn]
{
  // XCD swizzle: 528 = 8 XCDs x 66 blocks; each XCD gets a contiguous packed range
  // -> contiguous (by,bx) region -> B-panels stay resident in that XCD's L2.
  int bid = (blockIdx.x & 7) * 66 + (blockIdx.x >> 3);
  int by = (int)((sqrtf(8.f * bid + 1.f) - 1.f) * 0.5f);
  while ((by + 1) * (by + 2) / 2 <= bid) ++by;
  while (by * (by + 1) / 2 > bid) --by;
  int bx = bid - by * (by + 1) / 2;
  const int K = 2048;
  __shared__ unsigned short SM[17024];
  unsigned short* Asb = SM;
  unsigned short* Bsb = SM + 8192;
  const int tid = threadIdx.x;
  const int m0 = bx * 128, n0 = by * 128;
  const int wave = tid >> 6, lane = tid & 63;
  const int wr = (wave >> 1) * 64, wc = (wave & 1) * 64;
  const int l16 = lane & 15, lq = lane >> 4;
  f32x4 acc[4][4] = {};
  const int NT = K >> 5;

  auto stage = [&](int buf, int kt) {
    const int k0 = kt * 32;
    #pragma unroll
    for (int i = 0; i < 2; ++i) {
      int t2 = tid + i * 256;
      int r = t2 >> 2, c = (t2 & 3) * 8;
      gload_lds16(CAT + (size_t)(m0 + r) * K + k0 + c, Asb + buf * 4096 + t2 * 8);
    }
    #pragma unroll
    for (int i = 0; i < 2; ++i) {
      int t2 = tid + i * 256;
      int r = t2 >> 2, c = (t2 & 3) * 8;
      gload_lds16(CAT + (size_t)(n0 + r) * K + k0 + c, Bsb + buf * 4096 + t2 * 8);
    }
  };

  stage(0, 0);
  __syncthreads();
  int buf = 0;
  for (int kt = 0; kt < NT; ++kt) {
    if (kt + 1 < NT) stage(buf ^ 1, kt + 1);
    bf16x8 af[4], bfr[4];
    #pragma unroll
    for (int m = 0; m < 4; ++m)
      af[m] = *reinterpret_cast<const bf16x8*>(Asb + buf * 4096 + (wr + m * 16 + l16) * 32 + lq * 8);
    #pragma unroll
    for (int n = 0; n < 4; ++n)
      bfr[n] = *reinterpret_cast<const bf16x8*>(Bsb + buf * 4096 + (wc + n * 16 + l16) * 32 + lq * 8);
    #pragma unroll
    for (int m = 0; m < 4; ++m)
      #pragma unroll
      for (int n = 0; n < 4; ++n)
        acc[m][n] = __builtin_amdgcn_mfma_f32_16x16x32_bf16(af[m], bfr[n], acc[m][n], 0, 0, 0);
    __syncthreads();
    buf ^= 1;
  }
  // normal epilogue (upper/diag region)
  #pragma unroll
  for (int m = 0; m < 4; ++m)
    #pragma unroll
    for (int q = 0; q < 4; ++q) {
      int row = m0 + wr + m * 16 + lq * 4 + q;
      float s = 0.f;
      #pragma unroll
      for (int n = 0; n < 4; ++n) {
        int col = n0 + wc + n * 16 + l16;
        size_t idx = (size_t)row * Nn + col;
        float e = expf(bf2f(Gb[idx]) + acc[m][n][q]);
        Gb[idx] = f2bf(e);
        s += e;
      }
      s += __shfl_xor(s, 1); s += __shfl_xor(s, 2);
      s += __shfl_xor(s, 4); s += __shfl_xor(s, 8);
      if (l16 == 0) atomicAdd(&rowsum[row], s);
    }
  if (bx == by) return;

  // transposed epilogue (lower region): mirror tile via LDS
  __syncthreads();
  unsigned short* Tg = SM;  // [128][132]
  {
    int cc = tid >> 1, r0 = (tid & 1) * 64;
    const unsigned short* src = Gb + (size_t)(n0 + cc) * Nn + m0 + r0;
    unsigned short* dst = Tg + cc * 132 + r0;
    #pragma unroll
    for (int v = 0; v < 8; ++v)
      *reinterpret_cast<u16x8*>(dst + v * 8) = *reinterpret_cast<const u16x8*>(src + v * 8);
  }
  __syncthreads();
  #pragma unroll
  for (int n = 0; n < 4; ++n) {
    int ccl = wc + n * 16 + l16;
    float cs = 0.f;
    #pragma unroll
    for (int m = 0; m < 4; ++m) {
      int sa = ccl * 132 + wr + m * 16 + lq * 4;
      ushort4 lg = *reinterpret_cast<const ushort4*>(&Tg[sa]);
      ushort4 eo;
      float e0 = expf(bf2f(lg.x) + acc[m][n][0]); eo.x = f2bf(e0); cs += e0;
      float e1 = expf(bf2f(lg.y) + acc[m][n][1]); eo.y = f2bf(e1); cs += e1;
      float e2 = expf(bf2f(lg.z) + acc[m][n][2]); eo.z = f2bf(e2); cs += e2;
      float e3 = expf(bf2f(lg.w) + acc[m][n][3]); eo.w = f2bf(e3); cs += e3;
      *reinterpret_cast<ushort4*>(&Tg[sa]) = eo;
    }
    cs += __shfl_xor(cs, 16); cs += __shfl_xor(cs, 32);
    if (lq == 0) atomicAdd(&rowsum[n0 + ccl], cs);
  }
  __syncthreads();
  {
    int cc = tid >> 1, r0 = (tid & 1) * 64;
    const unsigned short* src = Tg + cc * 132 + r0;
    unsigned short* dst = Gb + (size_t)(n0 + cc) * Nn + m0 + r0;
    #pragma unroll
    for (int v = 0; v < 8; ++v)
      *reinterpret_cast<u16x8*>(dst + v * 8) = *reinterpret_cast<const u16x8*>(src + v * 8);
  }
}

// ---------------- bf16 MFMA GEMM, 64x64 tile, BK=64, split-K via atomicAdd ----------------
__global__ __launch_bounds__(256) void gemm64s_bt_bf16(
    const unsigned short* __restrict__ Ab, const unsigned short* __restrict__ Bb,
    float* __restrict__ Cp, int M, int N, int K, int KS)
{
  __shared__ unsigned short As[2][64 * 64];
  __shared__ unsigned short Bs[2][64 * 64];
  const int tid = threadIdx.x;
  const int m0 = blockIdx.x * 64, n0 = blockIdx.y * 64;
  const int kbase = blockIdx.z * KS;
  const int wave = tid >> 6, lane = tid & 63;
  const int wr = (wave >> 1) * 32, wc = (wave & 1) * 32;
  const int l16 = lane & 15, lq = lane >> 4;
  f32x4 acc[2][2] = {};
  const int NT = KS >> 6;

  auto stage = [&](int buf, int kt) {
    const int k0 = kbase + kt * 64;
    #pragma unroll
    for (int i = 0; i < 2; ++i) {
      int t2 = tid + i * 256;
      int r = t2 >> 3, c = (t2 & 7) * 8;
      gload_lds16(Ab + (size_t)(m0 + r) * K + k0 + c, &As[buf][t2 * 8]);
    }
    #pragma unroll
    for (int i = 0; i < 2; ++i) {
      int t2 = tid + i * 256;
      int r = t2 >> 3, c = (t2 & 7) * 8;
      gload_lds16(Bb + (size_t)(n0 + r) * K + k0 + c, &Bs[buf][t2 * 8]);
    }
  };

  stage(0, 0);
  __syncthreads();
  int buf = 0;
  for (int kt = 0; kt < NT; ++kt) {
    if (kt + 1 < NT) stage(buf ^ 1, kt + 1);
    bf16x8 af[2][2], bfr[2][2];
    #pragma unroll
    for (int m = 0; m < 2; ++m)
      #pragma unroll
      for (int ks = 0; ks < 2; ++ks)
        af[m][ks] = *reinterpret_cast<const bf16x8*>(
            &As[buf][(wr + m * 16 + l16) * 64 + ks * 32 + lq * 8]);
    #pragma unroll
    for (int n = 0; n < 2; ++n)
      #pragma unroll
      for (int ks = 0; ks < 2; ++ks)
        bfr[n][ks] = *reinterpret_cast<const bf16x8*>(
            &Bs[buf][(wc + n * 16 + l16) * 64 + ks * 32 + lq * 8]);
    #pragma unroll
    for (int m = 0; m < 2; ++m)
      #pragma unroll
      for (int n = 0; n < 2; ++n)
        #pragma unroll
        for (int ks = 0; ks < 2; ++ks)
          acc[m][n] = __builtin_amdgcn_mfma_f32_16x16x32_bf16(af[m][ks], bfr[n][ks], acc[m][n], 0, 0, 0);
    __syncthreads();
    buf ^= 1;
  }
  #pragma unroll
  for (int m = 0; m < 2; ++m)
    #pragma unroll
    for (int n = 0; n < 2; ++n) {
      int col = n0 + wc + n * 16 + l16;
      #pragma unroll
      for (int q = 0; q < 4; ++q) {
        int row = m0 + wr + m * 16 + lq * 4 + q;
        atomicAdd(&Cp[(size_t)row * N + col], acc[m][n][q]);
      }
    }
}

// ---------------- f32 -> bf16 convert ----------------
__global__ __launch_bounds__(256) void cvt_bf16_k(const float* __restrict__ in,
                                                  unsigned short* __restrict__ out, long n) {
  long i = ((long)blockIdx.x * 256 + threadIdx.x) * 8;
  if (i + 8 > n) return;
  float4 a = *reinterpret_cast<const float4*>(&in[i]);
  float4 b = *reinterpret_cast<const float4*>(&in[i + 4]);
  u16x8 o;
  o[0] = f2bf(a.x); o[1] = f2bf(a.y); o[2] = f2bf(a.z); o[3] = f2bf(a.w);
  o[4] = f2bf(b.x); o[5] = f2bf(b.y); o[6] = f2bf(b.z); o[7] = f2bf(b.w);
  *reinterpret_cast<u16x8*>(&out[i]) = o;
}

// ---------------- transpose-convert f32 [R rows, S stride] -> bf16 [C][R], opt col scale ----------------
__global__ __launch_bounds__(256) void tcvt_k(const float* __restrict__ in,
                                              unsigned short* __restrict__ outT, int R, int S,
                                              const float* __restrict__ coldiv) {
  __shared__ unsigned short tile[64][65];
  int r0 = blockIdx.x * 64, c0 = blockIdx.y * 64;
  int t = threadIdx.x & 63, q = threadIdx.x >> 6;
  float sc = coldiv ? 1.f / fmaxf(coldiv[c0 + t], 1.f) : 1.f;
  for (int rr = q; rr < 64; rr += 4)
    tile[t][rr] = f2bf(in[(long)(r0 + rr) * S + c0 + t] * sc);
  __syncthreads();
  for (int cc = q; cc < 64; cc += 4)
    outT[(long)(c0 + cc) * R + r0 + t] = tile[cc][t];
}

// ---------------- 4x W transpose-convert (256x256 each) in one launch ----------------
__global__ __launch_bounds__(256) void tcvtW_k(const float* __restrict__ W0,
                                               const float* __restrict__ W1,
                                               const float* __restrict__ W2,
                                               const float* __restrict__ W3,
                                               unsigned short* __restrict__ outT) {
  __shared__ unsigned short tile[64][65];
  int s = blockIdx.z;
  const float* in = s == 0 ? W0 : (s == 1 ? W1 : (s == 2 ? W2 : W3));
  unsigned short* o = outT + (size_t)s * 256 * 256;
  int r0 = blockIdx.x * 64, c0 = blockIdx.y * 64;
  int t = threadIdx.x & 63, q = threadIdx.x >> 6;
  for (int rr = q; rr < 64; rr += 4)
    tile[t][rr] = f2bf(in[(long)(r0 + rr) * Dd + c0 + t]);
  __syncthreads();
  for (int cc = q; cc < 64; cc += 4)
    o[(long)(c0 + cc) * Dd + r0 + t] = tile[cc][t];
}

// ---------------- 2x hcat4-slice transpose-convert (hW->hWT, h_g->hgT) ----------------
__global__ __launch_bounds__(256) void tcvtH_k(const float* __restrict__ hcat4,
                                               unsigned short* __restrict__ hWT,
                                               unsigned short* __restrict__ hgT) {
  __shared__ unsigned short tile[64][65];
  int s = blockIdx.z;
  const float* in = hcat4 + (s == 0 ? 768 : 512);
  unsigned short* o = s == 0 ? hWT : hgT;
  int r0 = blockIdx.x * 64, c0 = blockIdx.y * 64;
  int t = threadIdx.x & 63, q = threadIdx.x >> 6;
  for (int rr = q; rr < 64; rr += 4)
    tile[t][rr] = f2bf(in[(long)(r0 + rr) * 1024 + c0 + t]);
  __syncthreads();
  for (int cc = q; cc < 64; cc += 4)
    o[(long)(c0 + cc) * Nn + r0 + t] = tile[cc][t];
}

// ---------------- final: scale z_g rows by 1/rowsum, elu both halves ----------------
__global__ __launch_bounds__(256) void elu_rows_k(float* __restrict__ p,
                                                  const float* __restrict__ rowsum) {
  long i = ((long)blockIdx.x * 256 + threadIdx.x) * 4;
  float4 v = *reinterpret_cast<const float4*>(&p[i]);
  float sc = 1.f;
  long half = (long)Nn * Dd;
  if (i >= half) sc = 1.f / rowsum[(i - half) >> 8];
  v.x *= sc; v.y *= sc; v.z *= sc; v.w *= sc;
  v.x = v.x > 0.f ? v.x : expm1f(v.x);
  v.y = v.y > 0.f ? v.y : expm1f(v.y);
  v.z = v.z > 0.f ? v.z : expm1f(v.z);
  v.w = v.w > 0.f ? v.w : expm1f(v.w);
  *reinterpret_cast<float4*>(&p[i]) = v;
}

// ---------------- generic strided f32 GEMM, 64x64 tile (Wp only) ----------------
__global__ __launch_bounds__(256) void gemm64_k(
    const float* __restrict__ Ap, const float* __restrict__ Bp, float* __restrict__ Cp,
    int M, int N, int K, int Asm, int Ask, int Bsk, int Bsn)
{
  __shared__ alignas(16) float As[16][68];
  __shared__ alignas(16) float Bs[16][68];
  const int tid = threadIdx.x;
  const int tx = tid & 15, ty = tid >> 4;
  const int m0 = blockIdx.x * 64, n0 = blockIdx.y * 64;
  float acc[4][4] = {};
  for (int k0 = 0; k0 < K; k0 += 16) {
    if (Ask == 1) {
      int mm = tid >> 2, kk = (tid & 3) << 2;
      float4 v = *reinterpret_cast<const float4*>(&Ap[(long)(m0 + mm) * Asm + k0 + kk]);
      As[kk + 0][mm] = v.x; As[kk + 1][mm] = v.y; As[kk + 2][mm] = v.z; As[kk + 3][mm] = v.w;
    } else {
      int kk = tid >> 4, mm = (tid & 15) << 2;
      *reinterpret_cast<float4*>(&As[kk][mm]) =
          *reinterpret_cast<const float4*>(&Ap[(long)(k0 + kk) * Ask + m0 + mm]);
    }
    if (Bsn == 1) {
      int kk = tid >> 4, nn = (tid & 15) << 2;
      *reinterpret_cast<float4*>(&Bs[kk][nn]) =
          *reinterpret_cast<const float4*>(&Bp[(long)(k0 + kk) * Bsk + n0 + nn]);
    } else {
      int nn = tid >> 2, kk = (tid & 3) << 2;
      float4 v = *reinterpret_cast<const float4*>(&Bp[(long)(n0 + nn) * Bsn + k0 + kk]);
      Bs[kk + 0][nn] = v.x; Bs[kk + 1][nn] = v.y; Bs[kk + 2][nn] = v.z; Bs[kk + 3][nn] = v.w;
    }
    __syncthreads();
    #pragma unroll
    for (int kk = 0; kk < 16; ++kk) {
      float4 av = *reinterpret_cast<const float4*>(&As[kk][ty << 2]);
      float4 bv = *reinterpret_cast<const float4*>(&Bs[kk][tx << 2]);
      float a[4] = {av.x, av.y, av.z, av.w};
      float b[4] = {bv.x, bv.y, bv.z, bv.w};
      #pragma unroll
      for (int r = 0; r < 4; ++r)
        #pragma unroll
        for (int c = 0; c < 4; ++c) acc[r][c] = fmaf(a[r], b[c], acc[r][c]);
    }
    __syncthreads();
  }
  #pragma unroll
  for (int r = 0; r < 4; ++r) {
    long base = (long)(m0 + (ty << 2) + r) * N + n0 + (tx << 2);
    float4 o = {acc[r][0], acc[r][1], acc[r][2], acc[r][3]};
    *reinterpret_cast<float4*>(&Cp[base]) = o;
  }
}

// ---------------- sc/s1/s2 row dots (hcat4 stride 1024) ----------------
__global__ __launch_bounds__(256) void rowdots_k(
    const float* __restrict__ hcat, const float* __restrict__ u, const float* __restrict__ a_g,
    float* __restrict__ esc, float* __restrict__ s1, float* __restrict__ s2)
{
  int i = blockIdx.x, t = threadIdx.x;
  float hh = hcat[(long)i * 1024 + t];
  float hg = hcat[(long)i * 1024 + 512 + t];
  float d0 = block_reduce_sum(hh * u[t]);
  float d1 = block_reduce_sum(hg * a_g[t]);
  float d2 = block_reduce_sum(hg * a_g[Dd + t]);
  if (t == 0) {
    esc[i] = expf(d0 * 0.0625f);
    s1[i] = d1;
    s2[i] = d2;
  }
}

// ---------------- column softmax stats for A ----------------
__global__ __launch_bounds__(256) void colstats_k(
    const float* __restrict__ H, const float* __restrict__ esc,
    float* __restrict__ colden, float* __restrict__ cnt)
{
  int e = blockIdx.x * 256 + threadIdx.x;
  int r0 = blockIdx.y * 128;
  float d = 0.f, c = 0.f;
  for (int r = r0; r < r0 + 128; ++r) {
    float h = H[(long)r * Ee + e];
    if (h > 0.f) { d += esc[r]; c += 1.f; }
  }
  atomicAdd(&colden[e], d);
  atomicAdd(&cnt[e], c);
}

// ---------------- A fill (tile): CAT A-half bf16 + AbT bf16 ----------------
__global__ __launch_bounds__(256) void fillA_k(
    const float* __restrict__ H, const float* __restrict__ esc,
    const float* __restrict__ colden,
    unsigned short* __restrict__ CAT, unsigned short* __restrict__ AbT)
{
  __shared__ unsigned short tile[64][68];
  int r0 = blockIdx.x * 64, e0 = blockIdx.y * 64;
  int te = threadIdx.x & 63, tq = threadIdx.x >> 6;
  float cd = colden[e0 + te];
  for (int rr = tq; rr < 64; rr += 4) {
    long idx = (long)(r0 + rr) * Ee + e0 + te;
    float h = H[idx];
    float val = h > 0.f ? esc[r0 + rr] / cd : 0.f;
    unsigned short vb = f2bf(val);
    CAT[(long)(r0 + rr) * 2048 + 1024 + e0 + te] = vb;
    tile[te][rr] = vb;
  }
  __syncthreads();
  for (int ee = tq; ee < 64; ee += 4)
    AbT[(long)(e0 + ee) * Nn + r0 + te] = tile[ee][te];
}

// ---------------- B row softmax: CAT B-half bf16 only ----------------
__global__ __launch_bounds__(256) void brow_k(const float* __restrict__ Bbuf,
                                              const float* __restrict__ H,
                                              unsigned short* __restrict__ CAT)
{
  int i = blockIdx.x, t = threadIdx.x;
  long base = (long)i * Ee + t * 4;
  float4 raw = *reinterpret_cast<const float4*>(&Bbuf[base]);
  float4 h = *reinterpret_cast<const float4*>(&H[base]);
  float rr[4] = {raw.x, raw.y, raw.z, raw.w}, hh[4] = {h.x, h.y, h.z, h.w};
  float p[4]; float s = 0.f;
  #pragma unroll
  for (int k = 0; k < 4; ++k) { p[k] = hh[k] > 0.f ? expf(rr[k]) : 0.f; s += p[k]; }
  float den = block_reduce_sum(s);
  float inv = den > 0.f ? 1.f / den : 0.f;
  ushort4 ob = {f2bf(p[0] * inv), f2bf(p[1] * inv), f2bf(p[2] * inv), f2bf(p[3] * inv)};
  *reinterpret_cast<ushort4*>(&CAT[(long)i * 2048 + t * 4]) = ob;
}

// ---------------- G fill: bf16 logits only ----------------
__global__ __launch_bounds__(256) void gfill_k(
    const float* __restrict__ adj, const float* __restrict__ s1,
    const float* __restrict__ s2, unsigned short* __restrict__ Gb)
{
  int i = blockIdx.x, t = threadIdx.x;
  float s1i = s1[i];
  float p[16]; float sum = 0.f;
  #pragma unroll
  for (int c = 0; c < 4; ++c) {
    int j = c * 1024 + t * 4;
    float4 a = *reinterpret_cast<const float4*>(&adj[(long)i * Nn + j]);
    float4 sv = *reinterpret_cast<const float4*>(&s2[j]);
    float aa[4] = {a.x, a.y, a.z, a.w}, ss[4] = {sv.x, sv.y, sv.z, sv.w};
    #pragma unroll
    for (int k = 0; k < 4; ++k) {
      float f = (aa[k] > 0.f ? 1.f : 0.f) + ((j + k) == i ? 1.f : 0.f);
      float l = s1i + ss[k];
      l = l > 0.f ? l : 0.2f * l;
      float val = l * f - 1e9f * fmaxf(1.f - f, 0.f);
      float pp = expf(val);
      p[c * 4 + k] = pp; sum += pp;
    }
  }
  float den = block_reduce_sum(sum);
  float inv = 1.f / den;
  #pragma unroll
  for (int c = 0; c < 4; ++c) {
    int j = c * 1024 + t * 4;
    ushort4 ob = {f2bf(p[c * 4] * inv), f2bf(p[c * 4 + 1] * inv),
                  f2bf(p[c * 4 + 2] * inv), f2bf(p[c * 4 + 3] * inv)};
    *reinterpret_cast<ushort4*>(&Gb[(long)i * Nn + j]) = ob;
  }
}

// ---------------- A_hat denominators (A from CAT bf16) ----------------
__global__ __launch_bounds__(256) void amstats_k(
    const unsigned short* __restrict__ CAT, const float* __restrict__ Mm,
    float* __restrict__ aden)
{
  int e = blockIdx.x * 256 + threadIdx.x;
  int r0 = blockIdx.y * 128;
  float d = 0.f;
  for (int r = r0; r < r0 + 128; ++r)
    d += expf(bf2f(CAT[(size_t)r * 2048 + 1024 + e]) + Mm[(size_t)r * Ee + e]);
  atomicAdd(&aden[e], d);
}

// ---------------- A_hat fill (A from CAT bf16, transpose, bf16 out) ----------------
__global__ __launch_bounds__(256) void ahat_k(
    const unsigned short* __restrict__ CAT, const float* __restrict__ Mm,
    const float* __restrict__ H, const float* __restrict__ aden,
    unsigned short* __restrict__ AhB)
{
  __shared__ float tile[64][65];
  int j0 = blockIdx.x * 64, e0 = blockIdx.y * 64;
  int te = threadIdx.x & 63;
  int tq = threadIdx.x >> 6;
  int e = e0 + te;
  float inv = 1.f / aden[e];
  for (int jj = tq; jj < 64; jj += 4) {
    long idx = (long)(j0 + jj) * Ee + e;
    float a = bf2f(CAT[(size_t)(j0 + jj) * 2048 + 1024 + e]);
    float val = (H[idx] > 0.f) ? expf(a + Mm[idx]) * inv : 0.f;
    tile[te][jj] = val;
  }
  __syncthreads();
  for (int ee = tq; ee < 64; ee += 4)
    AhB[(long)(e0 + ee) * Nn + j0 + te] = f2bf(tile[ee][te]);
}

// ---------------- B_hat (B from CAT bf16): bf16 out ----------------
__global__ __launch_bounds__(256) void bhat_k(const unsigned short* __restrict__ CAT,
                                              const float* __restrict__ Mm,
                                              const float* __restrict__ H,
                                              unsigned short* __restrict__ Bb2)
{
  int i = blockIdx.x, t = threadIdx.x;
  long base = (long)i * Ee + t * 4;
  ushort4 bu = *reinterpret_cast<const ushort4*>(&CAT[(long)i * 2048 + t * 4]);
  float4 m = *reinterpret_cast<const float4*>(&Mm[base]);
  float4 h = *reinterpret_cast<const float4*>(&H[base]);
  float bb[4] = {bf2f(bu.x), bf2f(bu.y), bf2f(bu.z), bf2f(bu.w)};
  float mm2[4] = {m.x, m.y, m.z, m.w}, hh[4] = {h.x, h.y, h.z, h.w};
  float p[4]; float s = 0.f;
  #pragma unroll
  for (int k = 0; k < 4; ++k) { p[k] = expf(bb[k] + mm2[k]); s += p[k]; }
  float den = block_reduce_sum(s);
  float inv = 1.f / den;
  #pragma unroll
  for (int k = 0; k < 4; ++k) p[k] = hh[k] > 0.f ? p[k] * inv : 0.f;
  ushort4 ob = {f2bf(p[0]), f2bf(p[1]), f2bf(p[2]), f2bf(p[3])};
  *reinterpret_cast<ushort4*>(&Bb2[base]) = ob;
}

// ---------------- launcher ----------------
extern "C" void kernel_launch(void* const* d_in, const int* in_sizes, int n_in,
                              void* d_out, int out_size, void* d_ws, size_t ws_size,
                              hipStream_t stream) {
  const float* x    = (const float*)d_in[0];
  const float* H    = (const float*)d_in[1];
  const float* adj  = (const float*)d_in[2];
  const float* W_he = (const float*)d_in[3];
  const float* u    = (const float*)d_in[4];
  const float* W_e  = (const float*)d_in[5];
  const float* W_n  = (const float*)d_in[6];
  const float* W_g  = (const float*)d_in[7];
  const float* a_g  = (const float*)d_in[8];
  float* out = (float*)d_out;
  float* ws  = (float*)d_ws;
  (void)in_sizes; (void)n_in; (void)out_size; (void)ws_size;

  size_t off = 0;
  auto alloc = [&](size_t n) { float* p = ws + off; off += n; return p; };
  float* hcat4  = alloc((size_t)Nn * 1024);  // [h_he | hn | h_g | hW]
  float* Wp     = alloc((size_t)Dd * Dd);    // W_he @ W_e
  float* esc    = alloc(Nn);
  float* s1     = alloc(Nn);
  float* s2     = alloc(Nn);
  float* colden = alloc(Ee);   // colden,cnt,aden,rowsum contiguous -> one memset
  float* cnt    = alloc(Ee);
  float* aden   = alloc(Ee);
  float* rowsum = alloc(Nn);
  float* heb    = alloc((size_t)Ee * Dd);    // heb,tewTf contiguous -> one memset
  float* tewTf  = alloc((size_t)Dd * Ee);
  float* Bbuf   = alloc((size_t)Nn * Ee);
  float* Mm     = alloc((size_t)Nn * Ee);
  unsigned short* Gb    = (unsigned short*)alloc((size_t)Nn * Nn / 2);
  unsigned short* CAT   = (unsigned short*)alloc((size_t)Nn * 2048 / 2);
  unsigned short* Hbt   = (unsigned short*)alloc((size_t)Ee * Nn / 2);
  unsigned short* AbT   = (unsigned short*)alloc((size_t)Ee * Nn / 2);
  unsigned short* AhB   = (unsigned short*)alloc((size_t)Ee * Nn / 2);
  unsigned short* hWT   = (unsigned short*)alloc((size_t)Dd * Nn / 2);
  unsigned short* hgT   = (unsigned short*)alloc((size_t)Dd * Nn / 2);
  unsigned short* tewT  = (unsigned short*)alloc((size_t)Dd * Ee / 2);
  unsigned short* Bb2   = (unsigned short*)alloc((size_t)Nn * Ee / 2);
  unsigned short* xb    = (unsigned short*)alloc((size_t)Nn * Dd / 2);
  unsigned short* WcTb4 = (unsigned short*)alloc((size_t)1024 * Dd / 2);
  unsigned short* hcatB = (unsigned short*)alloc((size_t)Nn * 1024 / 2);
  unsigned short* hebB  = (unsigned short*)alloc((size_t)Ee * Dd / 2);

  hipMemsetAsync(colden, 0, (3 * Ee + Nn) * sizeof(float), stream);
  hipMemsetAsync(heb, 0, 2 * (size_t)Ee * Dd * sizeof(float), stream);
  hipMemsetAsync(Mm, 0, (size_t)Nn * Ee * sizeof(float), stream);
  hipMemsetAsync(out, 0, 2 * (size_t)Nn * Dd * sizeof(float), stream);

  auto gbt = [&](const unsigned short* A, const unsigned short* B, float* C, unsigned short* Cb,
                 int M, int N, int K, int lda, int ldb, float alpha) {
    gemm_bt_bf16<<<dim3(M / 128, N / 128), 256, 0, stream>>>(A, B, C, Cb, M, N, K, lda, ldb, alpha);
  };
  auto gbts = [&](const unsigned short* A, const unsigned short* B, float* C,
                  int M, int N, int K, int lda, int ldb, int KS) {
    gemm_bts_bf16<<<dim3(M / 128, N / 128, K / KS), 256, 0, stream>>>(A, B, C, M, N, K, lda, ldb, KS);
  };
  auto gs64 = [&](const unsigned short* A, const unsigned short* B, float* C,
                  int M, int N, int K, int KS) {
    gemm64s_bt_bf16<<<dim3(M / 64, N / 64, K / KS), 256, 0, stream>>>(A, B, C, M, N, K, KS);
  };
  auto tcvt = [&](const float* in, unsigned short* o, int R, int S, int cols, const float* cd) {
    tcvt_k<<<dim3(R / 64, cols / 64), 256, 0, stream>>>(in, o, R, S, cd);
  };

  // Wp = W_he @ W_e (tiny f32)
  gemm64_k<<<dim3(4, 4), 256, 0, stream>>>(W_he, W_e, Wp, Dd, Dd, Dd, Dd, 1, Dd, 1);
  // bf16 operands
  cvt_bf16_k<<<(Nn * Dd) / 2048, 256, 0, stream>>>(x, xb, (long)Nn * Dd);
  tcvtW_k<<<dim3(4, 4, 4), 256, 0, stream>>>(W_he, W_n, W_g, Wp, WcTb4);
  // fused projections: hcat4(+hcatB) = x @ [W_he|W_n|W_g|Wp]
  gbt(xb, WcTb4, hcat4, hcatB, Nn, 1024, Dd, Dd, Dd, 1.f);
  rowdots_k<<<Nn, 256, 0, stream>>>(hcat4, u, a_g, esc, s1, s2);
  // hWT + hgT in one launch
  tcvtH_k<<<dim3(Nn / 64, Dd / 64, 2), 256, 0, stream>>>(hcat4, hWT, hgT);
  // A column softmax
  colstats_k<<<dim3(Ee / 256, 32), 256, 0, stream>>>(H, esc, colden, cnt);
  fillA_k<<<dim3(Nn / 64, Ee / 64), 256, 0, stream>>>(H, esc, colden, CAT, AbT);
  // heb = A^T @ hW  (split-K, 512 blocks)
  gs64(AbT, hWT, heb, Ee, Dd, Nn, 512);
  cvt_bf16_k<<<(Ee * Dd) / 2048, 256, 0, stream>>>(heb, hebB, (long)Ee * Dd);
  // Bsc = (hn @ heb^T)/16, row softmax -> CAT B-half
  gbt(hcatB + 256, hebB, Bbuf, nullptr, Nn, Ee, Dd, 1024, Dd, 0.0625f);
  brow_k<<<Nn, 256, 0, stream>>>(Bbuf, H, CAT);
  // G softmax -> bf16 logits
  gfill_k<<<Nn, 256, 0, stream>>>(adj, s1, s2, Gb);
  // M = G @ (H/he_sz) : pre-scaled Hbt, split-K atomic
  tcvt(H, Hbt, Nn, Ee, Ee, cnt);
  gbts(Gb, Hbt, Mm, Nn, Ee, Nn, Nn, Nn, 2048);
  // symmetric fused Gram (packed triangular + XCD swizzle): Gb = exp(Gb + BB^T + AA^T), rowsum
  gemm_gram_k<<<528, 256, 0, stream>>>(CAT, Gb, rowsum);
  // A_hat
  amstats_k<<<dim3(Ee / 256, 32), 256, 0, stream>>>(CAT, Mm, aden);
  ahat_k<<<dim3(Nn / 64, Ee / 64), 256, 0, stream>>>(CAT, Mm, H, aden, AhB);
  // tewT = (A_hat @ hW)^T = hW^T @ A_hat^T  (split-K, 512 blocks)
  gs64(hWT, AhB, tewTf, Dd, Ee, Nn, 512);
  cvt_bf16_k<<<(Dd * Ee) / 2048, 256, 0, stream>>>(tewTf, tewT, (long)Dd * Ee);
  // B_hat, z_h
  bhat_k<<<Nn, 256, 0, stream>>>(CAT, Mm, H, Bb2);
  gs64(Bb2, tewT, out, Nn, Dd, Ee, 512);
  // z_g (unnormalized) on 128^2-tile split-K (512 blocks), then row-scale + elu
  gbts(Gb, hgT, out + (size_t)Nn * Dd, Nn, Dd, Nn, Nn, Nn, 512);
  elu_rows_k<<<(2 * Nn * Dd) / 1024, 256, 0, stream>>>(out, rowsum);
}